// Round 9
// baseline (903.213 us; speedup 1.0000x reference)
//
#include <hip/hip_runtime.h>
#include <stdint.h>

#define B_   4096
#define S_   544
#define H_   256
#define D_   128
#define M_   50000
#define KNN  50
#define NSLICE 8
#define SL_REAL 6250
#define BKEY 64
#define NB   98                  // 64-key tiles per slice
#define SL_PAD (NB * BKEY)       // 6272
#define CAP  128
#define RR   64
#define IMG_U32 5120             // 5 chunks * 4 kslices * 64 keys * 4 u32 = 20KB
#define PROBE_TILES 32

typedef unsigned long long u64;
typedef unsigned int u32;
typedef __attribute__((ext_vector_type(8))) __bf16 bf16x8;
typedef __attribute__((ext_vector_type(8))) unsigned short u16x8;
typedef __attribute__((ext_vector_type(4))) float f32x4;
typedef __attribute__((ext_vector_type(4))) u32 u32x4;

__device__ __forceinline__ u32 bf16_rne(float x) {
  u32 u = __float_as_uint(x);
  return (u + 0x7FFFu + ((u >> 16) & 1u)) >> 16;
}

__device__ __forceinline__ void gl_lds16(const u32* g, u32* l) {
  __builtin_amdgcn_global_load_lds(
      (const __attribute__((address_space(1))) u32*)g,
      (__attribute__((address_space(3))) u32*)l, 16, 0, 0);
}

// ---------------- K1: h = relu(states@W1+b1) (z=0), v1 = relu(states@V1+c1) (z=1) ----
__global__ __launch_bounds__(256) void k1_gemm(
    const float* __restrict__ A,
    const float* __restrict__ W1, const float* __restrict__ b1,
    const float* __restrict__ V1, const float* __restrict__ c1,
    float* __restrict__ hout, float* __restrict__ v1out)
{
  const float* W    = (blockIdx.z == 0) ? W1 : V1;
  const float* bias = (blockIdx.z == 0) ? b1 : c1;
  float* out        = (blockIdx.z == 0) ? hout : v1out;

  __shared__ float as[16][68];
  __shared__ float bs[16][64];

  int tid = threadIdx.x;
  int tx = tid & 15, ty = tid >> 4;
  int rb = blockIdx.y * 64, cb = blockIdx.x * 64;

  float acc[4][4] = {};

  for (int k0 = 0; k0 < S_; k0 += 16) {
    {
      int r = tid >> 2, k4 = (tid & 3) << 2;
      float4 a = *(const float4*)&A[(size_t)(rb + r) * S_ + k0 + k4];
      as[k4 + 0][r] = a.x; as[k4 + 1][r] = a.y;
      as[k4 + 2][r] = a.z; as[k4 + 3][r] = a.w;
    }
    {
      int kk = tid >> 4, c4 = (tid & 15) << 2;
      *(float4*)&bs[kk][c4] = *(const float4*)&W[(size_t)(k0 + kk) * H_ + cb + c4];
    }
    __syncthreads();
#pragma unroll
    for (int kk = 0; kk < 16; ++kk) {
      float4 a4 = *(const float4*)&as[kk][ty << 2];
      float4 b4 = *(const float4*)&bs[kk][tx << 2];
      float av[4] = {a4.x, a4.y, a4.z, a4.w};
      float bv[4] = {b4.x, b4.y, b4.z, b4.w};
#pragma unroll
      for (int i = 0; i < 4; ++i)
#pragma unroll
        for (int j = 0; j < 4; ++j)
          acc[i][j] = fmaf(av[i], bv[j], acc[i][j]);
    }
    __syncthreads();
  }

#pragma unroll
  for (int i = 0; i < 4; ++i) {
    int r = rb + (ty << 2) + i;
#pragma unroll
    for (int j = 0; j < 4; ++j) {
      int c = cb + (tx << 2) + j;
      float v = acc[i][j] + bias[c];
      out[(size_t)r * H_ + c] = v > 0.0f ? v : 0.0f;
    }
  }
}

// ---------------- K2: mode 0: q = LN(h@W2+b2) -> qrow(f32), qext2(bf16 of -2q), q2
//                      mode 1: v2 = relu(v1@V2+c2); net = v2@V3 + c3 ------------------
__global__ __launch_bounds__(256) void k2_fused(
    int mode,
    const float* __restrict__ A,      // [B_][H_]
    const float* __restrict__ W,      // [H_][D_]
    const float* __restrict__ bias,   // [D_]
    const float* __restrict__ lng, const float* __restrict__ lnb,
    const float* __restrict__ V3, const float* __restrict__ c3,
    ushort* __restrict__ qext2, float* __restrict__ qrow,
    float* __restrict__ q2out, float* __restrict__ netout)
{
  __shared__ float as[32][36];
  __shared__ float bs[32][132];
  __shared__ float yt[32][132];
  __shared__ float v3s[128];

  int tid = threadIdx.x;
  int tx = tid & 31, ty = tid >> 5;
  int rb = blockIdx.x * 32;

  if (mode == 1 && tid < 128) v3s[tid] = V3[tid];

  float acc[4][4] = {};

  for (int k0 = 0; k0 < H_; k0 += 32) {
    {
      int r = tid >> 3, k4 = (tid & 7) << 2;
      float4 a = *(const float4*)&A[(size_t)(rb + r) * H_ + k0 + k4];
      as[k4 + 0][r] = a.x; as[k4 + 1][r] = a.y;
      as[k4 + 2][r] = a.z; as[k4 + 3][r] = a.w;
    }
    {
      int kk = tid >> 3, c16 = (tid & 7) << 4;
#pragma unroll
      for (int t = 0; t < 4; ++t)
        *(float4*)&bs[kk][c16 + (t << 2)] =
            *(const float4*)&W[(size_t)(k0 + kk) * D_ + c16 + (t << 2)];
    }
    __syncthreads();
#pragma unroll
    for (int kk = 0; kk < 32; ++kk) {
      float4 a4 = *(const float4*)&as[kk][ty << 2];
      float4 b4 = *(const float4*)&bs[kk][tx << 2];
      float av[4] = {a4.x, a4.y, a4.z, a4.w};
      float bv[4] = {b4.x, b4.y, b4.z, b4.w};
#pragma unroll
      for (int i = 0; i < 4; ++i)
#pragma unroll
        for (int j = 0; j < 4; ++j)
          acc[i][j] = fmaf(av[i], bv[j], acc[i][j]);
    }
    __syncthreads();
  }

#pragma unroll
  for (int i = 0; i < 4; ++i)
#pragma unroll
    for (int j = 0; j < 4; ++j) {
      int c = (tx << 2) + j;
      yt[(ty << 2) + i][c] = acc[i][j] + bias[c];
    }
  __syncthreads();

  int r8 = tid >> 3, j8 = tid & 7;
  int rg = rb + r8;
  if (mode == 0) {
    float s = 0.f;
#pragma unroll
    for (int t = 0; t < 16; ++t) s += yt[r8][(j8 << 4) + t];
    s += __shfl_xor(s, 1); s += __shfl_xor(s, 2); s += __shfl_xor(s, 4);
    float mu = s * (1.0f / 128.0f);
    float vs = 0.f;
#pragma unroll
    for (int t = 0; t < 16; ++t) {
      float d = yt[r8][(j8 << 4) + t] - mu;
      vs = fmaf(d, d, vs);
    }
    vs += __shfl_xor(vs, 1); vs += __shfl_xor(vs, 2); vs += __shfl_xor(vs, 4);
    float var = vs * (1.0f / 128.0f);
    float rstd = 1.0f / sqrtf(var + 1e-5f);
    float q2p = 0.f;
    ushort* qe = qext2 + (size_t)rg * 128;
#pragma unroll
    for (int t = 0; t < 16; ++t) {
      int c = (j8 << 4) + t;
      float qv = (yt[r8][c] - mu) * rstd * lng[c] + lnb[c];
      qrow[(size_t)rg * D_ + c] = qv;
      qe[c] = (ushort)bf16_rne(-2.0f * qv);
      q2p = fmaf(qv, qv, q2p);
    }
    q2p += __shfl_xor(q2p, 1); q2p += __shfl_xor(q2p, 2); q2p += __shfl_xor(q2p, 4);
    if (j8 == 0) q2out[rg] = q2p;
  } else {
    float s = 0.f;
#pragma unroll
    for (int t = 0; t < 16; ++t) {
      int c = (j8 << 4) + t;
      float v = yt[r8][c];
      v = v > 0.f ? v : 0.f;
      s = fmaf(v, v3s[c], s);
    }
    s += __shfl_xor(s, 1); s += __shfl_xor(s, 2); s += __shfl_xor(s, 4);
    if (j8 == 0) netout[rg] = s + c3[0];
  }
}

// ---------------- K5: build kslice-major key image + exact k2 norms -------------------
__global__ __launch_bounds__(256) void k5_keyimg(
    const float* __restrict__ keys, u32* __restrict__ keyimg,
    float* __restrict__ k2out)
{
  int tid = threadIdx.x;
  int p = blockIdx.x * 128 + (tid >> 1);   // padded key index
  int sub = tid & 1;
  int slice = p / SL_PAD;
  int within = p - slice * SL_PAD;
  int kb = within >> 6, kib = within & 63;
  u32* img = keyimg + (size_t)(slice * NB + kb) * IMG_U32;
  bool real = within < SL_REAL;

  u32 w[32];
  float ss = 0.f;
  if (real) {
    const float* kp = keys + (size_t)(slice * SL_REAL + within) * D_ + sub * 64;
#pragma unroll
    for (int i = 0; i < 16; ++i) {
      float4 x = *(const float4*)(kp + i * 4);
      ss = fmaf(x.x, x.x, fmaf(x.y, x.y, fmaf(x.z, x.z, fmaf(x.w, x.w, ss))));
      w[i * 2]     = bf16_rne(x.x) | (bf16_rne(x.y) << 16);
      w[i * 2 + 1] = bf16_rne(x.z) | (bf16_rne(x.w) << 16);
    }
  } else {
#pragma unroll
    for (int i = 0; i < 32; ++i) w[i] = 0;
  }
#pragma unroll
  for (int cc = 0; cc < 2; ++cc) {
    int c = sub * 2 + cc;
#pragma unroll
    for (int j = 0; j < 4; ++j) {
      u32x4 v = {w[cc*16 + j*4], w[cc*16 + j*4 + 1], w[cc*16 + j*4 + 2], w[cc*16 + j*4 + 3]};
      *(u32x4*)&img[c * 1024 + j * 256 + kib * 4] = v;
    }
  }
  float tot = ss + __shfl_xor(ss, 1);
  if (sub == 0) {
    u32 w0;
    if (real) {
      k2out[slice * SL_REAL + within] = tot;
      u32 h = bf16_rne(tot);
      float hf = __uint_as_float(h << 16);
      u32 lo = bf16_rne(tot - hf);
      w0 = h | (lo << 16);
    } else {
      w0 = 0x7FC07FC0u;   // NaN,NaN -> dd = NaN -> never selected
    }
    u32x4 v0 = {w0, 0, 0, 0};
    u32x4 z  = {0, 0, 0, 0};
    *(u32x4*)&img[4 * 1024 + 0 * 256 + kib * 4] = v0;
    *(u32x4*)&img[4 * 1024 + 1 * 256 + kib * 4] = z;
    *(u32x4*)&img[4 * 1024 + 2 * 256 + kib * 4] = z;
    *(u32x4*)&img[4 * 1024 + 3 * 256 + kib * 4] = z;
  }
}

// ---------------- K3 helpers ----------------------------------------------------------
__device__ __forceinline__ void sort128_wave(u32* sb, int lane) {
  for (int k = 2; k <= 128; k <<= 1)
    for (int j = k >> 1; j > 0; j >>= 1) {
#pragma unroll
      for (int half = 0; half < 2; ++half) {
        int e = lane + (half << 6);
        int pp = e ^ j;
        if (pp > e) {
          u32 x = sb[e], y = sb[pp];
          bool up = ((e & k) == 0);
          if ((x > y) == up) { sb[e] = y; sb[pp] = x; }
        }
      }
      __builtin_amdgcn_wave_barrier();
    }
}

// 8 waves x 8 rows
__device__ void compact_block(
    bool final_, int rb, int slice, int tid,
    u32 (*sortbuf)[128], float* threshL, int* cnt, u32* lbuf)
{
  int w = tid >> 6, lane = tid & 63;
  for (int rr = 0; rr < 8; ++rr) {
    int r = (w << 3) | rr;
    int c0 = cnt[r];
    if (!final_ && c0 <= CAP) continue;
    int valid = c0 < CAP ? c0 : CAP;
    u32* gb = &lbuf[(((size_t)(rb + r)) * NSLICE + slice) * CAP];
    u32 e0 = (lane < valid) ? gb[lane] : 0xFFFFFFFFu;
    u32 e1 = (lane + 64 < valid) ? gb[lane + 64] : 0xFFFFFFFFu;
    u32* sb = sortbuf[w];
    sb[lane] = e0; sb[lane + 64] = e1;
    __builtin_amdgcn_wave_barrier();
    sort128_wave(sb, lane);
    __builtin_amdgcn_wave_barrier();
    if (lane < KNN) gb[lane] = sb[lane];
    if (lane == 0) { cnt[r] = KNN; threshL[r] = __uint_as_float(sb[KNN - 1]); }
    __builtin_amdgcn_wave_barrier();
  }
}

// ---------------- K3: K=160 bf16 MFMA distance GEMM + approx top-50 -------------------
__global__ __launch_bounds__(512, 4) void k3_knn(
    const ushort* __restrict__ qext2,  // [B][128] bf16 of (-2q)
    const float* __restrict__ q2g,
    const u32* __restrict__ keyimg,    // kslice-major images
    u32* __restrict__ lbuf)
{
  __shared__ u32 kbuf[2][IMG_U32];     // 2 x 20KB
  __shared__ u32 sortbuf[8][128];      // 4KB
  __shared__ float threshL[64];
  __shared__ int cnt[64];
  __shared__ int ovf[2];

  int tid = threadIdx.x;
  int l = tid & 63, w = tid >> 6;
  int l15 = l & 15, l4 = l >> 4;
  int wr = w & 3, wc = w >> 2;         // wr: key quarter, wc: row half
  int slice = blockIdx.x & 7;          // consecutive blocks -> different XCDs
  int rb = (blockIdx.x >> 3) << 6;     // 64 q rows per block

  if (tid < 64) { threshL[tid] = __uint_as_float(0x7F800000u); cnt[tid] = 0; }
  if (tid == 0) { ovf[0] = 0; ovf[1] = 0; }

  bf16x8 bfr[4][2];
#pragma unroll
  for (int c = 0; c < 4; ++c)
#pragma unroll
    for (int qf = 0; qf < 2; ++qf) {
      const ushort* qp = qext2 + (size_t)(rb + wc * 32 + qf * 16 + l15) * 128 + c * 32 + l4 * 8;
      bfr[c][qf] = __builtin_bit_cast(bf16x8, *(const u32x4*)qp);
    }
  bf16x8 bk2;
  {
    u16x8 v = {0, 0, 0, 0, 0, 0, 0, 0};
    if (l4 == 0) { v[0] = 0x3F80; v[1] = 0x3F80; }
    bk2 = __builtin_bit_cast(bf16x8, v);
  }
  float q2v[2];
#pragma unroll
  for (int qf = 0; qf < 2; ++qf) q2v[qf] = q2g[rb + wc * 32 + qf * 16 + l15];

  const u32* imgbase = keyimg + (size_t)slice * NB * IMG_U32;

  auto stage = [&](int b, int t) {
    if (w < 5) {
      const u32* src = imgbase + (size_t)t * IMG_U32 + w * 1024 + l * 4;
      u32* dst = &kbuf[b][w * 1024];
#pragma unroll
      for (int i = 0; i < 4; ++i)
        gl_lds16(src + i * 256, dst + i * 256);
    }
  };

  stage(0, 0);
  __syncthreads();

  int cur = 0;
  for (int t = 0; t < NB; ++t) {
    if (t + 1 < NB) stage(cur ^ 1, t + 1);

    f32x4 acc[2] = {};
    __builtin_amdgcn_s_setprio(1);
#pragma unroll
    for (int c = 0; c < 5; ++c) {
      bf16x8 a = __builtin_bit_cast(bf16x8,
          *(const u32x4*)&kbuf[cur][c * 1024 + l4 * 256 + (wr * 16 + l15) * 4]);
      acc[0] = __builtin_amdgcn_mfma_f32_16x16x32_bf16(a, (c < 4) ? bfr[c][0] : bk2, acc[0], 0, 0, 0);
      acc[1] = __builtin_amdgcn_mfma_f32_16x16x32_bf16(a, (c < 4) ? bfr[c][1] : bk2, acc[1], 0, 0, 0);
    }
    __builtin_amdgcn_s_setprio(0);

    float ddv[2][4];
    float thF[2];
    thF[0] = threshL[wc * 32 + l15];
    thF[1] = threshL[wc * 32 + 16 + l15];
    u32 pend = 0;
#pragma unroll
    for (int qf = 0; qf < 2; ++qf)
#pragma unroll
      for (int r = 0; r < 4; ++r) {
        float dd = q2v[qf] + acc[qf][r];
        ddv[qf][r] = dd;
        if (dd < thF[qf]) pend |= 1u << ((qf << 2) | r);
      }

    if (__any(pend != 0)) {
#pragma unroll
      for (int qf = 0; qf < 2; ++qf) {
        int row = wc * 32 + qf * 16 + l15;
#pragma unroll
        for (int r = 0; r < 4; ++r) {
          u32 bit = 1u << ((qf << 2) | r);
          if (pend & bit) {
            int pos = atomicAdd(&cnt[row], 1);
            if (pos < CAP) {
              int kl = t * BKEY + wr * 16 + (l4 << 2) + r;
              lbuf[(((size_t)(rb + row)) * NSLICE + slice) * CAP + pos] =
                  (__float_as_uint(ddv[qf][r]) & 0xFFFFE000u) | (u32)kl;
              pend &= ~bit;
            } else ovf[cur] = 1;    // benign race
          }
        }
      }
    }

    __syncthreads();               // stage drained, kbuf[cur] free, ovf visible

    if (ovf[cur]) {                // rare path
      do {
        compact_block(false, rb, slice, tid, sortbuf, threshL, cnt, lbuf);
        if (tid == 0) ovf[cur] = 0;
        __syncthreads();
        thF[0] = threshL[wc * 32 + l15];
        thF[1] = threshL[wc * 32 + 16 + l15];
        if (pend) {
#pragma unroll
          for (int qf = 0; qf < 2; ++qf) {
            int row = wc * 32 + qf * 16 + l15;
#pragma unroll
            for (int r = 0; r < 4; ++r) {
              u32 bit = 1u << ((qf << 2) | r);
              if (pend & bit) {
                if (ddv[qf][r] < thF[qf]) {
                  int pos = atomicAdd(&cnt[row], 1);
                  if (pos < CAP) {
                    int kl = t * BKEY + wr * 16 + (l4 << 2) + r;
                    lbuf[(((size_t)(rb + row)) * NSLICE + slice) * CAP + pos] =
                        (__float_as_uint(ddv[qf][r]) & 0xFFFFE000u) | (u32)kl;
                    pend &= ~bit;
                  } else ovf[cur] = 1;
                } else pend &= ~bit;
              }
            }
          }
        }
        __syncthreads();
      } while (ovf[cur]);
    }
    cur ^= 1;
  }

  compact_block(true, rb, slice, tid, sortbuf, threshL, cnt, lbuf);
}

// ---------------- PROBE P1: GEMM skeleton (stage + ds_read + MFMA + barrier) ----------
__global__ __launch_bounds__(512, 4) void k3p_gemm(
    const ushort* __restrict__ qext2, const float* __restrict__ q2g,
    const u32* __restrict__ keyimg, float* __restrict__ probe)
{
  __shared__ u32 kbuf[2][IMG_U32];

  int tid = threadIdx.x;
  int l = tid & 63, w = tid >> 6;
  int l15 = l & 15, l4 = l >> 4;
  int wr = w & 3, wc = w >> 2;
  int slice = blockIdx.x & 7;
  int rb = (blockIdx.x >> 3) << 6;

  bf16x8 bfr[4][2];
#pragma unroll
  for (int c = 0; c < 4; ++c)
#pragma unroll
    for (int qf = 0; qf < 2; ++qf) {
      const ushort* qp = qext2 + (size_t)(rb + wc * 32 + qf * 16 + l15) * 128 + c * 32 + l4 * 8;
      bfr[c][qf] = __builtin_bit_cast(bf16x8, *(const u32x4*)qp);
    }
  bf16x8 bk2;
  {
    u16x8 v = {0, 0, 0, 0, 0, 0, 0, 0};
    if (l4 == 0) { v[0] = 0x3F80; v[1] = 0x3F80; }
    bk2 = __builtin_bit_cast(bf16x8, v);
  }
  float q2v[2];
#pragma unroll
  for (int qf = 0; qf < 2; ++qf) q2v[qf] = q2g[rb + wc * 32 + qf * 16 + l15];

  const u32* imgbase = keyimg + (size_t)slice * NB * IMG_U32;
  auto stage = [&](int b, int t) {
    if (w < 5) {
      const u32* src = imgbase + (size_t)t * IMG_U32 + w * 1024 + l * 4;
      u32* dst = &kbuf[b][w * 1024];
#pragma unroll
      for (int i = 0; i < 4; ++i)
        gl_lds16(src + i * 256, dst + i * 256);
    }
  };

  stage(0, 0);
  __syncthreads();

  float dmin[2] = {3.4e38f, 3.4e38f};
  int cur = 0;
  for (int t = 0; t < PROBE_TILES; ++t) {
    if (t + 1 < PROBE_TILES) stage(cur ^ 1, t + 1);

    f32x4 acc[2] = {};
#pragma unroll
    for (int c = 0; c < 5; ++c) {
      bf16x8 a = __builtin_bit_cast(bf16x8,
          *(const u32x4*)&kbuf[cur][c * 1024 + l4 * 256 + (wr * 16 + l15) * 4]);
      acc[0] = __builtin_amdgcn_mfma_f32_16x16x32_bf16(a, (c < 4) ? bfr[c][0] : bk2, acc[0], 0, 0, 0);
      acc[1] = __builtin_amdgcn_mfma_f32_16x16x32_bf16(a, (c < 4) ? bfr[c][1] : bk2, acc[1], 0, 0, 0);
    }
#pragma unroll
    for (int qf = 0; qf < 2; ++qf)
#pragma unroll
      for (int r = 0; r < 4; ++r)
        dmin[qf] = fminf(dmin[qf], q2v[qf] + acc[qf][r]);

    __syncthreads();
    cur ^= 1;
  }
  probe[((size_t)blockIdx.x * 512 + tid) * 2 + 0] = dmin[0];
  probe[((size_t)blockIdx.x * 512 + tid) * 2 + 1] = dmin[1];
}

// ---------------- PROBE P2: stage + barrier only --------------------------------------
__global__ __launch_bounds__(512, 4) void k3p_stage(
    const u32* __restrict__ keyimg, u32* __restrict__ probe)
{
  __shared__ u32 kbuf[2][IMG_U32];
  int tid = threadIdx.x;
  int l = tid & 63, w = tid >> 6;
  int slice = blockIdx.x & 7;

  const u32* imgbase = keyimg + (size_t)slice * NB * IMG_U32;
  auto stage = [&](int b, int t) {
    if (w < 5) {
      const u32* src = imgbase + (size_t)t * IMG_U32 + w * 1024 + l * 4;
      u32* dst = &kbuf[b][w * 1024];
#pragma unroll
      for (int i = 0; i < 4; ++i)
        gl_lds16(src + i * 256, dst + i * 256);
    }
  };

  stage(0, 0);
  __syncthreads();

  u32 accu = 0;
  int cur = 0;
  for (int t = 0; t < PROBE_TILES; ++t) {
    if (t + 1 < PROBE_TILES) stage(cur ^ 1, t + 1);
    u32x4 v = *(const u32x4*)&kbuf[cur][(tid * 4) & (IMG_U32 - 1)];
    accu ^= v[0] ^ v[1] ^ v[2] ^ v[3];
    __syncthreads();
    cur ^= 1;
  }
  probe[(size_t)blockIdx.x * 512 + tid] = accu;
}

// ---------------- K4: merge 8x50 -> approx top-64 -> exact fp32 rerank -> output ------
__global__ __launch_bounds__(256) void k4_rerank(
    const u32* __restrict__ lbuf, const float* __restrict__ qrow,
    const float* __restrict__ q2g, const float* __restrict__ k2g,
    const float* __restrict__ keys, const float* __restrict__ memv,
    const float* __restrict__ net, float* __restrict__ out)
{
  __shared__ u64 sb[512];
  __shared__ float qs[128];
  __shared__ float part[4][RR];
  __shared__ u64 cand[RR];
  int b = blockIdx.x, t = threadIdx.x;
  if (t < 128) qs[t] = qrow[(size_t)b * D_ + t];
#pragma unroll
  for (int h = 0; h < 2; ++h) {
    int e = t + (h << 8);
    u64 v = ~0ull;
    if (e < NSLICE * KNN) {
      int s = e / KNN, j = e - s * KNN;
      u32 k32 = lbuf[((size_t)b * NSLICE + s) * CAP + j];
      v = ((u64)(k32 & 0xFFFFE000u) << 32) | (u32)(s * SL_REAL + (k32 & 0x1FFFu));
    }
    sb[e] = v;
  }
  __syncthreads();
  for (int k = 2; k <= 512; k <<= 1)
    for (int j = k >> 1; j > 0; j >>= 1) {
#pragma unroll
      for (int h = 0; h < 2; ++h) {
        int e = t + (h << 8);
        int p = e ^ j;
        if (p > e) {
          u64 x = sb[e], y = sb[p];
          bool up = ((e & k) == 0);
          if ((x > y) == up) { sb[e] = y; sb[p] = x; }
        }
      }
      __syncthreads();
    }

  int cid = t & 63, g = t >> 6;
  u32 gidx = (u32)sb[cid];
  const float* kp = keys + (size_t)gidx * D_ + g * 32;
  float dot = 0.f;
#pragma unroll
  for (int i = 0; i < 8; ++i) {
    float4 kv = *(const float4*)(kp + i * 4);
    float4 qv = *(const float4*)&qs[g * 32 + i * 4];
    dot = fmaf(kv.x, qv.x, dot); dot = fmaf(kv.y, qv.y, dot);
    dot = fmaf(kv.z, qv.z, dot); dot = fmaf(kv.w, qv.w, dot);
  }
  part[g][cid] = dot;
  __syncthreads();
  if (t < RR) {
    float dotf = part[0][t] + part[1][t] + part[2][t] + part[3][t];
    u32 gi = (u32)sb[t];
    float dd = q2g[b] + k2g[gi] - 2.0f * dotf;
    cand[t] = ((u64)__float_as_uint(dd) << 32) | gi;
  }
  __syncthreads();
  if (t < 64) {
    for (int k = 2; k <= 64; k <<= 1)
      for (int j = k >> 1; j > 0; j >>= 1) {
        u64 x = cand[t], y = cand[t ^ j];
        __builtin_amdgcn_wave_barrier();
        bool up = ((t & k) == 0);
        u64 mn = x < y ? x : y, mx = x < y ? y : x;
        cand[t] = ((t < (t ^ j)) == up) ? mn : mx;
        __builtin_amdgcn_wave_barrier();
      }
    u64 key = cand[t];
    float d = __uint_as_float((u32)(key >> 32));
    u32 idx = (u32)key;
    float w = 0.f, wv = 0.f;
    if (t < KNN) {
      float ww = 1.0f / (d + 1e-7f);
      w = ww;
      wv = ww * memv[idx];
    }
#pragma unroll
    for (int o = 1; o < 64; o <<= 1) {
      w += __shfl_xor(w, o);
      wv += __shfl_xor(wv, o);
    }
    if (t == 0) out[b] = 0.9f * (wv / w) + 0.1f * net[b];
  }
}

// ---------------- launch --------------------------------------------------------------
extern "C" void kernel_launch(void* const* d_in, const int* in_sizes, int n_in,
                              void* d_out, int out_size, void* d_ws, size_t ws_size,
                              hipStream_t stream)
{
  const float* states     = (const float*)d_in[0];
  const float* W1         = (const float*)d_in[1];
  const float* b1         = (const float*)d_in[2];
  const float* W2         = (const float*)d_in[3];
  const float* b2         = (const float*)d_in[4];
  const float* lng        = (const float*)d_in[5];
  const float* lnb        = (const float*)d_in[6];
  const float* mem_keys   = (const float*)d_in[7];
  const float* mem_values = (const float*)d_in[8];
  const float* V1         = (const float*)d_in[9];
  const float* c1         = (const float*)d_in[10];
  const float* V2         = (const float*)d_in[11];
  const float* c2         = (const float*)d_in[12];
  const float* V3         = (const float*)d_in[13];
  const float* c3         = (const float*)d_in[14];
  float* out = (float*)d_out;

  char* ws = (char*)d_ws;
  ushort* qext2 = (ushort*)(ws + 0);          // 1 MB
  float*  qrow  = (float*)(ws + 1048576);     // 2 MB
  float*  q2    = (float*)(ws + 3145728);     // 16 KB
  float*  net   = (float*)(ws + 3162112);     // 16 KB
  float*  k2g   = (float*)(ws + 3178496);     // 200 KB (ends 3383296)
  u32*  keyimg  = (u32*)(ws + 3383296);       // 16.06 MB (ends 19,439,616)
  u32*  lbuf    = (u32*)(ws + 19439616);      // 16.78 MB (ends 36,216,832)
  float* probe  = (float*)(ws + 36216832);    // 2.25 MB probe scratch (ends ~38.6 MB)
  float* h  = (float*)(ws + 3383296);             // overlays keyimg (dead before k5)
  float* v1 = (float*)(ws + 3383296 + 4194304);

  k1_gemm<<<dim3(H_ / 64, B_ / 64, 2), 256, 0, stream>>>(states, W1, b1, V1, c1, h, v1);
  k2_fused<<<dim3(B_ / 32), 256, 0, stream>>>(0, h, W2, b2, lng, lnb, V3, c3, qext2, qrow, q2, net);
  k2_fused<<<dim3(B_ / 32), 256, 0, stream>>>(1, v1, V2, c2, lng, lnb, V3, c3, qext2, qrow, q2, net);
  k5_keyimg<<<dim3(NSLICE * SL_PAD / 128), 256, 0, stream>>>(mem_keys, keyimg, k2g);
  // diagnostic probes (write only probe scratch; deterministic)
  k3p_stage<<<dim3((B_ / 64) * NSLICE), 512, 0, stream>>>(keyimg, (u32*)probe);
  k3p_gemm<<<dim3((B_ / 64) * NSLICE), 512, 0, stream>>>(qext2, q2, keyimg, probe);
  k3_knn<<<dim3((B_ / 64) * NSLICE), 512, 0, stream>>>(qext2, q2, keyimg, lbuf);
  k4_rerank<<<dim3(B_), 256, 0, stream>>>(lbuf, qrow, q2, k2g, mem_keys, mem_values, net, out);
}

// Round 10
// 869.496 us; speedup vs baseline: 1.0388x; 1.0388x over previous
//
#include <hip/hip_runtime.h>
#include <stdint.h>

#define B_   4096
#define S_   544
#define H_   256
#define D_   128
#define M_   50000
#define KNN  50
#define NSLICE 8
#define SL_REAL 6250
#define BKEY 64
#define NB   98                  // 64-key tiles per slice
#define SL_PAD (NB * BKEY)       // 6272
#define CAP  128
#define RR   64
#define IMG_U32 5120             // 5 chunks * 4 kslices * 64 keys * 4 u32 = 20KB
#define QT   24                  // per-lane queue depth

typedef unsigned long long u64;
typedef unsigned int u32;
typedef __attribute__((ext_vector_type(8))) __bf16 bf16x8;
typedef __attribute__((ext_vector_type(8))) unsigned short u16x8;
typedef __attribute__((ext_vector_type(4))) float f32x4;
typedef __attribute__((ext_vector_type(4))) u32 u32x4;

__device__ __forceinline__ u32 bf16_rne(float x) {
  u32 u = __float_as_uint(x);
  return (u + 0x7FFFu + ((u >> 16) & 1u)) >> 16;
}

__device__ __forceinline__ void gl_lds16(const u32* g, u32* l) {
  __builtin_amdgcn_global_load_lds(
      (const __attribute__((address_space(1))) u32*)g,
      (__attribute__((address_space(3))) u32*)l, 16, 0, 0);
}

// ---------------- K1: h = relu(states@W1+b1) (z=0), v1 = relu(states@V1+c1) (z=1) ----
__global__ __launch_bounds__(256) void k1_gemm(
    const float* __restrict__ A,
    const float* __restrict__ W1, const float* __restrict__ b1,
    const float* __restrict__ V1, const float* __restrict__ c1,
    float* __restrict__ hout, float* __restrict__ v1out)
{
  const float* W    = (blockIdx.z == 0) ? W1 : V1;
  const float* bias = (blockIdx.z == 0) ? b1 : c1;
  float* out        = (blockIdx.z == 0) ? hout : v1out;

  __shared__ float as[16][68];
  __shared__ float bs[16][64];

  int tid = threadIdx.x;
  int tx = tid & 15, ty = tid >> 4;
  int rb = blockIdx.y * 64, cb = blockIdx.x * 64;

  float acc[4][4] = {};

  for (int k0 = 0; k0 < S_; k0 += 16) {
    {
      int r = tid >> 2, k4 = (tid & 3) << 2;
      float4 a = *(const float4*)&A[(size_t)(rb + r) * S_ + k0 + k4];
      as[k4 + 0][r] = a.x; as[k4 + 1][r] = a.y;
      as[k4 + 2][r] = a.z; as[k4 + 3][r] = a.w;
    }
    {
      int kk = tid >> 4, c4 = (tid & 15) << 2;
      *(float4*)&bs[kk][c4] = *(const float4*)&W[(size_t)(k0 + kk) * H_ + cb + c4];
    }
    __syncthreads();
#pragma unroll
    for (int kk = 0; kk < 16; ++kk) {
      float4 a4 = *(const float4*)&as[kk][ty << 2];
      float4 b4 = *(const float4*)&bs[kk][tx << 2];
      float av[4] = {a4.x, a4.y, a4.z, a4.w};
      float bv[4] = {b4.x, b4.y, b4.z, b4.w};
#pragma unroll
      for (int i = 0; i < 4; ++i)
#pragma unroll
        for (int j = 0; j < 4; ++j)
          acc[i][j] = fmaf(av[i], bv[j], acc[i][j]);
    }
    __syncthreads();
  }

#pragma unroll
  for (int i = 0; i < 4; ++i) {
    int r = rb + (ty << 2) + i;
#pragma unroll
    for (int j = 0; j < 4; ++j) {
      int c = cb + (tx << 2) + j;
      float v = acc[i][j] + bias[c];
      out[(size_t)r * H_ + c] = v > 0.0f ? v : 0.0f;
    }
  }
}

// ---------------- K2: mode 0: q = LN(h@W2+b2) -> qrow(f32), qext2(bf16 of -2q), q2
//                      mode 1: v2 = relu(v1@V2+c2); net = v2@V3 + c3 ------------------
__global__ __launch_bounds__(256) void k2_fused(
    int mode,
    const float* __restrict__ A,      // [B_][H_]
    const float* __restrict__ W,      // [H_][D_]
    const float* __restrict__ bias,   // [D_]
    const float* __restrict__ lng, const float* __restrict__ lnb,
    const float* __restrict__ V3, const float* __restrict__ c3,
    ushort* __restrict__ qext2, float* __restrict__ qrow,
    float* __restrict__ q2out, float* __restrict__ netout)
{
  __shared__ float as[32][36];
  __shared__ float bs[32][132];
  __shared__ float yt[32][132];
  __shared__ float v3s[128];

  int tid = threadIdx.x;
  int tx = tid & 31, ty = tid >> 5;
  int rb = blockIdx.x * 32;

  if (mode == 1 && tid < 128) v3s[tid] = V3[tid];

  float acc[4][4] = {};

  for (int k0 = 0; k0 < H_; k0 += 32) {
    {
      int r = tid >> 3, k4 = (tid & 7) << 2;
      float4 a = *(const float4*)&A[(size_t)(rb + r) * H_ + k0 + k4];
      as[k4 + 0][r] = a.x; as[k4 + 1][r] = a.y;
      as[k4 + 2][r] = a.z; as[k4 + 3][r] = a.w;
    }
    {
      int kk = tid >> 3, c16 = (tid & 7) << 4;
#pragma unroll
      for (int t = 0; t < 4; ++t)
        *(float4*)&bs[kk][c16 + (t << 2)] =
            *(const float4*)&W[(size_t)(k0 + kk) * D_ + c16 + (t << 2)];
    }
    __syncthreads();
#pragma unroll
    for (int kk = 0; kk < 32; ++kk) {
      float4 a4 = *(const float4*)&as[kk][ty << 2];
      float4 b4 = *(const float4*)&bs[kk][tx << 2];
      float av[4] = {a4.x, a4.y, a4.z, a4.w};
      float bv[4] = {b4.x, b4.y, b4.z, b4.w};
#pragma unroll
      for (int i = 0; i < 4; ++i)
#pragma unroll
        for (int j = 0; j < 4; ++j)
          acc[i][j] = fmaf(av[i], bv[j], acc[i][j]);
    }
    __syncthreads();
  }

#pragma unroll
  for (int i = 0; i < 4; ++i)
#pragma unroll
    for (int j = 0; j < 4; ++j) {
      int c = (tx << 2) + j;
      yt[(ty << 2) + i][c] = acc[i][j] + bias[c];
    }
  __syncthreads();

  int r8 = tid >> 3, j8 = tid & 7;
  int rg = rb + r8;
  if (mode == 0) {
    float s = 0.f;
#pragma unroll
    for (int t = 0; t < 16; ++t) s += yt[r8][(j8 << 4) + t];
    s += __shfl_xor(s, 1); s += __shfl_xor(s, 2); s += __shfl_xor(s, 4);
    float mu = s * (1.0f / 128.0f);
    float vs = 0.f;
#pragma unroll
    for (int t = 0; t < 16; ++t) {
      float d = yt[r8][(j8 << 4) + t] - mu;
      vs = fmaf(d, d, vs);
    }
    vs += __shfl_xor(vs, 1); vs += __shfl_xor(vs, 2); vs += __shfl_xor(vs, 4);
    float var = vs * (1.0f / 128.0f);
    float rstd = 1.0f / sqrtf(var + 1e-5f);
    float q2p = 0.f;
    ushort* qe = qext2 + (size_t)rg * 128;
#pragma unroll
    for (int t = 0; t < 16; ++t) {
      int c = (j8 << 4) + t;
      float qv = (yt[r8][c] - mu) * rstd * lng[c] + lnb[c];
      qrow[(size_t)rg * D_ + c] = qv;
      qe[c] = (ushort)bf16_rne(-2.0f * qv);
      q2p = fmaf(qv, qv, q2p);
    }
    q2p += __shfl_xor(q2p, 1); q2p += __shfl_xor(q2p, 2); q2p += __shfl_xor(q2p, 4);
    if (j8 == 0) q2out[rg] = q2p;
  } else {
    float s = 0.f;
#pragma unroll
    for (int t = 0; t < 16; ++t) {
      int c = (j8 << 4) + t;
      float v = yt[r8][c];
      v = v > 0.f ? v : 0.f;
      s = fmaf(v, v3s[c], s);
    }
    s += __shfl_xor(s, 1); s += __shfl_xor(s, 2); s += __shfl_xor(s, 4);
    if (j8 == 0) netout[rg] = s + c3[0];
  }
}

// ---------------- K5: build kslice-major key image + exact k2 norms -------------------
__global__ __launch_bounds__(256) void k5_keyimg(
    const float* __restrict__ keys, u32* __restrict__ keyimg,
    float* __restrict__ k2out)
{
  int tid = threadIdx.x;
  int p = blockIdx.x * 128 + (tid >> 1);   // padded key index
  int sub = tid & 1;
  int slice = p / SL_PAD;
  int within = p - slice * SL_PAD;
  int kb = within >> 6, kib = within & 63;
  u32* img = keyimg + (size_t)(slice * NB + kb) * IMG_U32;
  bool real = within < SL_REAL;

  u32 w[32];
  float ss = 0.f;
  if (real) {
    const float* kp = keys + (size_t)(slice * SL_REAL + within) * D_ + sub * 64;
#pragma unroll
    for (int i = 0; i < 16; ++i) {
      float4 x = *(const float4*)(kp + i * 4);
      ss = fmaf(x.x, x.x, fmaf(x.y, x.y, fmaf(x.z, x.z, fmaf(x.w, x.w, ss))));
      w[i * 2]     = bf16_rne(x.x) | (bf16_rne(x.y) << 16);
      w[i * 2 + 1] = bf16_rne(x.z) | (bf16_rne(x.w) << 16);
    }
  } else {
#pragma unroll
    for (int i = 0; i < 32; ++i) w[i] = 0;
  }
#pragma unroll
  for (int cc = 0; cc < 2; ++cc) {
    int c = sub * 2 + cc;
#pragma unroll
    for (int j = 0; j < 4; ++j) {
      u32x4 v = {w[cc*16 + j*4], w[cc*16 + j*4 + 1], w[cc*16 + j*4 + 2], w[cc*16 + j*4 + 3]};
      *(u32x4*)&img[c * 1024 + j * 256 + kib * 4] = v;
    }
  }
  float tot = ss + __shfl_xor(ss, 1);
  if (sub == 0) {
    u32 w0;
    if (real) {
      k2out[slice * SL_REAL + within] = tot;
      u32 h = bf16_rne(tot);
      float hf = __uint_as_float(h << 16);
      u32 lo = bf16_rne(tot - hf);
      w0 = h | (lo << 16);
    } else {
      w0 = 0x7FC07FC0u;   // NaN,NaN -> dd = NaN -> never selected
    }
    u32x4 v0 = {w0, 0, 0, 0};
    u32x4 z  = {0, 0, 0, 0};
    *(u32x4*)&img[4 * 1024 + 0 * 256 + kib * 4] = v0;
    *(u32x4*)&img[4 * 1024 + 1 * 256 + kib * 4] = z;
    *(u32x4*)&img[4 * 1024 + 2 * 256 + kib * 4] = z;
    *(u32x4*)&img[4 * 1024 + 3 * 256 + kib * 4] = z;
  }
}

// ---------------- K3 helper: single-wave bitonic sort of 512 u32 ----------------------
__device__ __forceinline__ void sort512_wave(u32* sb, int lane) {
  for (int k = 2; k <= 512; k <<= 1)
    for (int j = k >> 1; j > 0; j >>= 1) {
#pragma unroll
      for (int half = 0; half < 8; ++half) {
        int e = lane + (half << 6);
        int pp = e ^ j;
        if (pp > e) {
          u32 x = sb[e], y = sb[pp];
          bool up = ((e & k) == 0);
          if ((x > y) == up) { sb[e] = y; sb[pp] = x; }
        }
      }
      __builtin_amdgcn_wave_barrier();
    }
}

// branch-free sorted insert of c into ascending q[0..QT-1] (c = 0xFFFFFFFF is a no-op)
#define INSERT_Q(QARR, CVAL) do {                                   \
    u32 c_ = (CVAL);                                                \
    _Pragma("unroll")                                               \
    for (int i_ = QT - 1; i_ >= 1; --i_) {                          \
      u32 mx_ = QARR[i_ - 1] > c_ ? QARR[i_ - 1] : c_;              \
      QARR[i_] = mx_ < QARR[i_] ? mx_ : QARR[i_];                   \
    }                                                               \
    QARR[0] = c_ < QARR[0] ? c_ : QARR[0];                          \
  } while (0)

// per-row selection: build packed candidates from acc[QF], insert passers via pick-min
#define SELECT_ROW(QF) do {                                         \
    u32 qt_ = topq[QF][QT - 1];                                     \
    u32 cc_[4]; u32 live_ = 0;                                      \
    _Pragma("unroll")                                               \
    for (int r_ = 0; r_ < 4; ++r_) {                                \
      float dd_ = q2v[QF] + acc[QF][r_];                            \
      cc_[r_] = (__float_as_uint(dd_) & 0xFFFFE000u) |              \
                (u32)(t * BKEY + wr * 16 + (l4 << 2) + r_);         \
      if (cc_[r_] < qt_) live_ |= 1u << r_;                         \
    }                                                               \
    while (__any(live_ != 0)) {                                     \
      u32 m_ = 0xFFFFFFFFu; int sel_ = -1;                          \
      _Pragma("unroll")                                             \
      for (int r_ = 0; r_ < 4; ++r_)                                \
        if ((live_ >> r_) & 1u) {                                   \
          if (cc_[r_] < m_) { m_ = cc_[r_]; sel_ = r_; }            \
        }                                                           \
      INSERT_Q(topq[QF], m_);                                       \
      if (sel_ >= 0) live_ &= ~(1u << (u32)sel_);                   \
      u32 qt2_ = topq[QF][QT - 1];                                  \
      _Pragma("unroll")                                             \
      for (int r_ = 0; r_ < 4; ++r_)                                \
        if (cc_[r_] >= qt2_) live_ &= ~(1u << r_);                  \
    }                                                               \
  } while (0)

// ---------------- K3: K=160 bf16 MFMA distance GEMM + register-queue top-k ------------
__global__ __launch_bounds__(512, 4) void k3_knn(
    const ushort* __restrict__ qext2,  // [B][128] bf16 of (-2q)
    const float* __restrict__ q2g,
    const u32* __restrict__ keyimg,    // kslice-major images
    u32* __restrict__ lbuf)
{
  __shared__ u32 kbuf[2][IMG_U32];     // 2 x 20KB; aliased as merge buffer at the end

  int tid = threadIdx.x;
  int l = tid & 63, w = tid >> 6;
  int l15 = l & 15, l4 = l >> 4;
  int wr = w & 3, wc = w >> 2;         // wr: key quarter, wc: row half
  int slice = blockIdx.x & 7;          // consecutive blocks -> different XCDs
  int rb = (blockIdx.x >> 3) << 6;     // 64 q rows per block

  // ---- B-frags (q side) in registers for the whole kernel ----
  bf16x8 bfr[4][2];
#pragma unroll
  for (int c = 0; c < 4; ++c)
#pragma unroll
    for (int qf = 0; qf < 2; ++qf) {
      const ushort* qp = qext2 + (size_t)(rb + wc * 32 + qf * 16 + l15) * 128 + c * 32 + l4 * 8;
      bfr[c][qf] = __builtin_bit_cast(bf16x8, *(const u32x4*)qp);
    }
  bf16x8 bk2;
  {
    u16x8 v = {0, 0, 0, 0, 0, 0, 0, 0};
    if (l4 == 0) { v[0] = 0x3F80; v[1] = 0x3F80; }
    bk2 = __builtin_bit_cast(bf16x8, v);
  }
  float q2v[2];
#pragma unroll
  for (int qf = 0; qf < 2; ++qf) q2v[qf] = q2g[rb + wc * 32 + qf * 16 + l15];

  // ---- per-lane register top-QT queues (2 rows per lane) ----
  u32 topq[2][QT];
#pragma unroll
  for (int a = 0; a < 2; ++a)
#pragma unroll
    for (int j = 0; j < QT; ++j) topq[a][j] = 0xFFFFFFFFu;

  const u32* imgbase = keyimg + (size_t)slice * NB * IMG_U32;

  auto stage = [&](int b, int t) {
    if (w < 5) {
      const u32* src = imgbase + (size_t)t * IMG_U32 + w * 1024 + l * 4;
      u32* dst = &kbuf[b][w * 1024];
#pragma unroll
      for (int i = 0; i < 4; ++i)
        gl_lds16(src + i * 256, dst + i * 256);
    }
  };

  stage(0, 0);
  __syncthreads();

  int cur = 0;
  for (int t = 0; t < NB; ++t) {
    if (t + 1 < NB) stage(cur ^ 1, t + 1);   // in flight across compute+selection

    f32x4 acc[2] = {};
#pragma unroll
    for (int c = 0; c < 5; ++c) {
      bf16x8 a = __builtin_bit_cast(bf16x8,
          *(const u32x4*)&kbuf[cur][c * 1024 + l4 * 256 + (wr * 16 + l15) * 4]);
      acc[0] = __builtin_amdgcn_mfma_f32_16x16x32_bf16(a, (c < 4) ? bfr[c][0] : bk2, acc[0], 0, 0, 0);
      acc[1] = __builtin_amdgcn_mfma_f32_16x16x32_bf16(a, (c < 4) ? bfr[c][1] : bk2, acc[1], 0, 0, 0);
    }

    // ---- selection: dd = q2 + (-2*dot + k2), all in registers ----
    SELECT_ROW(0);
    SELECT_ROW(1);

    __syncthreads();               // stage(t+1) drained; kbuf[cur] free
    cur ^= 1;
  }

  // ---- end-of-kernel merge: 16 lane-positions x QT per row -> exact top-50 ----------
  __syncthreads();
  u32* mb = &kbuf[0][0];           // [16 rows][512] = 32KB, fits in kbuf (40KB)

#pragma unroll 1
  for (int g = 0; g < 4; ++g) {    // row group: rows g*16 .. g*16+15
    // dump: waves with wc == g>>1 contribute queue qf == g&1
    if (wc == (g >> 1)) {
      int pos = wr * 4 + l4;       // 0..15
      u32* dst = mb + l15 * 512 + pos * QT;
      if ((g & 1) == 0) {
#pragma unroll
        for (int j = 0; j < QT; ++j) dst[j] = topq[0][j];
      } else {
#pragma unroll
        for (int j = 0; j < QT; ++j) dst[j] = topq[1][j];
      }
    }
    // pad entries 384..511 of each row
#pragma unroll
    for (int i = 0; i < 4; ++i) {
      int e = tid + i * 512;       // 0..2047 = 16 rows x 128 pads
      mb[(e >> 7) * 512 + 384 + (e & 127)] = 0xFFFFFFFFu;
    }
    __syncthreads();

    // each wave sorts 2 rows (wave-private LDS regions)
#pragma unroll 1
    for (int rr = 0; rr < 2; ++rr)
      sort512_wave(mb + ((w << 1) + rr) * 512, l);

    // write exact top-50 per (row, slice)
#pragma unroll 1
    for (int rr = 0; rr < 2; ++rr) {
      int r = (w << 1) + rr;
      if (l < KNN) {
        int grow = rb + g * 16 + r;
        lbuf[((size_t)grow * NSLICE + slice) * CAP + l] = mb[r * 512 + l];
      }
    }
    __syncthreads();               // before next group's dump overwrites mb
  }
}

// ---------------- K4: merge 8x50 -> approx top-64 -> exact fp32 rerank -> output ------
__global__ __launch_bounds__(256) void k4_rerank(
    const u32* __restrict__ lbuf, const float* __restrict__ qrow,
    const float* __restrict__ q2g, const float* __restrict__ k2g,
    const float* __restrict__ keys, const float* __restrict__ memv,
    const float* __restrict__ net, float* __restrict__ out)
{
  __shared__ u64 sb[512];
  __shared__ float qs[128];
  __shared__ float part[4][RR];
  __shared__ u64 cand[RR];
  int b = blockIdx.x, t = threadIdx.x;
  if (t < 128) qs[t] = qrow[(size_t)b * D_ + t];
#pragma unroll
  for (int h = 0; h < 2; ++h) {
    int e = t + (h << 8);
    u64 v = ~0ull;
    if (e < NSLICE * KNN) {
      int s = e / KNN, j = e - s * KNN;
      u32 k32 = lbuf[((size_t)b * NSLICE + s) * CAP + j];
      v = ((u64)(k32 & 0xFFFFE000u) << 32) | (u32)(s * SL_REAL + (k32 & 0x1FFFu));
    }
    sb[e] = v;
  }
  __syncthreads();
  for (int k = 2; k <= 512; k <<= 1)
    for (int j = k >> 1; j > 0; j >>= 1) {
#pragma unroll
      for (int h = 0; h < 2; ++h) {
        int e = t + (h << 8);
        int p = e ^ j;
        if (p > e) {
          u64 x = sb[e], y = sb[p];
          bool up = ((e & k) == 0);
          if ((x > y) == up) { sb[e] = y; sb[p] = x; }
        }
      }
      __syncthreads();
    }

  // exact rerank of approx-top-RR
  int cid = t & 63, g = t >> 6;
  u32 gidx = (u32)sb[cid];
  const float* kp = keys + (size_t)gidx * D_ + g * 32;
  float dot = 0.f;
#pragma unroll
  for (int i = 0; i < 8; ++i) {
    float4 kv = *(const float4*)(kp + i * 4);
    float4 qv = *(const float4*)&qs[g * 32 + i * 4];
    dot = fmaf(kv.x, qv.x, dot); dot = fmaf(kv.y, qv.y, dot);
    dot = fmaf(kv.z, qv.z, dot); dot = fmaf(kv.w, qv.w, dot);
  }
  part[g][cid] = dot;
  __syncthreads();
  if (t < RR) {
    float dotf = part[0][t] + part[1][t] + part[2][t] + part[3][t];
    u32 gi = (u32)sb[t];
    float dd = q2g[b] + k2g[gi] - 2.0f * dotf;
    cand[t] = ((u64)__float_as_uint(dd) << 32) | gi;
  }
  __syncthreads();
  if (t < 64) {
    for (int k = 2; k <= 64; k <<= 1)
      for (int j = k >> 1; j > 0; j >>= 1) {
        u64 x = cand[t], y = cand[t ^ j];
        __builtin_amdgcn_wave_barrier();
        bool up = ((t & k) == 0);
        u64 mn = x < y ? x : y, mx = x < y ? y : x;
        cand[t] = ((t < (t ^ j)) == up) ? mn : mx;
        __builtin_amdgcn_wave_barrier();
      }
    u64 key = cand[t];
    float d = __uint_as_float((u32)(key >> 32));
    u32 idx = (u32)key;
    float w = 0.f, wv = 0.f;
    if (t < KNN) {
      float ww = 1.0f / (d + 1e-7f);
      w = ww;
      wv = ww * memv[idx];
    }
#pragma unroll
    for (int o = 1; o < 64; o <<= 1) {
      w += __shfl_xor(w, o);
      wv += __shfl_xor(wv, o);
    }
    if (t == 0) out[b] = 0.9f * (wv / w) + 0.1f * net[b];
  }
}

// ---------------- launch --------------------------------------------------------------
extern "C" void kernel_launch(void* const* d_in, const int* in_sizes, int n_in,
                              void* d_out, int out_size, void* d_ws, size_t ws_size,
                              hipStream_t stream)
{
  const float* states     = (const float*)d_in[0];
  const float* W1         = (const float*)d_in[1];
  const float* b1         = (const float*)d_in[2];
  const float* W2         = (const float*)d_in[3];
  const float* b2         = (const float*)d_in[4];
  const float* lng        = (const float*)d_in[5];
  const float* lnb        = (const float*)d_in[6];
  const float* mem_keys   = (const float*)d_in[7];
  const float* mem_values = (const float*)d_in[8];
  const float* V1         = (const float*)d_in[9];
  const float* c1         = (const float*)d_in[10];
  const float* V2         = (const float*)d_in[11];
  const float* c2         = (const float*)d_in[12];
  const float* V3         = (const float*)d_in[13];
  const float* c3         = (const float*)d_in[14];
  float* out = (float*)d_out;

  char* ws = (char*)d_ws;
  ushort* qext2 = (ushort*)(ws + 0);          // 1 MB
  float*  qrow  = (float*)(ws + 1048576);     // 2 MB
  float*  q2    = (float*)(ws + 3145728);     // 16 KB
  float*  net   = (float*)(ws + 3162112);     // 16 KB
  float*  k2g   = (float*)(ws + 3178496);     // 200 KB (ends 3383296)
  u32*  keyimg  = (u32*)(ws + 3383296);       // 16.06 MB (ends 19,439,616)
  u32*  lbuf    = (u32*)(ws + 19439616);      // 16.78 MB (ends 36,216,832)
  float* h  = (float*)(ws + 3383296);             // overlays keyimg (dead before k5)
  float* v1 = (float*)(ws + 3383296 + 4194304);

  k1_gemm<<<dim3(H_ / 64, B_ / 64, 2), 256, 0, stream>>>(states, W1, b1, V1, c1, h, v1);
  k2_fused<<<dim3(B_ / 32), 256, 0, stream>>>(0, h, W2, b2, lng, lnb, V3, c3, qext2, qrow, q2, net);
  k2_fused<<<dim3(B_ / 32), 256, 0, stream>>>(1, v1, V2, c2, lng, lnb, V3, c3, qext2, qrow, q2, net);
  k5_keyimg<<<dim3(NSLICE * SL_PAD / 128), 256, 0, stream>>>(mem_keys, keyimg, k2g);
  k3_knn<<<dim3((B_ / 64) * NSLICE), 512, 0, stream>>>(qext2, q2, keyimg, lbuf);
  k4_rerank<<<dim3(B_), 256, 0, stream>>>(lbuf, qrow, q2, k2g, mem_keys, mem_values, net, out);
}

// Round 11
// 616.794 us; speedup vs baseline: 1.4644x; 1.4097x over previous
//
#include <hip/hip_runtime.h>
#include <stdint.h>

#define B_   4096
#define S_   544
#define H_   256
#define D_   128
#define M_   50000
#define KNN  50
#define NSLICE 8
#define SL_REAL 6250
#define BKEY 64
#define NB   98                  // 64-key tiles per slice
#define SL_PAD (NB * BKEY)       // 6272
#define CAP  128
#define RR   64
#define IMG_U32 5120             // 5 chunks * 4 kslices * 64 keys * 4 u32 = 20KB
#define QT   24                  // per-lane queue depth

typedef unsigned long long u64;
typedef unsigned int u32;
typedef __attribute__((ext_vector_type(8))) __bf16 bf16x8;
typedef __attribute__((ext_vector_type(8))) unsigned short u16x8;
typedef __attribute__((ext_vector_type(4))) float f32x4;
typedef __attribute__((ext_vector_type(4))) u32 u32x4;

__device__ __forceinline__ u32 bf16_rne(float x) {
  u32 u = __float_as_uint(x);
  return (u + 0x7FFFu + ((u >> 16) & 1u)) >> 16;
}

__device__ __forceinline__ void gl_lds16(const u32* g, u32* l) {
  __builtin_amdgcn_global_load_lds(
      (const __attribute__((address_space(1))) u32*)g,
      (__attribute__((address_space(3))) u32*)l, 16, 0, 0);
}

// ---------------- K1: h = relu(states@W1+b1) (z=0), v1 = relu(states@V1+c1) (z=1) ----
__global__ __launch_bounds__(256) void k1_gemm(
    const float* __restrict__ A,
    const float* __restrict__ W1, const float* __restrict__ b1,
    const float* __restrict__ V1, const float* __restrict__ c1,
    float* __restrict__ hout, float* __restrict__ v1out)
{
  const float* W    = (blockIdx.z == 0) ? W1 : V1;
  const float* bias = (blockIdx.z == 0) ? b1 : c1;
  float* out        = (blockIdx.z == 0) ? hout : v1out;

  __shared__ float as[16][68];
  __shared__ float bs[16][64];

  int tid = threadIdx.x;
  int tx = tid & 15, ty = tid >> 4;
  int rb = blockIdx.y * 64, cb = blockIdx.x * 64;

  float acc[4][4] = {};

  for (int k0 = 0; k0 < S_; k0 += 16) {
    {
      int r = tid >> 2, k4 = (tid & 3) << 2;
      float4 a = *(const float4*)&A[(size_t)(rb + r) * S_ + k0 + k4];
      as[k4 + 0][r] = a.x; as[k4 + 1][r] = a.y;
      as[k4 + 2][r] = a.z; as[k4 + 3][r] = a.w;
    }
    {
      int kk = tid >> 4, c4 = (tid & 15) << 2;
      *(float4*)&bs[kk][c4] = *(const float4*)&W[(size_t)(k0 + kk) * H_ + cb + c4];
    }
    __syncthreads();
#pragma unroll
    for (int kk = 0; kk < 16; ++kk) {
      float4 a4 = *(const float4*)&as[kk][ty << 2];
      float4 b4 = *(const float4*)&bs[kk][tx << 2];
      float av[4] = {a4.x, a4.y, a4.z, a4.w};
      float bv[4] = {b4.x, b4.y, b4.z, b4.w};
#pragma unroll
      for (int i = 0; i < 4; ++i)
#pragma unroll
        for (int j = 0; j < 4; ++j)
          acc[i][j] = fmaf(av[i], bv[j], acc[i][j]);
    }
    __syncthreads();
  }

#pragma unroll
  for (int i = 0; i < 4; ++i) {
    int r = rb + (ty << 2) + i;
#pragma unroll
    for (int j = 0; j < 4; ++j) {
      int c = cb + (tx << 2) + j;
      float v = acc[i][j] + bias[c];
      out[(size_t)r * H_ + c] = v > 0.0f ? v : 0.0f;
    }
  }
}

// ---------------- K2: mode 0: q = LN(h@W2+b2) -> qrow(f32), qext2(bf16 of -2q), q2
//                      mode 1: v2 = relu(v1@V2+c2); net = v2@V3 + c3 ------------------
__global__ __launch_bounds__(256) void k2_fused(
    int mode,
    const float* __restrict__ A,      // [B_][H_]
    const float* __restrict__ W,      // [H_][D_]
    const float* __restrict__ bias,   // [D_]
    const float* __restrict__ lng, const float* __restrict__ lnb,
    const float* __restrict__ V3, const float* __restrict__ c3,
    ushort* __restrict__ qext2, float* __restrict__ qrow,
    float* __restrict__ q2out, float* __restrict__ netout)
{
  __shared__ float as[32][36];
  __shared__ float bs[32][132];
  __shared__ float yt[32][132];
  __shared__ float v3s[128];

  int tid = threadIdx.x;
  int tx = tid & 31, ty = tid >> 5;
  int rb = blockIdx.x * 32;

  if (mode == 1 && tid < 128) v3s[tid] = V3[tid];

  float acc[4][4] = {};

  for (int k0 = 0; k0 < H_; k0 += 32) {
    {
      int r = tid >> 3, k4 = (tid & 7) << 2;
      float4 a = *(const float4*)&A[(size_t)(rb + r) * H_ + k0 + k4];
      as[k4 + 0][r] = a.x; as[k4 + 1][r] = a.y;
      as[k4 + 2][r] = a.z; as[k4 + 3][r] = a.w;
    }
    {
      int kk = tid >> 3, c16 = (tid & 7) << 4;
#pragma unroll
      for (int t = 0; t < 4; ++t)
        *(float4*)&bs[kk][c16 + (t << 2)] =
            *(const float4*)&W[(size_t)(k0 + kk) * D_ + c16 + (t << 2)];
    }
    __syncthreads();
#pragma unroll
    for (int kk = 0; kk < 32; ++kk) {
      float4 a4 = *(const float4*)&as[kk][ty << 2];
      float4 b4 = *(const float4*)&bs[kk][tx << 2];
      float av[4] = {a4.x, a4.y, a4.z, a4.w};
      float bv[4] = {b4.x, b4.y, b4.z, b4.w};
#pragma unroll
      for (int i = 0; i < 4; ++i)
#pragma unroll
        for (int j = 0; j < 4; ++j)
          acc[i][j] = fmaf(av[i], bv[j], acc[i][j]);
    }
    __syncthreads();
  }

#pragma unroll
  for (int i = 0; i < 4; ++i)
#pragma unroll
    for (int j = 0; j < 4; ++j) {
      int c = (tx << 2) + j;
      yt[(ty << 2) + i][c] = acc[i][j] + bias[c];
    }
  __syncthreads();

  int r8 = tid >> 3, j8 = tid & 7;
  int rg = rb + r8;
  if (mode == 0) {
    float s = 0.f;
#pragma unroll
    for (int t = 0; t < 16; ++t) s += yt[r8][(j8 << 4) + t];
    s += __shfl_xor(s, 1); s += __shfl_xor(s, 2); s += __shfl_xor(s, 4);
    float mu = s * (1.0f / 128.0f);
    float vs = 0.f;
#pragma unroll
    for (int t = 0; t < 16; ++t) {
      float d = yt[r8][(j8 << 4) + t] - mu;
      vs = fmaf(d, d, vs);
    }
    vs += __shfl_xor(vs, 1); vs += __shfl_xor(vs, 2); vs += __shfl_xor(vs, 4);
    float var = vs * (1.0f / 128.0f);
    float rstd = 1.0f / sqrtf(var + 1e-5f);
    float q2p = 0.f;
    ushort* qe = qext2 + (size_t)rg * 128;
#pragma unroll
    for (int t = 0; t < 16; ++t) {
      int c = (j8 << 4) + t;
      float qv = (yt[r8][c] - mu) * rstd * lng[c] + lnb[c];
      qrow[(size_t)rg * D_ + c] = qv;
      qe[c] = (ushort)bf16_rne(-2.0f * qv);
      q2p = fmaf(qv, qv, q2p);
    }
    q2p += __shfl_xor(q2p, 1); q2p += __shfl_xor(q2p, 2); q2p += __shfl_xor(q2p, 4);
    if (j8 == 0) q2out[rg] = q2p;
  } else {
    float s = 0.f;
#pragma unroll
    for (int t = 0; t < 16; ++t) {
      int c = (j8 << 4) + t;
      float v = yt[r8][c];
      v = v > 0.f ? v : 0.f;
      s = fmaf(v, v3s[c], s);
    }
    s += __shfl_xor(s, 1); s += __shfl_xor(s, 2); s += __shfl_xor(s, 4);
    if (j8 == 0) netout[rg] = s + c3[0];
  }
}

// ---------------- K5: build kslice-major key image + exact k2 norms -------------------
__global__ __launch_bounds__(256) void k5_keyimg(
    const float* __restrict__ keys, u32* __restrict__ keyimg,
    float* __restrict__ k2out)
{
  int tid = threadIdx.x;
  int p = blockIdx.x * 128 + (tid >> 1);   // padded key index
  int sub = tid & 1;
  int slice = p / SL_PAD;
  int within = p - slice * SL_PAD;
  int kb = within >> 6, kib = within & 63;
  u32* img = keyimg + (size_t)(slice * NB + kb) * IMG_U32;
  bool real = within < SL_REAL;

  u32 w[32];
  float ss = 0.f;
  if (real) {
    const float* kp = keys + (size_t)(slice * SL_REAL + within) * D_ + sub * 64;
#pragma unroll
    for (int i = 0; i < 16; ++i) {
      float4 x = *(const float4*)(kp + i * 4);
      ss = fmaf(x.x, x.x, fmaf(x.y, x.y, fmaf(x.z, x.z, fmaf(x.w, x.w, ss))));
      w[i * 2]     = bf16_rne(x.x) | (bf16_rne(x.y) << 16);
      w[i * 2 + 1] = bf16_rne(x.z) | (bf16_rne(x.w) << 16);
    }
  } else {
#pragma unroll
    for (int i = 0; i < 32; ++i) w[i] = 0;
  }
#pragma unroll
  for (int cc = 0; cc < 2; ++cc) {
    int c = sub * 2 + cc;
#pragma unroll
    for (int j = 0; j < 4; ++j) {
      u32x4 v = {w[cc*16 + j*4], w[cc*16 + j*4 + 1], w[cc*16 + j*4 + 2], w[cc*16 + j*4 + 3]};
      *(u32x4*)&img[c * 1024 + j * 256 + kib * 4] = v;
    }
  }
  float tot = ss + __shfl_xor(ss, 1);
  if (sub == 0) {
    u32 w0;
    if (real) {
      k2out[slice * SL_REAL + within] = tot;
      u32 h = bf16_rne(tot);
      float hf = __uint_as_float(h << 16);
      u32 lo = bf16_rne(tot - hf);
      w0 = h | (lo << 16);
    } else {
      w0 = 0x7FC07FC0u;   // NaN,NaN -> dd = NaN -> never selected
    }
    u32x4 v0 = {w0, 0, 0, 0};
    u32x4 z  = {0, 0, 0, 0};
    *(u32x4*)&img[4 * 1024 + 0 * 256 + kib * 4] = v0;
    *(u32x4*)&img[4 * 1024 + 1 * 256 + kib * 4] = z;
    *(u32x4*)&img[4 * 1024 + 2 * 256 + kib * 4] = z;
    *(u32x4*)&img[4 * 1024 + 3 * 256 + kib * 4] = z;
  }
}

// ---------------- K3 helper: single-wave bitonic sort of 512 u32 ----------------------
__device__ __forceinline__ void sort512_wave(u32* sb, int lane) {
  for (int k = 2; k <= 512; k <<= 1)
    for (int j = k >> 1; j > 0; j >>= 1) {
#pragma unroll
      for (int half = 0; half < 8; ++half) {
        int e = lane + (half << 6);
        int pp = e ^ j;
        if (pp > e) {
          u32 x = sb[e], y = sb[pp];
          bool up = ((e & k) == 0);
          if ((x > y) == up) { sb[e] = y; sb[pp] = x; }
        }
      }
      __builtin_amdgcn_wave_barrier();
    }
}

// branch-free sorted insert of c into ascending q[0..QT-1] (no-op when c >= q[QT-1])
#define INSERT_Q(QARR, CVAL) do {                                   \
    u32 c_ = (CVAL);                                                \
    _Pragma("unroll")                                               \
    for (int i_ = QT - 1; i_ >= 1; --i_) {                          \
      u32 mx_ = QARR[i_ - 1] > c_ ? QARR[i_ - 1] : c_;              \
      QARR[i_] = mx_ < QARR[i_] ? mx_ : QARR[i_];                   \
    }                                                               \
    QARR[0] = c_ < QARR[0] ? c_ : QARR[0];                          \
  } while (0)

#define CSWAP(A, B) do { u32 lo_ = (A) < (B) ? (A) : (B);           \
    u32 hi_ = (A) < (B) ? (B) : (A); (A) = lo_; (B) = hi_; } while (0)

// ---------------- K3: K=160 bf16 MFMA distance GEMM + register-queue top-k ------------
// 32 q-rows x 6250 keys per block; 1 row & 1 queue per lane.
__global__ __launch_bounds__(512, 6) void k3_knn(
    const ushort* __restrict__ qext2,  // [B][128] bf16 of (-2q)
    const float* __restrict__ q2g,
    const u32* __restrict__ keyimg,    // kslice-major images
    u32* __restrict__ lbuf)
{
  __shared__ u32 kbuf[2][IMG_U32];     // 2 x 20KB; aliased as merge buffer at the end

  int tid = threadIdx.x;
  int l = tid & 63, w = tid >> 6;
  int l15 = l & 15, l4 = l >> 4;
  int wr = w & 3, wc = w >> 2;         // wr: key quarter, wc: row half (16 rows each)
  int slice = blockIdx.x & 7;          // consecutive blocks -> different XCDs
  int rb = (blockIdx.x >> 3) << 5;     // 32 q rows per block

  // ---- B-frags (q side) in registers for the whole kernel ----
  bf16x8 bfr[4];
#pragma unroll
  for (int c = 0; c < 4; ++c) {
    const ushort* qp = qext2 + (size_t)(rb + wc * 16 + l15) * 128 + c * 32 + l4 * 8;
    bfr[c] = __builtin_bit_cast(bf16x8, *(const u32x4*)qp);
  }
  bf16x8 bk2;
  {
    u16x8 v = {0, 0, 0, 0, 0, 0, 0, 0};
    if (l4 == 0) { v[0] = 0x3F80; v[1] = 0x3F80; }
    bk2 = __builtin_bit_cast(bf16x8, v);
  }
  float q2v = q2g[rb + wc * 16 + l15];

  // ---- per-lane register top-QT queue (ONE row per lane) ----
  u32 topq[QT];
#pragma unroll
  for (int j = 0; j < QT; ++j) topq[j] = 0xFFFFFFFFu;

  const u32* imgbase = keyimg + (size_t)slice * NB * IMG_U32;

  auto stage = [&](int b, int t) {
    if (w < 5) {
      const u32* src = imgbase + (size_t)t * IMG_U32 + w * 1024 + l * 4;
      u32* dst = &kbuf[b][w * 1024];
#pragma unroll
      for (int i = 0; i < 4; ++i)
        gl_lds16(src + i * 256, dst + i * 256);
    }
  };

  stage(0, 0);
  __syncthreads();

  int cur = 0;
  for (int t = 0; t < NB; ++t) {
    if (t + 1 < NB) stage(cur ^ 1, t + 1);   // in flight across compute+selection

    f32x4 acc = {};
#pragma unroll
    for (int c = 0; c < 5; ++c) {
      bf16x8 a = __builtin_bit_cast(bf16x8,
          *(const u32x4*)&kbuf[cur][c * 1024 + l4 * 256 + (wr * 16 + l15) * 4]);
      acc = __builtin_amdgcn_mfma_f32_16x16x32_bf16(a, (c < 4) ? bfr[c] : bk2, acc, 0, 0, 0);
    }

    // ---- selection: dd = q2 + (-2*dot + k2); sort4 then ascending guarded inserts ---
    u32 cc[4];
#pragma unroll
    for (int r = 0; r < 4; ++r) {
      float dd = q2v + acc[r];
      cc[r] = (__float_as_uint(dd) & 0xFFFFE000u) |
              (u32)(t * BKEY + wr * 16 + (l4 << 2) + r);
    }
    CSWAP(cc[0], cc[1]); CSWAP(cc[2], cc[3]);
    CSWAP(cc[0], cc[2]); CSWAP(cc[1], cc[3]);
    CSWAP(cc[1], cc[2]);
    {
      bool go = true;
#pragma unroll
      for (int r = 0; r < 4; ++r) {
        go = go && __any(cc[r] < topq[QT - 1]);
        if (go) INSERT_Q(topq, cc[r]);
      }
    }

    __syncthreads();               // stage(t+1) drained; kbuf[cur] free
    cur ^= 1;
  }

  // ---- end-of-kernel merge: 16 slots x QT per row -> exact per-slice top-50 ---------
  __syncthreads();
  u32* mb = &kbuf[0][0];           // [16 rows][512] = 32KB, fits in kbuf (40KB)

#pragma unroll 1
  for (int g = 0; g < 2; ++g) {    // row group: rows g*16 .. g*16+15
    if (wc == g) {
      u32* dst = mb + l15 * 512 + (wr * 4 + l4) * QT;
#pragma unroll
      for (int j = 0; j < QT; ++j) dst[j] = topq[j];
    }
    // pad entries 384..511 of each row
#pragma unroll
    for (int i = 0; i < 4; ++i) {
      int e = tid + i * 512;       // 0..2047 = 16 rows x 128 pads
      mb[(e >> 7) * 512 + 384 + (e & 127)] = 0xFFFFFFFFu;
    }
    __syncthreads();

    // each wave sorts 2 rows (wave-private LDS regions)
#pragma unroll 1
    for (int rr = 0; rr < 2; ++rr)
      sort512_wave(mb + ((w << 1) + rr) * 512, l);

    // write exact top-50 per (row, slice)
#pragma unroll 1
    for (int rr = 0; rr < 2; ++rr) {
      int r = (w << 1) + rr;
      if (l < KNN) {
        int grow = rb + g * 16 + r;
        lbuf[((size_t)grow * NSLICE + slice) * CAP + l] = mb[r * 512 + l];
      }
    }
    __syncthreads();               // before next group's dump overwrites mb
  }
}

// ---------------- K4: merge 8x50 -> approx top-64 -> exact fp32 rerank -> output ------
__global__ __launch_bounds__(256) void k4_rerank(
    const u32* __restrict__ lbuf, const float* __restrict__ qrow,
    const float* __restrict__ q2g, const float* __restrict__ k2g,
    const float* __restrict__ keys, const float* __restrict__ memv,
    const float* __restrict__ net, float* __restrict__ out)
{
  __shared__ u64 sb[512];
  __shared__ float qs[128];
  __shared__ float part[4][RR];
  __shared__ u64 cand[RR];
  int b = blockIdx.x, t = threadIdx.x;
  if (t < 128) qs[t] = qrow[(size_t)b * D_ + t];
#pragma unroll
  for (int h = 0; h < 2; ++h) {
    int e = t + (h << 8);
    u64 v = ~0ull;
    if (e < NSLICE * KNN) {
      int s = e / KNN, j = e - s * KNN;
      u32 k32 = lbuf[((size_t)b * NSLICE + s) * CAP + j];
      v = ((u64)(k32 & 0xFFFFE000u) << 32) | (u32)(s * SL_REAL + (k32 & 0x1FFFu));
    }
    sb[e] = v;
  }
  __syncthreads();
  for (int k = 2; k <= 512; k <<= 1)
    for (int j = k >> 1; j > 0; j >>= 1) {
#pragma unroll
      for (int h = 0; h < 2; ++h) {
        int e = t + (h << 8);
        int p = e ^ j;
        if (p > e) {
          u64 x = sb[e], y = sb[p];
          bool up = ((e & k) == 0);
          if ((x > y) == up) { sb[e] = y; sb[p] = x; }
        }
      }
      __syncthreads();
    }

  // exact rerank of approx-top-RR
  int cid = t & 63, g = t >> 6;
  u32 gidx = (u32)sb[cid];
  const float* kp = keys + (size_t)gidx * D_ + g * 32;
  float dot = 0.f;
#pragma unroll
  for (int i = 0; i < 8; ++i) {
    float4 kv = *(const float4*)(kp + i * 4);
    float4 qv = *(const float4*)&qs[g * 32 + i * 4];
    dot = fmaf(kv.x, qv.x, dot); dot = fmaf(kv.y, qv.y, dot);
    dot = fmaf(kv.z, qv.z, dot); dot = fmaf(kv.w, qv.w, dot);
  }
  part[g][cid] = dot;
  __syncthreads();
  if (t < RR) {
    float dotf = part[0][t] + part[1][t] + part[2][t] + part[3][t];
    u32 gi = (u32)sb[t];
    float dd = q2g[b] + k2g[gi] - 2.0f * dotf;
    cand[t] = ((u64)__float_as_uint(dd) << 32) | gi;
  }
  __syncthreads();
  if (t < 64) {
    for (int k = 2; k <= 64; k <<= 1)
      for (int j = k >> 1; j > 0; j >>= 1) {
        u64 x = cand[t], y = cand[t ^ j];
        __builtin_amdgcn_wave_barrier();
        bool up = ((t & k) == 0);
        u64 mn = x < y ? x : y, mx = x < y ? y : x;
        cand[t] = ((t < (t ^ j)) == up) ? mn : mx;
        __builtin_amdgcn_wave_barrier();
      }
    u64 key = cand[t];
    float d = __uint_as_float((u32)(key >> 32));
    u32 idx = (u32)key;
    float w = 0.f, wv = 0.f;
    if (t < KNN) {
      float ww = 1.0f / (d + 1e-7f);
      w = ww;
      wv = ww * memv[idx];
    }
#pragma unroll
    for (int o = 1; o < 64; o <<= 1) {
      w += __shfl_xor(w, o);
      wv += __shfl_xor(wv, o);
    }
    if (t == 0) out[b] = 0.9f * (wv / w) + 0.1f * net[b];
  }
}

// ---------------- launch --------------------------------------------------------------
extern "C" void kernel_launch(void* const* d_in, const int* in_sizes, int n_in,
                              void* d_out, int out_size, void* d_ws, size_t ws_size,
                              hipStream_t stream)
{
  const float* states     = (const float*)d_in[0];
  const float* W1         = (const float*)d_in[1];
  const float* b1         = (const float*)d_in[2];
  const float* W2         = (const float*)d_in[3];
  const float* b2         = (const float*)d_in[4];
  const float* lng        = (const float*)d_in[5];
  const float* lnb        = (const float*)d_in[6];
  const float* mem_keys   = (const float*)d_in[7];
  const float* mem_values = (const float*)d_in[8];
  const float* V1         = (const float*)d_in[9];
  const float* c1         = (const float*)d_in[10];
  const float* V2         = (const float*)d_in[11];
  const float* c2         = (const float*)d_in[12];
  const float* V3         = (const float*)d_in[13];
  const float* c3         = (const float*)d_in[14];
  float* out = (float*)d_out;

  char* ws = (char*)d_ws;
  ushort* qext2 = (ushort*)(ws + 0);          // 1 MB
  float*  qrow  = (float*)(ws + 1048576);     // 2 MB
  float*  q2    = (float*)(ws + 3145728);     // 16 KB
  float*  net   = (float*)(ws + 3162112);     // 16 KB
  float*  k2g   = (float*)(ws + 3178496);     // 200 KB (ends 3383296)
  u32*  keyimg  = (u32*)(ws + 3383296);       // 16.06 MB (ends 19,439,616)
  u32*  lbuf    = (u32*)(ws + 19439616);      // 16.78 MB (ends 36,216,832)
  float* h  = (float*)(ws + 3383296);             // overlays keyimg (dead before k5)
  float* v1 = (float*)(ws + 3383296 + 4194304);

  k1_gemm<<<dim3(H_ / 64, B_ / 64, 2), 256, 0, stream>>>(states, W1, b1, V1, c1, h, v1);
  k2_fused<<<dim3(B_ / 32), 256, 0, stream>>>(0, h, W2, b2, lng, lnb, V3, c3, qext2, qrow, q2, net);
  k2_fused<<<dim3(B_ / 32), 256, 0, stream>>>(1, v1, V2, c2, lng, lnb, V3, c3, qext2, qrow, q2, net);
  k5_keyimg<<<dim3(NSLICE * SL_PAD / 128), 256, 0, stream>>>(mem_keys, keyimg, k2g);
  k3_knn<<<dim3((B_ / 32) * NSLICE), 512, 0, stream>>>(qext2, q2, keyimg, lbuf);
  k4_rerank<<<dim3(B_), 256, 0, stream>>>(lbuf, qrow, q2, k2g, mem_keys, mem_values, net, out);
}

// Round 12
// 407.853 us; speedup vs baseline: 2.2146x; 1.5123x over previous
//
#include <hip/hip_runtime.h>
#include <stdint.h>

#define B_   4096
#define S_   544
#define H_   256
#define D_   128
#define M_   50000
#define KNN  50
#define NSLICE 8
#define SL_REAL 6250
#define BKEY 64
#define NB   98                  // 64-key tiles per slice
#define SL_PAD (NB * BKEY)       // 6272
#define CAP  128
#define RR   64
#define IMG_U32 5120             // 5 chunks * 4 kslices * 64 keys * 4 u32 = 20KB
#define QT   16                  // per-lane queue depth (16 slots x 16 = 256 merge)

typedef unsigned long long u64;
typedef unsigned int u32;
typedef __attribute__((ext_vector_type(8))) __bf16 bf16x8;
typedef __attribute__((ext_vector_type(8))) unsigned short u16x8;
typedef __attribute__((ext_vector_type(4))) float f32x4;
typedef __attribute__((ext_vector_type(4))) u32 u32x4;

__device__ __forceinline__ u32 bf16_rne(float x) {
  u32 u = __float_as_uint(x);
  return (u + 0x7FFFu + ((u >> 16) & 1u)) >> 16;
}

__device__ __forceinline__ void gl_lds16(const u32* g, u32* l) {
  __builtin_amdgcn_global_load_lds(
      (const __attribute__((address_space(1))) u32*)g,
      (__attribute__((address_space(3))) u32*)l, 16, 0, 0);
}

// ---------------- K1: h = relu(states@W1+b1) (z=0), v1 = relu(states@V1+c1) (z=1) ----
__global__ __launch_bounds__(256) void k1_gemm(
    const float* __restrict__ A,
    const float* __restrict__ W1, const float* __restrict__ b1,
    const float* __restrict__ V1, const float* __restrict__ c1,
    float* __restrict__ hout, float* __restrict__ v1out)
{
  const float* W    = (blockIdx.z == 0) ? W1 : V1;
  const float* bias = (blockIdx.z == 0) ? b1 : c1;
  float* out        = (blockIdx.z == 0) ? hout : v1out;

  __shared__ float as[16][68];
  __shared__ float bs[16][64];

  int tid = threadIdx.x;
  int tx = tid & 15, ty = tid >> 4;
  int rb = blockIdx.y * 64, cb = blockIdx.x * 64;

  float acc[4][4] = {};

  for (int k0 = 0; k0 < S_; k0 += 16) {
    {
      int r = tid >> 2, k4 = (tid & 3) << 2;
      float4 a = *(const float4*)&A[(size_t)(rb + r) * S_ + k0 + k4];
      as[k4 + 0][r] = a.x; as[k4 + 1][r] = a.y;
      as[k4 + 2][r] = a.z; as[k4 + 3][r] = a.w;
    }
    {
      int kk = tid >> 4, c4 = (tid & 15) << 2;
      *(float4*)&bs[kk][c4] = *(const float4*)&W[(size_t)(k0 + kk) * H_ + cb + c4];
    }
    __syncthreads();
#pragma unroll
    for (int kk = 0; kk < 16; ++kk) {
      float4 a4 = *(const float4*)&as[kk][ty << 2];
      float4 b4 = *(const float4*)&bs[kk][tx << 2];
      float av[4] = {a4.x, a4.y, a4.z, a4.w};
      float bv[4] = {b4.x, b4.y, b4.z, b4.w};
#pragma unroll
      for (int i = 0; i < 4; ++i)
#pragma unroll
        for (int j = 0; j < 4; ++j)
          acc[i][j] = fmaf(av[i], bv[j], acc[i][j]);
    }
    __syncthreads();
  }

#pragma unroll
  for (int i = 0; i < 4; ++i) {
    int r = rb + (ty << 2) + i;
#pragma unroll
    for (int j = 0; j < 4; ++j) {
      int c = cb + (tx << 2) + j;
      float v = acc[i][j] + bias[c];
      out[(size_t)r * H_ + c] = v > 0.0f ? v : 0.0f;
    }
  }
}

// ---------------- K2: mode 0: q = LN(h@W2+b2) -> qrow(f32), qext2(bf16 of -2q), q2
//                      mode 1: v2 = relu(v1@V2+c2); net = v2@V3 + c3 ------------------
__global__ __launch_bounds__(256) void k2_fused(
    int mode,
    const float* __restrict__ A,      // [B_][H_]
    const float* __restrict__ W,      // [H_][D_]
    const float* __restrict__ bias,   // [D_]
    const float* __restrict__ lng, const float* __restrict__ lnb,
    const float* __restrict__ V3, const float* __restrict__ c3,
    ushort* __restrict__ qext2, float* __restrict__ qrow,
    float* __restrict__ q2out, float* __restrict__ netout)
{
  __shared__ float as[32][36];
  __shared__ float bs[32][132];
  __shared__ float yt[32][132];
  __shared__ float v3s[128];

  int tid = threadIdx.x;
  int tx = tid & 31, ty = tid >> 5;
  int rb = blockIdx.x * 32;

  if (mode == 1 && tid < 128) v3s[tid] = V3[tid];

  float acc[4][4] = {};

  for (int k0 = 0; k0 < H_; k0 += 32) {
    {
      int r = tid >> 3, k4 = (tid & 7) << 2;
      float4 a = *(const float4*)&A[(size_t)(rb + r) * H_ + k0 + k4];
      as[k4 + 0][r] = a.x; as[k4 + 1][r] = a.y;
      as[k4 + 2][r] = a.z; as[k4 + 3][r] = a.w;
    }
    {
      int kk = tid >> 3, c16 = (tid & 7) << 4;
#pragma unroll
      for (int t = 0; t < 4; ++t)
        *(float4*)&bs[kk][c16 + (t << 2)] =
            *(const float4*)&W[(size_t)(k0 + kk) * D_ + c16 + (t << 2)];
    }
    __syncthreads();
#pragma unroll
    for (int kk = 0; kk < 32; ++kk) {
      float4 a4 = *(const float4*)&as[kk][ty << 2];
      float4 b4 = *(const float4*)&bs[kk][tx << 2];
      float av[4] = {a4.x, a4.y, a4.z, a4.w};
      float bv[4] = {b4.x, b4.y, b4.z, b4.w};
#pragma unroll
      for (int i = 0; i < 4; ++i)
#pragma unroll
        for (int j = 0; j < 4; ++j)
          acc[i][j] = fmaf(av[i], bv[j], acc[i][j]);
    }
    __syncthreads();
  }

#pragma unroll
  for (int i = 0; i < 4; ++i)
#pragma unroll
    for (int j = 0; j < 4; ++j) {
      int c = (tx << 2) + j;
      yt[(ty << 2) + i][c] = acc[i][j] + bias[c];
    }
  __syncthreads();

  int r8 = tid >> 3, j8 = tid & 7;
  int rg = rb + r8;
  if (mode == 0) {
    float s = 0.f;
#pragma unroll
    for (int t = 0; t < 16; ++t) s += yt[r8][(j8 << 4) + t];
    s += __shfl_xor(s, 1); s += __shfl_xor(s, 2); s += __shfl_xor(s, 4);
    float mu = s * (1.0f / 128.0f);
    float vs = 0.f;
#pragma unroll
    for (int t = 0; t < 16; ++t) {
      float d = yt[r8][(j8 << 4) + t] - mu;
      vs = fmaf(d, d, vs);
    }
    vs += __shfl_xor(vs, 1); vs += __shfl_xor(vs, 2); vs += __shfl_xor(vs, 4);
    float var = vs * (1.0f / 128.0f);
    float rstd = 1.0f / sqrtf(var + 1e-5f);
    float q2p = 0.f;
    ushort* qe = qext2 + (size_t)rg * 128;
#pragma unroll
    for (int t = 0; t < 16; ++t) {
      int c = (j8 << 4) + t;
      float qv = (yt[r8][c] - mu) * rstd * lng[c] + lnb[c];
      qrow[(size_t)rg * D_ + c] = qv;
      qe[c] = (ushort)bf16_rne(-2.0f * qv);
      q2p = fmaf(qv, qv, q2p);
    }
    q2p += __shfl_xor(q2p, 1); q2p += __shfl_xor(q2p, 2); q2p += __shfl_xor(q2p, 4);
    if (j8 == 0) q2out[rg] = q2p;
  } else {
    float s = 0.f;
#pragma unroll
    for (int t = 0; t < 16; ++t) {
      int c = (j8 << 4) + t;
      float v = yt[r8][c];
      v = v > 0.f ? v : 0.f;
      s = fmaf(v, v3s[c], s);
    }
    s += __shfl_xor(s, 1); s += __shfl_xor(s, 2); s += __shfl_xor(s, 4);
    if (j8 == 0) netout[rg] = s + c3[0];
  }
}

// ---------------- K5: build kslice-major key image + exact k2 norms -------------------
__global__ __launch_bounds__(256) void k5_keyimg(
    const float* __restrict__ keys, u32* __restrict__ keyimg,
    float* __restrict__ k2out)
{
  int tid = threadIdx.x;
  int p = blockIdx.x * 128 + (tid >> 1);   // padded key index
  int sub = tid & 1;
  int slice = p / SL_PAD;
  int within = p - slice * SL_PAD;
  int kb = within >> 6, kib = within & 63;
  u32* img = keyimg + (size_t)(slice * NB + kb) * IMG_U32;
  bool real = within < SL_REAL;

  u32 w[32];
  float ss = 0.f;
  if (real) {
    const float* kp = keys + (size_t)(slice * SL_REAL + within) * D_ + sub * 64;
#pragma unroll
    for (int i = 0; i < 16; ++i) {
      float4 x = *(const float4*)(kp + i * 4);
      ss = fmaf(x.x, x.x, fmaf(x.y, x.y, fmaf(x.z, x.z, fmaf(x.w, x.w, ss))));
      w[i * 2]     = bf16_rne(x.x) | (bf16_rne(x.y) << 16);
      w[i * 2 + 1] = bf16_rne(x.z) | (bf16_rne(x.w) << 16);
    }
  } else {
#pragma unroll
    for (int i = 0; i < 32; ++i) w[i] = 0;
  }
#pragma unroll
  for (int cc = 0; cc < 2; ++cc) {
    int c = sub * 2 + cc;
#pragma unroll
    for (int j = 0; j < 4; ++j) {
      u32x4 v = {w[cc*16 + j*4], w[cc*16 + j*4 + 1], w[cc*16 + j*4 + 2], w[cc*16 + j*4 + 3]};
      *(u32x4*)&img[c * 1024 + j * 256 + kib * 4] = v;
    }
  }
  float tot = ss + __shfl_xor(ss, 1);
  if (sub == 0) {
    u32 w0;
    if (real) {
      k2out[slice * SL_REAL + within] = tot;
      u32 h = bf16_rne(tot);
      float hf = __uint_as_float(h << 16);
      u32 lo = bf16_rne(tot - hf);
      w0 = h | (lo << 16);
    } else {
      w0 = 0x7FC07FC0u;   // NaN,NaN -> dd = NaN -> never selected
    }
    u32x4 v0 = {w0, 0, 0, 0};
    u32x4 z  = {0, 0, 0, 0};
    *(u32x4*)&img[4 * 1024 + 0 * 256 + kib * 4] = v0;
    *(u32x4*)&img[4 * 1024 + 1 * 256 + kib * 4] = z;
    *(u32x4*)&img[4 * 1024 + 2 * 256 + kib * 4] = z;
    *(u32x4*)&img[4 * 1024 + 3 * 256 + kib * 4] = z;
  }
}

// ---------------- K3 helper: single-wave bitonic sort of 256 u32 ----------------------
__device__ __forceinline__ void sort256_wave(u32* sb, int lane) {
  for (int k = 2; k <= 256; k <<= 1)
    for (int j = k >> 1; j > 0; j >>= 1) {
#pragma unroll
      for (int half = 0; half < 4; ++half) {
        int e = lane + (half << 6);
        int pp = e ^ j;
        if (pp > e) {
          u32 x = sb[e], y = sb[pp];
          bool up = ((e & k) == 0);
          if ((x > y) == up) { sb[e] = y; sb[pp] = x; }
        }
      }
      __builtin_amdgcn_wave_barrier();
    }
}

// branch-free sorted insert of c into ascending q[0..QT-1] (no-op when c >= q[QT-1])
#define INSERT_Q(QARR, CVAL) do {                                   \
    u32 c_ = (CVAL);                                                \
    _Pragma("unroll")                                               \
    for (int i_ = QT - 1; i_ >= 1; --i_) {                          \
      u32 mx_ = QARR[i_ - 1] > c_ ? QARR[i_ - 1] : c_;              \
      QARR[i_] = mx_ < QARR[i_] ? mx_ : QARR[i_];                   \
    }                                                               \
    QARR[0] = c_ < QARR[0] ? c_ : QARR[0];                          \
  } while (0)

#define CSWAP(A, B) do { u32 lo_ = (A) < (B) ? (A) : (B);           \
    u32 hi_ = (A) < (B) ? (B) : (A); (A) = lo_; (B) = hi_; } while (0)

// ---------------- K3: K=160 bf16 MFMA distance GEMM + register-queue top-k ------------
// 32 q-rows x 6250 keys per block; 1 row & 1 queue per lane.
__global__ __launch_bounds__(512, 8) void k3_knn(
    const ushort* __restrict__ qext2,  // [B][128] bf16 of (-2q)
    const float* __restrict__ q2g,
    const u32* __restrict__ keyimg,    // kslice-major images
    u32* __restrict__ lbuf)
{
  __shared__ u32 kbuf[2][IMG_U32];     // 2 x 20KB; aliased as merge buffer at the end

  int tid = threadIdx.x;
  int l = tid & 63, w = tid >> 6;
  int l15 = l & 15, l4 = l >> 4;
  int wr = w & 3, wc = w >> 2;         // wr: key quarter, wc: row half (16 rows each)
  int slice = blockIdx.x & 7;          // consecutive blocks -> different XCDs
  int rb = (blockIdx.x >> 3) << 5;     // 32 q rows per block

  // ---- B-frags (q side) in registers for the whole kernel ----
  bf16x8 bfr[4];
#pragma unroll
  for (int c = 0; c < 4; ++c) {
    const ushort* qp = qext2 + (size_t)(rb + wc * 16 + l15) * 128 + c * 32 + l4 * 8;
    bfr[c] = __builtin_bit_cast(bf16x8, *(const u32x4*)qp);
  }
  bf16x8 bk2;
  {
    u16x8 v = {0, 0, 0, 0, 0, 0, 0, 0};
    if (l4 == 0) { v[0] = 0x3F80; v[1] = 0x3F80; }
    bk2 = __builtin_bit_cast(bf16x8, v);
  }
  float q2v = q2g[rb + wc * 16 + l15];

  // ---- per-lane register top-QT queue (ONE row per lane) ----
  u32 topq[QT];
#pragma unroll
  for (int j = 0; j < QT; ++j) topq[j] = 0xFFFFFFFFu;

  const u32* imgbase = keyimg + (size_t)slice * NB * IMG_U32;

  auto stage = [&](int b, int t) {
    if (w < 5) {
      const u32* src = imgbase + (size_t)t * IMG_U32 + w * 1024 + l * 4;
      u32* dst = &kbuf[b][w * 1024];
#pragma unroll
      for (int i = 0; i < 4; ++i)
        gl_lds16(src + i * 256, dst + i * 256);
    }
  };

  stage(0, 0);
  __syncthreads();

  int cur = 0;
  for (int t = 0; t < NB; ++t) {
    if (t + 1 < NB) stage(cur ^ 1, t + 1);   // in flight across compute+selection

    f32x4 acc = {};
#pragma unroll
    for (int c = 0; c < 5; ++c) {
      bf16x8 a = __builtin_bit_cast(bf16x8,
          *(const u32x4*)&kbuf[cur][c * 1024 + l4 * 256 + (wr * 16 + l15) * 4]);
      acc = __builtin_amdgcn_mfma_f32_16x16x32_bf16(a, (c < 4) ? bfr[c] : bk2, acc, 0, 0, 0);
    }

    // ---- selection: dd = q2 + (-2*dot + k2); sort4 then ascending guarded inserts ---
    u32 cc[4];
#pragma unroll
    for (int r = 0; r < 4; ++r) {
      float dd = q2v + acc[r];
      cc[r] = (__float_as_uint(dd) & 0xFFFFE000u) |
              (u32)(t * BKEY + wr * 16 + (l4 << 2) + r);
    }
    CSWAP(cc[0], cc[1]); CSWAP(cc[2], cc[3]);
    CSWAP(cc[0], cc[2]); CSWAP(cc[1], cc[3]);
    CSWAP(cc[1], cc[2]);
    {
      bool go = true;
#pragma unroll
      for (int r = 0; r < 4; ++r) {
        go = go && __any(cc[r] < topq[QT - 1]);
        if (go) INSERT_Q(topq, cc[r]);
      }
    }

    __syncthreads();               // stage(t+1) drained; kbuf[cur] free
    cur ^= 1;
  }

  // ---- end-of-kernel merge: 16 slots x QT=16 per row = 256 -> exact top-50 ----------
  __syncthreads();
  u32* mb = &kbuf[0][0];           // [16 rows][256] = 16KB, fits in kbuf (40KB)

#pragma unroll 1
  for (int g = 0; g < 2; ++g) {    // row group: rows g*16 .. g*16+15
    if (wc == g) {
      u32* dst = mb + l15 * 256 + (wr * 4 + l4) * QT;
#pragma unroll
      for (int j = 0; j < QT; ++j) dst[j] = topq[j];
    }
    __syncthreads();

    // each wave sorts 2 rows (wave-private LDS regions)
#pragma unroll 1
    for (int rr = 0; rr < 2; ++rr)
      sort256_wave(mb + ((w << 1) + rr) * 256, l);

    // write exact top-50 per (row, slice)
#pragma unroll 1
    for (int rr = 0; rr < 2; ++rr) {
      int r = (w << 1) + rr;
      if (l < KNN) {
        int grow = rb + g * 16 + r;
        lbuf[((size_t)grow * NSLICE + slice) * CAP + l] = mb[r * 256 + l];
      }
    }
    __syncthreads();               // before next group's dump overwrites mb
  }
}

// ---------------- K4: merge 8x50 -> approx top-64 -> exact fp32 rerank -> output ------
__global__ __launch_bounds__(256) void k4_rerank(
    const u32* __restrict__ lbuf, const float* __restrict__ qrow,
    const float* __restrict__ q2g, const float* __restrict__ k2g,
    const float* __restrict__ keys, const float* __restrict__ memv,
    const float* __restrict__ net, float* __restrict__ out)
{
  __shared__ u64 sb[512];
  __shared__ float qs[128];
  __shared__ float part[4][RR];
  __shared__ u64 cand[RR];
  int b = blockIdx.x, t = threadIdx.x;
  if (t < 128) qs[t] = qrow[(size_t)b * D_ + t];
#pragma unroll
  for (int h = 0; h < 2; ++h) {
    int e = t + (h << 8);
    u64 v = ~0ull;
    if (e < NSLICE * KNN) {
      int s = e / KNN, j = e - s * KNN;
      u32 k32 = lbuf[((size_t)b * NSLICE + s) * CAP + j];
      v = ((u64)(k32 & 0xFFFFE000u) << 32) | (u32)(s * SL_REAL + (k32 & 0x1FFFu));
    }
    sb[e] = v;
  }
  __syncthreads();
  for (int k = 2; k <= 512; k <<= 1)
    for (int j = k >> 1; j > 0; j >>= 1) {
#pragma unroll
      for (int h = 0; h < 2; ++h) {
        int e = t + (h << 8);
        int p = e ^ j;
        if (p > e) {
          u64 x = sb[e], y = sb[p];
          bool up = ((e & k) == 0);
          if ((x > y) == up) { sb[e] = y; sb[p] = x; }
        }
      }
      __syncthreads();
    }

  // exact rerank of approx-top-RR
  int cid = t & 63, g = t >> 6;
  u32 gidx = (u32)sb[cid];
  const float* kp = keys + (size_t)gidx * D_ + g * 32;
  float dot = 0.f;
#pragma unroll
  for (int i = 0; i < 8; ++i) {
    float4 kv = *(const float4*)(kp + i * 4);
    float4 qv = *(const float4*)&qs[g * 32 + i * 4];
    dot = fmaf(kv.x, qv.x, dot); dot = fmaf(kv.y, qv.y, dot);
    dot = fmaf(kv.z, qv.z, dot); dot = fmaf(kv.w, qv.w, dot);
  }
  part[g][cid] = dot;
  __syncthreads();
  if (t < RR) {
    float dotf = part[0][t] + part[1][t] + part[2][t] + part[3][t];
    u32 gi = (u32)sb[t];
    float dd = q2g[b] + k2g[gi] - 2.0f * dotf;
    cand[t] = ((u64)__float_as_uint(dd) << 32) | gi;
  }
  __syncthreads();
  if (t < 64) {
    for (int k = 2; k <= 64; k <<= 1)
      for (int j = k >> 1; j > 0; j >>= 1) {
        u64 x = cand[t], y = cand[t ^ j];
        __builtin_amdgcn_wave_barrier();
        bool up = ((t & k) == 0);
        u64 mn = x < y ? x : y, mx = x < y ? y : x;
        cand[t] = ((t < (t ^ j)) == up) ? mn : mx;
        __builtin_amdgcn_wave_barrier();
      }
    u64 key = cand[t];
    float d = __uint_as_float((u32)(key >> 32));
    u32 idx = (u32)key;
    float w = 0.f, wv = 0.f;
    if (t < KNN) {
      float ww = 1.0f / (d + 1e-7f);
      w = ww;
      wv = ww * memv[idx];
    }
#pragma unroll
    for (int o = 1; o < 64; o <<= 1) {
      w += __shfl_xor(w, o);
      wv += __shfl_xor(wv, o);
    }
    if (t == 0) out[b] = 0.9f * (wv / w) + 0.1f * net[b];
  }
}

// ---------------- launch --------------------------------------------------------------
extern "C" void kernel_launch(void* const* d_in, const int* in_sizes, int n_in,
                              void* d_out, int out_size, void* d_ws, size_t ws_size,
                              hipStream_t stream)
{
  const float* states     = (const float*)d_in[0];
  const float* W1         = (const float*)d_in[1];
  const float* b1         = (const float*)d_in[2];
  const float* W2         = (const float*)d_in[3];
  const float* b2         = (const float*)d_in[4];
  const float* lng        = (const float*)d_in[5];
  const float* lnb        = (const float*)d_in[6];
  const float* mem_keys   = (const float*)d_in[7];
  const float* mem_values = (const float*)d_in[8];
  const float* V1         = (const float*)d_in[9];
  const float* c1         = (const float*)d_in[10];
  const float* V2         = (const float*)d_in[11];
  const float* c2         = (const float*)d_in[12];
  const float* V3         = (const float*)d_in[13];
  const float* c3         = (const float*)d_in[14];
  float* out = (float*)d_out;

  char* ws = (char*)d_ws;
  ushort* qext2 = (ushort*)(ws + 0);          // 1 MB
  float*  qrow  = (float*)(ws + 1048576);     // 2 MB
  float*  q2    = (float*)(ws + 3145728);     // 16 KB
  float*  net   = (float*)(ws + 3162112);     // 16 KB
  float*  k2g   = (float*)(ws + 3178496);     // 200 KB (ends 3383296)
  u32*  keyimg  = (u32*)(ws + 3383296);       // 16.06 MB (ends 19,439,616)
  u32*  lbuf    = (u32*)(ws + 19439616);      // 16.78 MB (ends 36,216,832)
  float* h  = (float*)(ws + 3383296);             // overlays keyimg (dead before k5)
  float* v1 = (float*)(ws + 3383296 + 4194304);

  k1_gemm<<<dim3(H_ / 64, B_ / 64, 2), 256, 0, stream>>>(states, W1, b1, V1, c1, h, v1);
  k2_fused<<<dim3(B_ / 32), 256, 0, stream>>>(0, h, W2, b2, lng, lnb, V3, c3, qext2, qrow, q2, net);
  k2_fused<<<dim3(B_ / 32), 256, 0, stream>>>(1, v1, V2, c2, lng, lnb, V3, c3, qext2, qrow, q2, net);
  k5_keyimg<<<dim3(NSLICE * SL_PAD / 128), 256, 0, stream>>>(mem_keys, keyimg, k2g);
  k3_knn<<<dim3((B_ / 32) * NSLICE), 512, 0, stream>>>(qext2, q2, keyimg, lbuf);
  k4_rerank<<<dim3(B_), 256, 0, stream>>>(lbuf, qrow, q2, k2g, mem_keys, mem_values, net, out);
}

// Round 13
// 272.393 us; speedup vs baseline: 3.3158x; 1.4973x over previous
//
#include <hip/hip_runtime.h>
#include <stdint.h>

#define B_   4096
#define S_   544
#define H_   256
#define D_   128
#define M_   50000
#define KNN  50
#define NSLICE 8
#define SL_REAL 6250
#define BKEY 64
#define NB   98                  // 64-key tiles per slice
#define SL_PAD (NB * BKEY)       // 6272
#define CAP  128
#define RR   64
#define IMG_U32 5120             // 5 chunks * 4 kslices * 64 keys * 4 u32 = 20KB
#define QT   8                   // per-lane queue depth (16 slots x 8 = 128 merge)

typedef unsigned long long u64;
typedef unsigned int u32;
typedef __attribute__((ext_vector_type(8))) __bf16 bf16x8;
typedef __attribute__((ext_vector_type(8))) unsigned short u16x8;
typedef __attribute__((ext_vector_type(4))) float f32x4;
typedef __attribute__((ext_vector_type(4))) u32 u32x4;

__device__ __forceinline__ u32 bf16_rne(float x) {
  u32 u = __float_as_uint(x);
  return (u + 0x7FFFu + ((u >> 16) & 1u)) >> 16;
}

__device__ __forceinline__ void gl_lds16(const u32* g, u32* l) {
  __builtin_amdgcn_global_load_lds(
      (const __attribute__((address_space(1))) u32*)g,
      (__attribute__((address_space(3))) u32*)l, 16, 0, 0);
}

// ---------------- K1: h = relu(states@W1+b1) (z=0), v1 = relu(states@V1+c1) (z=1) ----
__global__ __launch_bounds__(256) void k1_gemm(
    const float* __restrict__ A,
    const float* __restrict__ W1, const float* __restrict__ b1,
    const float* __restrict__ V1, const float* __restrict__ c1,
    float* __restrict__ hout, float* __restrict__ v1out)
{
  const float* W    = (blockIdx.z == 0) ? W1 : V1;
  const float* bias = (blockIdx.z == 0) ? b1 : c1;
  float* out        = (blockIdx.z == 0) ? hout : v1out;

  __shared__ float as[16][68];
  __shared__ float bs[16][64];

  int tid = threadIdx.x;
  int tx = tid & 15, ty = tid >> 4;
  int rb = blockIdx.y * 64, cb = blockIdx.x * 64;

  float acc[4][4] = {};

  for (int k0 = 0; k0 < S_; k0 += 16) {
    {
      int r = tid >> 2, k4 = (tid & 3) << 2;
      float4 a = *(const float4*)&A[(size_t)(rb + r) * S_ + k0 + k4];
      as[k4 + 0][r] = a.x; as[k4 + 1][r] = a.y;
      as[k4 + 2][r] = a.z; as[k4 + 3][r] = a.w;
    }
    {
      int kk = tid >> 4, c4 = (tid & 15) << 2;
      *(float4*)&bs[kk][c4] = *(const float4*)&W[(size_t)(k0 + kk) * H_ + cb + c4];
    }
    __syncthreads();
#pragma unroll
    for (int kk = 0; kk < 16; ++kk) {
      float4 a4 = *(const float4*)&as[kk][ty << 2];
      float4 b4 = *(const float4*)&bs[kk][tx << 2];
      float av[4] = {a4.x, a4.y, a4.z, a4.w};
      float bv[4] = {b4.x, b4.y, b4.z, b4.w};
#pragma unroll
      for (int i = 0; i < 4; ++i)
#pragma unroll
        for (int j = 0; j < 4; ++j)
          acc[i][j] = fmaf(av[i], bv[j], acc[i][j]);
    }
    __syncthreads();
  }

#pragma unroll
  for (int i = 0; i < 4; ++i) {
    int r = rb + (ty << 2) + i;
#pragma unroll
    for (int j = 0; j < 4; ++j) {
      int c = cb + (tx << 2) + j;
      float v = acc[i][j] + bias[c];
      out[(size_t)r * H_ + c] = v > 0.0f ? v : 0.0f;
    }
  }
}

// ---------------- K2 (z=0): q = LN(h@W2+b2) -> qrow(f32), qext2(bf16 of -2q), q2
//                  (z=1): v2 = relu(v1@V2+c2); net = v2@V3 + c3 -----------------------
__global__ __launch_bounds__(256) void k2_fused(
    const float* __restrict__ A0,     // h  [B_][H_]
    const float* __restrict__ A1,     // v1 [B_][H_]
    const float* __restrict__ W2, const float* __restrict__ b2,
    const float* __restrict__ V2, const float* __restrict__ c2,
    const float* __restrict__ lng, const float* __restrict__ lnb,
    const float* __restrict__ V3, const float* __restrict__ c3,
    ushort* __restrict__ qext2, float* __restrict__ qrow,
    float* __restrict__ q2out, float* __restrict__ netout)
{
  __shared__ float as[32][36];
  __shared__ float bs[32][132];
  __shared__ float yt[32][132];
  __shared__ float v3s[128];

  int mode = blockIdx.z;
  const float* A    = mode ? A1 : A0;
  const float* W    = mode ? V2 : W2;
  const float* bias = mode ? c2 : b2;

  int tid = threadIdx.x;
  int tx = tid & 31, ty = tid >> 5;
  int rb = blockIdx.x * 32;

  if (mode == 1 && tid < 128) v3s[tid] = V3[tid];

  float acc[4][4] = {};

  for (int k0 = 0; k0 < H_; k0 += 32) {
    {
      int r = tid >> 3, k4 = (tid & 7) << 2;
      float4 a = *(const float4*)&A[(size_t)(rb + r) * H_ + k0 + k4];
      as[k4 + 0][r] = a.x; as[k4 + 1][r] = a.y;
      as[k4 + 2][r] = a.z; as[k4 + 3][r] = a.w;
    }
    {
      int kk = tid >> 3, c16 = (tid & 7) << 4;
#pragma unroll
      for (int t = 0; t < 4; ++t)
        *(float4*)&bs[kk][c16 + (t << 2)] =
            *(const float4*)&W[(size_t)(k0 + kk) * D_ + c16 + (t << 2)];
    }
    __syncthreads();
#pragma unroll
    for (int kk = 0; kk < 32; ++kk) {
      float4 a4 = *(const float4*)&as[kk][ty << 2];
      float4 b4 = *(const float4*)&bs[kk][tx << 2];
      float av[4] = {a4.x, a4.y, a4.z, a4.w};
      float bv[4] = {b4.x, b4.y, b4.z, b4.w};
#pragma unroll
      for (int i = 0; i < 4; ++i)
#pragma unroll
        for (int j = 0; j < 4; ++j)
          acc[i][j] = fmaf(av[i], bv[j], acc[i][j]);
    }
    __syncthreads();
  }

#pragma unroll
  for (int i = 0; i < 4; ++i)
#pragma unroll
    for (int j = 0; j < 4; ++j) {
      int c = (tx << 2) + j;
      yt[(ty << 2) + i][c] = acc[i][j] + bias[c];
    }
  __syncthreads();

  int r8 = tid >> 3, j8 = tid & 7;
  int rg = rb + r8;
  if (mode == 0) {
    float s = 0.f;
#pragma unroll
    for (int t = 0; t < 16; ++t) s += yt[r8][(j8 << 4) + t];
    s += __shfl_xor(s, 1); s += __shfl_xor(s, 2); s += __shfl_xor(s, 4);
    float mu = s * (1.0f / 128.0f);
    float vs = 0.f;
#pragma unroll
    for (int t = 0; t < 16; ++t) {
      float d = yt[r8][(j8 << 4) + t] - mu;
      vs = fmaf(d, d, vs);
    }
    vs += __shfl_xor(vs, 1); vs += __shfl_xor(vs, 2); vs += __shfl_xor(vs, 4);
    float var = vs * (1.0f / 128.0f);
    float rstd = 1.0f / sqrtf(var + 1e-5f);
    float q2p = 0.f;
    ushort* qe = qext2 + (size_t)rg * 128;
#pragma unroll
    for (int t = 0; t < 16; ++t) {
      int c = (j8 << 4) + t;
      float qv = (yt[r8][c] - mu) * rstd * lng[c] + lnb[c];
      qrow[(size_t)rg * D_ + c] = qv;
      qe[c] = (ushort)bf16_rne(-2.0f * qv);
      q2p = fmaf(qv, qv, q2p);
    }
    q2p += __shfl_xor(q2p, 1); q2p += __shfl_xor(q2p, 2); q2p += __shfl_xor(q2p, 4);
    if (j8 == 0) q2out[rg] = q2p;
  } else {
    float s = 0.f;
#pragma unroll
    for (int t = 0; t < 16; ++t) {
      int c = (j8 << 4) + t;
      float v = yt[r8][c];
      v = v > 0.f ? v : 0.f;
      s = fmaf(v, v3s[c], s);
    }
    s += __shfl_xor(s, 1); s += __shfl_xor(s, 2); s += __shfl_xor(s, 4);
    if (j8 == 0) netout[rg] = s + c3[0];
  }
}

// ---------------- K5: build kslice-major key image + exact k2 norms -------------------
__global__ __launch_bounds__(256) void k5_keyimg(
    const float* __restrict__ keys, u32* __restrict__ keyimg,
    float* __restrict__ k2out)
{
  int tid = threadIdx.x;
  int p = blockIdx.x * 128 + (tid >> 1);   // padded key index
  int sub = tid & 1;
  int slice = p / SL_PAD;
  int within = p - slice * SL_PAD;
  int kb = within >> 6, kib = within & 63;
  u32* img = keyimg + (size_t)(slice * NB + kb) * IMG_U32;
  bool real = within < SL_REAL;

  u32 w[32];
  float ss = 0.f;
  if (real) {
    const float* kp = keys + (size_t)(slice * SL_REAL + within) * D_ + sub * 64;
#pragma unroll
    for (int i = 0; i < 16; ++i) {
      float4 x = *(const float4*)(kp + i * 4);
      ss = fmaf(x.x, x.x, fmaf(x.y, x.y, fmaf(x.z, x.z, fmaf(x.w, x.w, ss))));
      w[i * 2]     = bf16_rne(x.x) | (bf16_rne(x.y) << 16);
      w[i * 2 + 1] = bf16_rne(x.z) | (bf16_rne(x.w) << 16);
    }
  } else {
#pragma unroll
    for (int i = 0; i < 32; ++i) w[i] = 0;
  }
#pragma unroll
  for (int cc = 0; cc < 2; ++cc) {
    int c = sub * 2 + cc;
#pragma unroll
    for (int j = 0; j < 4; ++j) {
      u32x4 v = {w[cc*16 + j*4], w[cc*16 + j*4 + 1], w[cc*16 + j*4 + 2], w[cc*16 + j*4 + 3]};
      *(u32x4*)&img[c * 1024 + j * 256 + kib * 4] = v;
    }
  }
  float tot = ss + __shfl_xor(ss, 1);
  if (sub == 0) {
    u32 w0;
    if (real) {
      k2out[slice * SL_REAL + within] = tot;
      u32 h = bf16_rne(tot);
      float hf = __uint_as_float(h << 16);
      u32 lo = bf16_rne(tot - hf);
      w0 = h | (lo << 16);
    } else {
      w0 = 0x7FC07FC0u;   // NaN,NaN -> dd = NaN -> never selected
    }
    u32x4 v0 = {w0, 0, 0, 0};
    u32x4 z  = {0, 0, 0, 0};
    *(u32x4*)&img[4 * 1024 + 0 * 256 + kib * 4] = v0;
    *(u32x4*)&img[4 * 1024 + 1 * 256 + kib * 4] = z;
    *(u32x4*)&img[4 * 1024 + 2 * 256 + kib * 4] = z;
    *(u32x4*)&img[4 * 1024 + 3 * 256 + kib * 4] = z;
  }
}

// ---------------- K3 helper: single-wave bitonic sort of 128 u32 ----------------------
__device__ __forceinline__ void sort128_wave(u32* sb, int lane) {
  for (int k = 2; k <= 128; k <<= 1)
    for (int j = k >> 1; j > 0; j >>= 1) {
#pragma unroll
      for (int half = 0; half < 2; ++half) {
        int e = lane + (half << 6);
        int pp = e ^ j;
        if (pp > e) {
          u32 x = sb[e], y = sb[pp];
          bool up = ((e & k) == 0);
          if ((x > y) == up) { sb[e] = y; sb[pp] = x; }
        }
      }
      __builtin_amdgcn_wave_barrier();
    }
}

// branch-free sorted insert of c into ascending q[0..QT-1] (no-op when c >= q[QT-1])
#define INSERT_Q(QARR, CVAL) do {                                   \
    u32 c_ = (CVAL);                                                \
    _Pragma("unroll")                                               \
    for (int i_ = QT - 1; i_ >= 1; --i_) {                          \
      u32 mx_ = QARR[i_ - 1] > c_ ? QARR[i_ - 1] : c_;              \
      QARR[i_] = mx_ < QARR[i_] ? mx_ : QARR[i_];                   \
    }                                                               \
    QARR[0] = c_ < QARR[0] ? c_ : QARR[0];                          \
  } while (0)

#define CSWAP(A, B) do { u32 lo_ = (A) < (B) ? (A) : (B);           \
    u32 hi_ = (A) < (B) ? (B) : (A); (A) = lo_; (B) = hi_; } while (0)

// ---------------- K3: K=160 bf16 MFMA distance GEMM + register-queue top-k ------------
// 32 q-rows x 6250 keys per block; 1 row & 1 queue per lane.
__global__ __launch_bounds__(512, 8) void k3_knn(
    const ushort* __restrict__ qext2,  // [B][128] bf16 of (-2q)
    const float* __restrict__ q2g,
    const u32* __restrict__ keyimg,    // kslice-major images
    u32* __restrict__ lbuf)
{
  __shared__ u32 kbuf[2][IMG_U32];     // 2 x 20KB; aliased as merge buffer at the end

  int tid = threadIdx.x;
  int l = tid & 63, w = tid >> 6;
  int l15 = l & 15, l4 = l >> 4;
  int wr = w & 3, wc = w >> 2;         // wr: key quarter, wc: row half (16 rows each)
  int slice = blockIdx.x & 7;          // consecutive blocks -> different XCDs
  int rb = (blockIdx.x >> 3) << 5;     // 32 q rows per block

  // ---- B-frags (q side) in registers for the whole kernel ----
  bf16x8 bfr[4];
#pragma unroll
  for (int c = 0; c < 4; ++c) {
    const ushort* qp = qext2 + (size_t)(rb + wc * 16 + l15) * 128 + c * 32 + l4 * 8;
    bfr[c] = __builtin_bit_cast(bf16x8, *(const u32x4*)qp);
  }
  bf16x8 bk2;
  {
    u16x8 v = {0, 0, 0, 0, 0, 0, 0, 0};
    if (l4 == 0) { v[0] = 0x3F80; v[1] = 0x3F80; }
    bk2 = __builtin_bit_cast(bf16x8, v);
  }
  float q2v = q2g[rb + wc * 16 + l15];

  // ---- per-lane register top-QT queue (ONE row per lane) ----
  u32 topq[QT];
#pragma unroll
  for (int j = 0; j < QT; ++j) topq[j] = 0xFFFFFFFFu;

  const u32* imgbase = keyimg + (size_t)slice * NB * IMG_U32;

  auto stage = [&](int b, int t) {
    if (w < 5) {
      const u32* src = imgbase + (size_t)t * IMG_U32 + w * 1024 + l * 4;
      u32* dst = &kbuf[b][w * 1024];
#pragma unroll
      for (int i = 0; i < 4; ++i)
        gl_lds16(src + i * 256, dst + i * 256);
    }
  };

  stage(0, 0);
  __syncthreads();

  int cur = 0;
  for (int t = 0; t < NB; ++t) {
    if (t + 1 < NB) stage(cur ^ 1, t + 1);   // in flight across compute+selection

    f32x4 acc = {};
#pragma unroll
    for (int c = 0; c < 5; ++c) {
      bf16x8 a = __builtin_bit_cast(bf16x8,
          *(const u32x4*)&kbuf[cur][c * 1024 + l4 * 256 + (wr * 16 + l15) * 4]);
      acc = __builtin_amdgcn_mfma_f32_16x16x32_bf16(a, (c < 4) ? bfr[c] : bk2, acc, 0, 0, 0);
    }

    // ---- selection: dd = q2 + (-2*dot + k2); sort4 then ascending guarded inserts ---
    u32 cc[4];
#pragma unroll
    for (int r = 0; r < 4; ++r) {
      float dd = q2v + acc[r];
      cc[r] = (__float_as_uint(dd) & 0xFFFFE000u) |
              (u32)(t * BKEY + wr * 16 + (l4 << 2) + r);
    }
    CSWAP(cc[0], cc[1]); CSWAP(cc[2], cc[3]);
    CSWAP(cc[0], cc[2]); CSWAP(cc[1], cc[3]);
    CSWAP(cc[1], cc[2]);
    {
      bool go = true;
#pragma unroll
      for (int r = 0; r < 4; ++r) {
        go = go && __any(cc[r] < topq[QT - 1]);
        if (go) INSERT_Q(topq, cc[r]);
      }
    }

    __syncthreads();               // stage(t+1) drained; kbuf[cur] free
    cur ^= 1;
  }

  // ---- end-of-kernel merge: 16 slots x QT=8 per row = 128 -> exact top-50 -----------
  __syncthreads();
  u32* mb = &kbuf[0][0];           // [16 rows][128] = 8KB, fits in kbuf (40KB)

#pragma unroll 1
  for (int g = 0; g < 2; ++g) {    // row group: rows g*16 .. g*16+15
    if (wc == g) {
      u32* dst = mb + l15 * 128 + (wr * 4 + l4) * QT;
#pragma unroll
      for (int j = 0; j < QT; ++j) dst[j] = topq[j];
    }
    __syncthreads();

    // each wave sorts 2 rows (wave-private LDS regions)
#pragma unroll 1
    for (int rr = 0; rr < 2; ++rr)
      sort128_wave(mb + ((w << 1) + rr) * 128, l);

    // write exact top-50 per (row, slice)
#pragma unroll 1
    for (int rr = 0; rr < 2; ++rr) {
      int r = (w << 1) + rr;
      if (l < KNN) {
        int grow = rb + g * 16 + r;
        lbuf[((size_t)grow * NSLICE + slice) * CAP + l] = mb[r * 128 + l];
      }
    }
    __syncthreads();               // before next group's dump overwrites mb
  }
}

// ---------------- K4: merge 8x50 -> approx top-64 -> exact fp32 rerank -> output ------
__global__ __launch_bounds__(256) void k4_rerank(
    const u32* __restrict__ lbuf, const float* __restrict__ qrow,
    const float* __restrict__ q2g, const float* __restrict__ k2g,
    const float* __restrict__ keys, const float* __restrict__ memv,
    const float* __restrict__ net, float* __restrict__ out)
{
  __shared__ u64 sb[512];
  __shared__ float qs[128];
  __shared__ float part[4][RR];
  __shared__ u64 cand[RR];
  int b = blockIdx.x, t = threadIdx.x;
  if (t < 128) qs[t] = qrow[(size_t)b * D_ + t];
#pragma unroll
  for (int h = 0; h < 2; ++h) {
    int e = t + (h << 8);
    u64 v = ~0ull;
    if (e < NSLICE * KNN) {
      int s = e / KNN, j = e - s * KNN;
      u32 k32 = lbuf[((size_t)b * NSLICE + s) * CAP + j];
      v = ((u64)(k32 & 0xFFFFE000u) << 32) | (u32)(s * SL_REAL + (k32 & 0x1FFFu));
    }
    sb[e] = v;
  }
  __syncthreads();
  for (int k = 2; k <= 512; k <<= 1)
    for (int j = k >> 1; j > 0; j >>= 1) {
#pragma unroll
      for (int h = 0; h < 2; ++h) {
        int e = t + (h << 8);
        int p = e ^ j;
        if (p > e) {
          u64 x = sb[e], y = sb[p];
          bool up = ((e & k) == 0);
          if ((x > y) == up) { sb[e] = y; sb[p] = x; }
        }
      }
      __syncthreads();
    }

  // exact rerank of approx-top-RR
  int cid = t & 63, g = t >> 6;
  u32 gidx = (u32)sb[cid];
  const float* kp = keys + (size_t)gidx * D_ + g * 32;
  float dot = 0.f;
#pragma unroll
  for (int i = 0; i < 8; ++i) {
    float4 kv = *(const float4*)(kp + i * 4);
    float4 qv = *(const float4*)&qs[g * 32 + i * 4];
    dot = fmaf(kv.x, qv.x, dot); dot = fmaf(kv.y, qv.y, dot);
    dot = fmaf(kv.z, qv.z, dot); dot = fmaf(kv.w, qv.w, dot);
  }
  part[g][cid] = dot;
  __syncthreads();
  if (t < RR) {
    float dotf = part[0][t] + part[1][t] + part[2][t] + part[3][t];
    u32 gi = (u32)sb[t];
    float dd = q2g[b] + k2g[gi] - 2.0f * dotf;
    cand[t] = ((u64)__float_as_uint(dd) << 32) | gi;
  }
  __syncthreads();
  if (t < 64) {
    for (int k = 2; k <= 64; k <<= 1)
      for (int j = k >> 1; j > 0; j >>= 1) {
        u64 x = cand[t], y = cand[t ^ j];
        __builtin_amdgcn_wave_barrier();
        bool up = ((t & k) == 0);
        u64 mn = x < y ? x : y, mx = x < y ? y : x;
        cand[t] = ((t < (t ^ j)) == up) ? mn : mx;
        __builtin_amdgcn_wave_barrier();
      }
    u64 key = cand[t];
    float d = __uint_as_float((u32)(key >> 32));
    u32 idx = (u32)key;
    float w = 0.f, wv = 0.f;
    if (t < KNN) {
      float ww = 1.0f / (d + 1e-7f);
      w = ww;
      wv = ww * memv[idx];
    }
#pragma unroll
    for (int o = 1; o < 64; o <<= 1) {
      w += __shfl_xor(w, o);
      wv += __shfl_xor(wv, o);
    }
    if (t == 0) out[b] = 0.9f * (wv / w) + 0.1f * net[b];
  }
}

// ---------------- launch --------------------------------------------------------------
extern "C" void kernel_launch(void* const* d_in, const int* in_sizes, int n_in,
                              void* d_out, int out_size, void* d_ws, size_t ws_size,
                              hipStream_t stream)
{
  const float* states     = (const float*)d_in[0];
  const float* W1         = (const float*)d_in[1];
  const float* b1         = (const float*)d_in[2];
  const float* W2         = (const float*)d_in[3];
  const float* b2         = (const float*)d_in[4];
  const float* lng        = (const float*)d_in[5];
  const float* lnb        = (const float*)d_in[6];
  const float* mem_keys   = (const float*)d_in[7];
  const float* mem_values = (const float*)d_in[8];
  const float* V1         = (const float*)d_in[9];
  const float* c1         = (const float*)d_in[10];
  const float* V2         = (const float*)d_in[11];
  const float* c2         = (const float*)d_in[12];
  const float* V3         = (const float*)d_in[13];
  const float* c3         = (const float*)d_in[14];
  float* out = (float*)d_out;

  char* ws = (char*)d_ws;
  ushort* qext2 = (ushort*)(ws + 0);          // 1 MB
  float*  qrow  = (float*)(ws + 1048576);     // 2 MB
  float*  q2    = (float*)(ws + 3145728);     // 16 KB
  float*  net   = (float*)(ws + 3162112);     // 16 KB
  float*  k2g   = (float*)(ws + 3178496);     // 200 KB (ends 3383296)
  u32*  keyimg  = (u32*)(ws + 3383296);       // 16.06 MB (ends 19,439,616)
  u32*  lbuf    = (u32*)(ws + 19439616);      // 16.78 MB (ends 36,216,832)
  float* h  = (float*)(ws + 3383296);             // overlays keyimg (dead before k5)
  float* v1 = (float*)(ws + 3383296 + 4194304);

  k1_gemm<<<dim3(H_ / 64, B_ / 64, 2), 256, 0, stream>>>(states, W1, b1, V1, c1, h, v1);
  k2_fused<<<dim3(B_ / 32, 1, 2), 256, 0, stream>>>(h, v1, W2, b2, V2, c2, lng, lnb, V3, c3,
                                                    qext2, qrow, q2, net);
  k5_keyimg<<<dim3(NSLICE * SL_PAD / 128), 256, 0, stream>>>(mem_keys, keyimg, k2g);
  k3_knn<<<dim3((B_ / 32) * NSLICE), 512, 0, stream>>>(qext2, q2, keyimg, lbuf);
  k4_rerank<<<dim3(B_), 256, 0, stream>>>(lbuf, qrow, q2, k2g, mem_keys, mem_values, net, out);
}

// Round 14
// 268.983 us; speedup vs baseline: 3.3579x; 1.0127x over previous
//
#include <hip/hip_runtime.h>
#include <stdint.h>

#define B_   4096
#define S_   544
#define H_   256
#define D_   128
#define M_   50000
#define KNN  50
#define NSLICE 8
#define SL_REAL 6250
#define BKEY 64
#define NB   98                  // 64-key tiles per slice
#define SL_PAD (NB * BKEY)       // 6272
#define CAP  128
#define RR   64
#define IMG_U32 5120             // 5 chunks * 4 kslices * 64 keys * 4 u32 = 20KB
#define QT   8                   // per-lane queue depth (16 slots x 8 = 128 merge)

typedef unsigned long long u64;
typedef unsigned int u32;
typedef __attribute__((ext_vector_type(8))) __bf16 bf16x8;
typedef __attribute__((ext_vector_type(8))) unsigned short u16x8;
typedef __attribute__((ext_vector_type(4))) float f32x4;
typedef __attribute__((ext_vector_type(4))) u32 u32x4;

__device__ __forceinline__ u32 bf16_rne(float x) {
  u32 u = __float_as_uint(x);
  return (u + 0x7FFFu + ((u >> 16) & 1u)) >> 16;
}

__device__ __forceinline__ void gl_lds16(const u32* g, u32* l) {
  __builtin_amdgcn_global_load_lds(
      (const __attribute__((address_space(1))) u32*)g,
      (__attribute__((address_space(3))) u32*)l, 16, 0, 0);
}

// ---------------- K1: h = relu(states@W1+b1) (z=0), v1 = relu(states@V1+c1) (z=1) ----
__global__ __launch_bounds__(256) void k1_gemm(
    const float* __restrict__ A,
    const float* __restrict__ W1, const float* __restrict__ b1,
    const float* __restrict__ V1, const float* __restrict__ c1,
    float* __restrict__ hout, float* __restrict__ v1out)
{
  const float* W    = (blockIdx.z == 0) ? W1 : V1;
  const float* bias = (blockIdx.z == 0) ? b1 : c1;
  float* out        = (blockIdx.z == 0) ? hout : v1out;

  __shared__ float as[16][68];
  __shared__ float bs[16][64];

  int tid = threadIdx.x;
  int tx = tid & 15, ty = tid >> 4;
  int rb = blockIdx.y * 64, cb = blockIdx.x * 64;

  float acc[4][4] = {};

  for (int k0 = 0; k0 < S_; k0 += 16) {
    {
      int r = tid >> 2, k4 = (tid & 3) << 2;
      float4 a = *(const float4*)&A[(size_t)(rb + r) * S_ + k0 + k4];
      as[k4 + 0][r] = a.x; as[k4 + 1][r] = a.y;
      as[k4 + 2][r] = a.z; as[k4 + 3][r] = a.w;
    }
    {
      int kk = tid >> 4, c4 = (tid & 15) << 2;
      *(float4*)&bs[kk][c4] = *(const float4*)&W[(size_t)(k0 + kk) * H_ + cb + c4];
    }
    __syncthreads();
#pragma unroll
    for (int kk = 0; kk < 16; ++kk) {
      float4 a4 = *(const float4*)&as[kk][ty << 2];
      float4 b4 = *(const float4*)&bs[kk][tx << 2];
      float av[4] = {a4.x, a4.y, a4.z, a4.w};
      float bv[4] = {b4.x, b4.y, b4.z, b4.w};
#pragma unroll
      for (int i = 0; i < 4; ++i)
#pragma unroll
        for (int j = 0; j < 4; ++j)
          acc[i][j] = fmaf(av[i], bv[j], acc[i][j]);
    }
    __syncthreads();
  }

#pragma unroll
  for (int i = 0; i < 4; ++i) {
    int r = rb + (ty << 2) + i;
#pragma unroll
    for (int j = 0; j < 4; ++j) {
      int c = cb + (tx << 2) + j;
      float v = acc[i][j] + bias[c];
      out[(size_t)r * H_ + c] = v > 0.0f ? v : 0.0f;
    }
  }
}

// ---------------- K2 (z=0): q = LN(h@W2+b2) -> qrow(f32), qext2(bf16 of -2q), q2
//                  (z=1): v2 = relu(v1@V2+c2); net = v2@V3 + c3 -----------------------
__global__ __launch_bounds__(256) void k2_fused(
    const float* __restrict__ A0,     // h  [B_][H_]
    const float* __restrict__ A1,     // v1 [B_][H_]
    const float* __restrict__ W2, const float* __restrict__ b2,
    const float* __restrict__ V2, const float* __restrict__ c2,
    const float* __restrict__ lng, const float* __restrict__ lnb,
    const float* __restrict__ V3, const float* __restrict__ c3,
    ushort* __restrict__ qext2, float* __restrict__ qrow,
    float* __restrict__ q2out, float* __restrict__ netout)
{
  __shared__ float as[32][36];
  __shared__ float bs[32][132];
  __shared__ float yt[32][132];
  __shared__ float v3s[128];

  int mode = blockIdx.z;
  const float* A    = mode ? A1 : A0;
  const float* W    = mode ? V2 : W2;
  const float* bias = mode ? c2 : b2;

  int tid = threadIdx.x;
  int tx = tid & 31, ty = tid >> 5;
  int rb = blockIdx.x * 32;

  if (mode == 1 && tid < 128) v3s[tid] = V3[tid];

  float acc[4][4] = {};

  for (int k0 = 0; k0 < H_; k0 += 32) {
    {
      int r = tid >> 3, k4 = (tid & 7) << 2;
      float4 a = *(const float4*)&A[(size_t)(rb + r) * H_ + k0 + k4];
      as[k4 + 0][r] = a.x; as[k4 + 1][r] = a.y;
      as[k4 + 2][r] = a.z; as[k4 + 3][r] = a.w;
    }
    {
      int kk = tid >> 3, c16 = (tid & 7) << 4;
#pragma unroll
      for (int t = 0; t < 4; ++t)
        *(float4*)&bs[kk][c16 + (t << 2)] =
            *(const float4*)&W[(size_t)(k0 + kk) * D_ + c16 + (t << 2)];
    }
    __syncthreads();
#pragma unroll
    for (int kk = 0; kk < 32; ++kk) {
      float4 a4 = *(const float4*)&as[kk][ty << 2];
      float4 b4 = *(const float4*)&bs[kk][tx << 2];
      float av[4] = {a4.x, a4.y, a4.z, a4.w};
      float bv[4] = {b4.x, b4.y, b4.z, b4.w};
#pragma unroll
      for (int i = 0; i < 4; ++i)
#pragma unroll
        for (int j = 0; j < 4; ++j)
          acc[i][j] = fmaf(av[i], bv[j], acc[i][j]);
    }
    __syncthreads();
  }

#pragma unroll
  for (int i = 0; i < 4; ++i)
#pragma unroll
    for (int j = 0; j < 4; ++j) {
      int c = (tx << 2) + j;
      yt[(ty << 2) + i][c] = acc[i][j] + bias[c];
    }
  __syncthreads();

  int r8 = tid >> 3, j8 = tid & 7;
  int rg = rb + r8;
  if (mode == 0) {
    float s = 0.f;
#pragma unroll
    for (int t = 0; t < 16; ++t) s += yt[r8][(j8 << 4) + t];
    s += __shfl_xor(s, 1); s += __shfl_xor(s, 2); s += __shfl_xor(s, 4);
    float mu = s * (1.0f / 128.0f);
    float vs = 0.f;
#pragma unroll
    for (int t = 0; t < 16; ++t) {
      float d = yt[r8][(j8 << 4) + t] - mu;
      vs = fmaf(d, d, vs);
    }
    vs += __shfl_xor(vs, 1); vs += __shfl_xor(vs, 2); vs += __shfl_xor(vs, 4);
    float var = vs * (1.0f / 128.0f);
    float rstd = 1.0f / sqrtf(var + 1e-5f);
    float q2p = 0.f;
    ushort* qe = qext2 + (size_t)rg * 128;
#pragma unroll
    for (int t = 0; t < 16; ++t) {
      int c = (j8 << 4) + t;
      float qv = (yt[r8][c] - mu) * rstd * lng[c] + lnb[c];
      qrow[(size_t)rg * D_ + c] = qv;
      qe[c] = (ushort)bf16_rne(-2.0f * qv);
      q2p = fmaf(qv, qv, q2p);
    }
    q2p += __shfl_xor(q2p, 1); q2p += __shfl_xor(q2p, 2); q2p += __shfl_xor(q2p, 4);
    if (j8 == 0) q2out[rg] = q2p;
  } else {
    float s = 0.f;
#pragma unroll
    for (int t = 0; t < 16; ++t) {
      int c = (j8 << 4) + t;
      float v = yt[r8][c];
      v = v > 0.f ? v : 0.f;
      s = fmaf(v, v3s[c], s);
    }
    s += __shfl_xor(s, 1); s += __shfl_xor(s, 2); s += __shfl_xor(s, 4);
    if (j8 == 0) netout[rg] = s + c3[0];
  }
}

// ---------------- K5: build kslice-major key image + exact k2 norms -------------------
__global__ __launch_bounds__(256) void k5_keyimg(
    const float* __restrict__ keys, u32* __restrict__ keyimg,
    float* __restrict__ k2out)
{
  int tid = threadIdx.x;
  int p = blockIdx.x * 128 + (tid >> 1);   // padded key index
  int sub = tid & 1;
  int slice = p / SL_PAD;
  int within = p - slice * SL_PAD;
  int kb = within >> 6, kib = within & 63;
  u32* img = keyimg + (size_t)(slice * NB + kb) * IMG_U32;
  bool real = within < SL_REAL;

  u32 w[32];
  float ss = 0.f;
  if (real) {
    const float* kp = keys + (size_t)(slice * SL_REAL + within) * D_ + sub * 64;
#pragma unroll
    for (int i = 0; i < 16; ++i) {
      float4 x = *(const float4*)(kp + i * 4);
      ss = fmaf(x.x, x.x, fmaf(x.y, x.y, fmaf(x.z, x.z, fmaf(x.w, x.w, ss))));
      w[i * 2]     = bf16_rne(x.x) | (bf16_rne(x.y) << 16);
      w[i * 2 + 1] = bf16_rne(x.z) | (bf16_rne(x.w) << 16);
    }
  } else {
#pragma unroll
    for (int i = 0; i < 32; ++i) w[i] = 0;
  }
#pragma unroll
  for (int cc = 0; cc < 2; ++cc) {
    int c = sub * 2 + cc;
#pragma unroll
    for (int j = 0; j < 4; ++j) {
      u32x4 v = {w[cc*16 + j*4], w[cc*16 + j*4 + 1], w[cc*16 + j*4 + 2], w[cc*16 + j*4 + 3]};
      *(u32x4*)&img[c * 1024 + j * 256 + kib * 4] = v;
    }
  }
  float tot = ss + __shfl_xor(ss, 1);
  if (sub == 0) {
    u32 w0;
    if (real) {
      k2out[slice * SL_REAL + within] = tot;
      u32 h = bf16_rne(tot);
      float hf = __uint_as_float(h << 16);
      u32 lo = bf16_rne(tot - hf);
      w0 = h | (lo << 16);
    } else {
      w0 = 0x7FC07FC0u;   // NaN,NaN -> dd = NaN -> never selected
    }
    u32x4 v0 = {w0, 0, 0, 0};
    u32x4 z  = {0, 0, 0, 0};
    *(u32x4*)&img[4 * 1024 + 0 * 256 + kib * 4] = v0;
    *(u32x4*)&img[4 * 1024 + 1 * 256 + kib * 4] = z;
    *(u32x4*)&img[4 * 1024 + 2 * 256 + kib * 4] = z;
    *(u32x4*)&img[4 * 1024 + 3 * 256 + kib * 4] = z;
  }
}

// ---------------- K3 helper: single-wave bitonic sort of 128 u32 ----------------------
__device__ __forceinline__ void sort128_wave(u32* sb, int lane) {
  for (int k = 2; k <= 128; k <<= 1)
    for (int j = k >> 1; j > 0; j >>= 1) {
#pragma unroll
      for (int half = 0; half < 2; ++half) {
        int e = lane + (half << 6);
        int pp = e ^ j;
        if (pp > e) {
          u32 x = sb[e], y = sb[pp];
          bool up = ((e & k) == 0);
          if ((x > y) == up) { sb[e] = y; sb[pp] = x; }
        }
      }
      __builtin_amdgcn_wave_barrier();
    }
}

// branch-free sorted insert of c into ascending q[0..QT-1] (no-op when c >= q[QT-1])
#define INSERT_Q(QARR, CVAL) do {                                   \
    u32 c_ = (CVAL);                                                \
    _Pragma("unroll")                                               \
    for (int i_ = QT - 1; i_ >= 1; --i_) {                          \
      u32 mx_ = QARR[i_ - 1] > c_ ? QARR[i_ - 1] : c_;              \
      QARR[i_] = mx_ < QARR[i_] ? mx_ : QARR[i_];                   \
    }                                                               \
    QARR[0] = c_ < QARR[0] ? c_ : QARR[0];                          \
  } while (0)

#define CSWAP(A, B) do { u32 lo_ = (A) < (B) ? (A) : (B);           \
    u32 hi_ = (A) < (B) ? (B) : (A); (A) = lo_; (B) = hi_; } while (0)

// ---------------- K3: K=160 bf16 MFMA distance GEMM + register-queue top-k ------------
// 64 q-rows x 6250 keys per block; 16 waves (4 row-groups x 4 key-quarters);
// 1 row & 1 queue per lane -> identical slot structure (16 slots/row, QT=8).
__global__ __launch_bounds__(1024, 8) void k3_knn(
    const ushort* __restrict__ qext2,  // [B][128] bf16 of (-2q)
    const float* __restrict__ q2g,
    const u32* __restrict__ keyimg,    // kslice-major images
    u32* __restrict__ lbuf)
{
  __shared__ u32 kbuf[2][IMG_U32];     // 2 x 20KB; aliased as merge buffer at the end

  int tid = threadIdx.x;
  int l = tid & 63, w = tid >> 6;      // w: 0..15
  int l15 = l & 15, l4 = l >> 4;
  int wr = w & 3, wc = w >> 2;         // wr: key quarter, wc: row quarter (16 rows each)
  int slice = blockIdx.x & 7;          // consecutive blocks -> different XCDs
  int rb = (blockIdx.x >> 3) << 6;     // 64 q rows per block

  // ---- B-frags (q side) in registers for the whole kernel ----
  bf16x8 bfr[4];
#pragma unroll
  for (int c = 0; c < 4; ++c) {
    const ushort* qp = qext2 + (size_t)(rb + wc * 16 + l15) * 128 + c * 32 + l4 * 8;
    bfr[c] = __builtin_bit_cast(bf16x8, *(const u32x4*)qp);
  }
  bf16x8 bk2;
  {
    u16x8 v = {0, 0, 0, 0, 0, 0, 0, 0};
    if (l4 == 0) { v[0] = 0x3F80; v[1] = 0x3F80; }
    bk2 = __builtin_bit_cast(bf16x8, v);
  }
  float q2v = q2g[rb + wc * 16 + l15];

  // ---- per-lane register top-QT queue (ONE row per lane) ----
  u32 topq[QT];
#pragma unroll
  for (int j = 0; j < QT; ++j) topq[j] = 0xFFFFFFFFu;

  const u32* imgbase = keyimg + (size_t)slice * NB * IMG_U32;

  auto stage = [&](int b, int t) {
    if (w < 5) {
      const u32* src = imgbase + (size_t)t * IMG_U32 + w * 1024 + l * 4;
      u32* dst = &kbuf[b][w * 1024];
#pragma unroll
      for (int i = 0; i < 4; ++i)
        gl_lds16(src + i * 256, dst + i * 256);
    }
  };

  stage(0, 0);
  __syncthreads();

  int cur = 0;
  for (int t = 0; t < NB; ++t) {
    if (t + 1 < NB) stage(cur ^ 1, t + 1);   // in flight across compute+selection

    f32x4 acc = {};
#pragma unroll
    for (int c = 0; c < 5; ++c) {
      bf16x8 a = __builtin_bit_cast(bf16x8,
          *(const u32x4*)&kbuf[cur][c * 1024 + l4 * 256 + (wr * 16 + l15) * 4]);
      acc = __builtin_amdgcn_mfma_f32_16x16x32_bf16(a, (c < 4) ? bfr[c] : bk2, acc, 0, 0, 0);
    }

    // ---- selection: dd = q2 + (-2*dot + k2); sort4 then ascending guarded inserts ---
    u32 cc[4];
#pragma unroll
    for (int r = 0; r < 4; ++r) {
      float dd = q2v + acc[r];
      cc[r] = (__float_as_uint(dd) & 0xFFFFE000u) |
              (u32)(t * BKEY + wr * 16 + (l4 << 2) + r);
    }
    CSWAP(cc[0], cc[1]); CSWAP(cc[2], cc[3]);
    CSWAP(cc[0], cc[2]); CSWAP(cc[1], cc[3]);
    CSWAP(cc[1], cc[2]);
    {
      bool go = true;
#pragma unroll
      for (int r = 0; r < 4; ++r) {
        go = go && __any(cc[r] < topq[QT - 1]);
        if (go) INSERT_Q(topq, cc[r]);
      }
    }

    __syncthreads();               // stage(t+1) drained; kbuf[cur] free
    cur ^= 1;
  }

  // ---- end-of-kernel merge: 16 slots x QT=8 per row = 128 -> exact top-50 -----------
  __syncthreads();
  u32* mb = &kbuf[0][0];           // [16 rows][128] = 8KB, fits in kbuf (40KB)

#pragma unroll 1
  for (int g = 0; g < 4; ++g) {    // row group: rows g*16 .. g*16+15
    if (wc == g) {
      u32* dst = mb + l15 * 128 + (wr * 4 + l4) * QT;
#pragma unroll
      for (int j = 0; j < QT; ++j) dst[j] = topq[j];
    }
    __syncthreads();

    // each of the 16 waves sorts one row (wave-private LDS region)
    sort128_wave(mb + w * 128, l);

    // write exact top-50 per (row, slice)
    if (l < KNN) {
      int grow = rb + g * 16 + w;
      lbuf[((size_t)grow * NSLICE + slice) * CAP + l] = mb[w * 128 + l];
    }
    __syncthreads();               // before next group's dump overwrites mb
  }
}

// ---------------- K4: merge 8x50 -> approx top-64 -> exact fp32 rerank -> output ------
__global__ __launch_bounds__(256) void k4_rerank(
    const u32* __restrict__ lbuf, const float* __restrict__ qrow,
    const float* __restrict__ q2g, const float* __restrict__ k2g,
    const float* __restrict__ keys, const float* __restrict__ memv,
    const float* __restrict__ net, float* __restrict__ out)
{
  __shared__ u64 sb[512];
  __shared__ float qs[128];
  __shared__ float part[4][RR];
  __shared__ u64 cand[RR];
  int b = blockIdx.x, t = threadIdx.x;
  if (t < 128) qs[t] = qrow[(size_t)b * D_ + t];
#pragma unroll
  for (int h = 0; h < 2; ++h) {
    int e = t + (h << 8);
    u64 v = ~0ull;
    if (e < NSLICE * KNN) {
      int s = e / KNN, j = e - s * KNN;
      u32 k32 = lbuf[((size_t)b * NSLICE + s) * CAP + j];
      v = ((u64)(k32 & 0xFFFFE000u) << 32) | (u32)(s * SL_REAL + (k32 & 0x1FFFu));
    }
    sb[e] = v;
  }
  __syncthreads();
  for (int k = 2; k <= 512; k <<= 1)
    for (int j = k >> 1; j > 0; j >>= 1) {
#pragma unroll
      for (int h = 0; h < 2; ++h) {
        int e = t + (h << 8);
        int p = e ^ j;
        if (p > e) {
          u64 x = sb[e], y = sb[p];
          bool up = ((e & k) == 0);
          if ((x > y) == up) { sb[e] = y; sb[p] = x; }
        }
      }
      __syncthreads();
    }

  // exact rerank of approx-top-RR
  int cid = t & 63, g = t >> 6;
  u32 gidx = (u32)sb[cid];
  const float* kp = keys + (size_t)gidx * D_ + g * 32;
  float dot = 0.f;
#pragma unroll
  for (int i = 0; i < 8; ++i) {
    float4 kv = *(const float4*)(kp + i * 4);
    float4 qv = *(const float4*)&qs[g * 32 + i * 4];
    dot = fmaf(kv.x, qv.x, dot); dot = fmaf(kv.y, qv.y, dot);
    dot = fmaf(kv.z, qv.z, dot); dot = fmaf(kv.w, qv.w, dot);
  }
  part[g][cid] = dot;
  __syncthreads();
  if (t < RR) {
    float dotf = part[0][t] + part[1][t] + part[2][t] + part[3][t];
    u32 gi = (u32)sb[t];
    float dd = q2g[b] + k2g[gi] - 2.0f * dotf;
    cand[t] = ((u64)__float_as_uint(dd) << 32) | gi;
  }
  __syncthreads();
  if (t < 64) {
    for (int k = 2; k <= 64; k <<= 1)
      for (int j = k >> 1; j > 0; j >>= 1) {
        u64 x = cand[t], y = cand[t ^ j];
        __builtin_amdgcn_wave_barrier();
        bool up = ((t & k) == 0);
        u64 mn = x < y ? x : y, mx = x < y ? y : x;
        cand[t] = ((t < (t ^ j)) == up) ? mn : mx;
        __builtin_amdgcn_wave_barrier();
      }
    u64 key = cand[t];
    float d = __uint_as_float((u32)(key >> 32));
    u32 idx = (u32)key;
    float w = 0.f, wv = 0.f;
    if (t < KNN) {
      float ww = 1.0f / (d + 1e-7f);
      w = ww;
      wv = ww * memv[idx];
    }
#pragma unroll
    for (int o = 1; o < 64; o <<= 1) {
      w += __shfl_xor(w, o);
      wv += __shfl_xor(wv, o);
    }
    if (t == 0) out[b] = 0.9f * (wv / w) + 0.1f * net[b];
  }
}

// ---------------- launch --------------------------------------------------------------
extern "C" void kernel_launch(void* const* d_in, const int* in_sizes, int n_in,
                              void* d_out, int out_size, void* d_ws, size_t ws_size,
                              hipStream_t stream)
{
  const float* states     = (const float*)d_in[0];
  const float* W1         = (const float*)d_in[1];
  const float* b1         = (const float*)d_in[2];
  const float* W2         = (const float*)d_in[3];
  const float* b2         = (const float*)d_in[4];
  const float* lng        = (const float*)d_in[5];
  const float* lnb        = (const float*)d_in[6];
  const float* mem_keys   = (const float*)d_in[7];
  const float* mem_values = (const float*)d_in[8];
  const float* V1         = (const float*)d_in[9];
  const float* c1         = (const float*)d_in[10];
  const float* V2         = (const float*)d_in[11];
  const float* c2         = (const float*)d_in[12];
  const float* V3         = (const float*)d_in[13];
  const float* c3         = (const float*)d_in[14];
  float* out = (float*)d_out;

  char* ws = (char*)d_ws;
  ushort* qext2 = (ushort*)(ws + 0);          // 1 MB
  float*  qrow  = (float*)(ws + 1048576);     // 2 MB
  float*  q2    = (float*)(ws + 3145728);     // 16 KB
  float*  net   = (float*)(ws + 3162112);     // 16 KB
  float*  k2g   = (float*)(ws + 3178496);     // 200 KB (ends 3383296)
  u32*  keyimg  = (u32*)(ws + 3383296);       // 16.06 MB (ends 19,439,616)
  u32*  lbuf    = (u32*)(ws + 19439616);      // 16.78 MB (ends 36,216,832)
  float* h  = (float*)(ws + 3383296);             // overlays keyimg (dead before k5)
  float* v1 = (float*)(ws + 3383296 + 4194304);

  k1_gemm<<<dim3(H_ / 64, B_ / 64, 2), 256, 0, stream>>>(states, W1, b1, V1, c1, h, v1);
  k2_fused<<<dim3(B_ / 32, 1, 2), 256, 0, stream>>>(h, v1, W2, b2, V2, c2, lng, lnb, V3, c3,
                                                    qext2, qrow, q2, net);
  k5_keyimg<<<dim3(NSLICE * SL_PAD / 128), 256, 0, stream>>>(mem_keys, keyimg, k2g);
  k3_knn<<<dim3((B_ / 64) * NSLICE), 1024, 0, stream>>>(qext2, q2, keyimg, lbuf);
  k4_rerank<<<dim3(B_), 256, 0, stream>>>(lbuf, qrow, q2, k2g, mem_keys, mem_values, net, out);
}

// Round 15
// 259.674 us; speedup vs baseline: 3.4783x; 1.0358x over previous
//
#include <hip/hip_runtime.h>
#include <stdint.h>

#define B_   4096
#define S_   544
#define H_   256
#define D_   128
#define M_   50000
#define KNN  50
#define NSLICE 8
#define SL_REAL 6250
#define BKEY 64
#define NB   98                  // 64-key tiles per slice
#define SL_PAD (NB * BKEY)       // 6272
#define CAP  128
#define RR   64
#define IMG_U32 5120             // 5 chunks * 4 kslices * 64 keys * 4 u32 = 20KB
#define QT   8                   // per-lane queue depth (16 slots x 8 = 128 merge)

typedef unsigned long long u64;
typedef unsigned int u32;
typedef __attribute__((ext_vector_type(8))) __bf16 bf16x8;
typedef __attribute__((ext_vector_type(8))) unsigned short u16x8;
typedef __attribute__((ext_vector_type(4))) float f32x4;
typedef __attribute__((ext_vector_type(4))) u32 u32x4;

__device__ __forceinline__ u32 bf16_rne(float x) {
  u32 u = __float_as_uint(x);
  return (u + 0x7FFFu + ((u >> 16) & 1u)) >> 16;
}

__device__ __forceinline__ void gl_lds16(const u32* g, u32* l) {
  __builtin_amdgcn_global_load_lds(
      (const __attribute__((address_space(1))) u32*)g,
      (__attribute__((address_space(3))) u32*)l, 16, 0, 0);
}

// ---------------- K1: h = relu(states@W1+b1) (z=0), v1 = relu(states@V1+c1) (z=1) ----
__global__ __launch_bounds__(256) void k1_gemm(
    const float* __restrict__ A,
    const float* __restrict__ W1, const float* __restrict__ b1,
    const float* __restrict__ V1, const float* __restrict__ c1,
    float* __restrict__ hout, float* __restrict__ v1out)
{
  const float* W    = (blockIdx.z == 0) ? W1 : V1;
  const float* bias = (blockIdx.z == 0) ? b1 : c1;
  float* out        = (blockIdx.z == 0) ? hout : v1out;

  __shared__ float as[16][68];
  __shared__ float bs[16][64];

  int tid = threadIdx.x;
  int tx = tid & 15, ty = tid >> 4;
  int rb = blockIdx.y * 64, cb = blockIdx.x * 64;

  float acc[4][4] = {};

  for (int k0 = 0; k0 < S_; k0 += 16) {
    {
      int r = tid >> 2, k4 = (tid & 3) << 2;
      float4 a = *(const float4*)&A[(size_t)(rb + r) * S_ + k0 + k4];
      as[k4 + 0][r] = a.x; as[k4 + 1][r] = a.y;
      as[k4 + 2][r] = a.z; as[k4 + 3][r] = a.w;
    }
    {
      int kk = tid >> 4, c4 = (tid & 15) << 2;
      *(float4*)&bs[kk][c4] = *(const float4*)&W[(size_t)(k0 + kk) * H_ + cb + c4];
    }
    __syncthreads();
#pragma unroll
    for (int kk = 0; kk < 16; ++kk) {
      float4 a4 = *(const float4*)&as[kk][ty << 2];
      float4 b4 = *(const float4*)&bs[kk][tx << 2];
      float av[4] = {a4.x, a4.y, a4.z, a4.w};
      float bv[4] = {b4.x, b4.y, b4.z, b4.w};
#pragma unroll
      for (int i = 0; i < 4; ++i)
#pragma unroll
        for (int j = 0; j < 4; ++j)
          acc[i][j] = fmaf(av[i], bv[j], acc[i][j]);
    }
    __syncthreads();
  }

#pragma unroll
  for (int i = 0; i < 4; ++i) {
    int r = rb + (ty << 2) + i;
#pragma unroll
    for (int j = 0; j < 4; ++j) {
      int c = cb + (tx << 2) + j;
      float v = acc[i][j] + bias[c];
      out[(size_t)r * H_ + c] = v > 0.0f ? v : 0.0f;
    }
  }
}

// ---------------- K2 (z=0): q = LN(h@W2+b2) -> qrow(f32), qext2(bf16 of -2q), q2
//                  (z=1): v2 = relu(v1@V2+c2); net = v2@V3 + c3 -----------------------
__global__ __launch_bounds__(256) void k2_fused(
    const float* __restrict__ A0,     // h  [B_][H_]
    const float* __restrict__ A1,     // v1 [B_][H_]
    const float* __restrict__ W2, const float* __restrict__ b2,
    const float* __restrict__ V2, const float* __restrict__ c2,
    const float* __restrict__ lng, const float* __restrict__ lnb,
    const float* __restrict__ V3, const float* __restrict__ c3,
    ushort* __restrict__ qext2, float* __restrict__ qrow,
    float* __restrict__ q2out, float* __restrict__ netout)
{
  __shared__ float as[32][36];
  __shared__ float bs[32][132];
  __shared__ float yt[32][132];
  __shared__ float v3s[128];

  int mode = blockIdx.z;
  const float* A    = mode ? A1 : A0;
  const float* W    = mode ? V2 : W2;
  const float* bias = mode ? c2 : b2;

  int tid = threadIdx.x;
  int tx = tid & 31, ty = tid >> 5;
  int rb = blockIdx.x * 32;

  if (mode == 1 && tid < 128) v3s[tid] = V3[tid];

  float acc[4][4] = {};

  for (int k0 = 0; k0 < H_; k0 += 32) {
    {
      int r = tid >> 3, k4 = (tid & 7) << 2;
      float4 a = *(const float4*)&A[(size_t)(rb + r) * H_ + k0 + k4];
      as[k4 + 0][r] = a.x; as[k4 + 1][r] = a.y;
      as[k4 + 2][r] = a.z; as[k4 + 3][r] = a.w;
    }
    {
      int kk = tid >> 3, c16 = (tid & 7) << 4;
#pragma unroll
      for (int t = 0; t < 4; ++t)
        *(float4*)&bs[kk][c16 + (t << 2)] =
            *(const float4*)&W[(size_t)(k0 + kk) * D_ + c16 + (t << 2)];
    }
    __syncthreads();
#pragma unroll
    for (int kk = 0; kk < 32; ++kk) {
      float4 a4 = *(const float4*)&as[kk][ty << 2];
      float4 b4 = *(const float4*)&bs[kk][tx << 2];
      float av[4] = {a4.x, a4.y, a4.z, a4.w};
      float bv[4] = {b4.x, b4.y, b4.z, b4.w};
#pragma unroll
      for (int i = 0; i < 4; ++i)
#pragma unroll
        for (int j = 0; j < 4; ++j)
          acc[i][j] = fmaf(av[i], bv[j], acc[i][j]);
    }
    __syncthreads();
  }

#pragma unroll
  for (int i = 0; i < 4; ++i)
#pragma unroll
    for (int j = 0; j < 4; ++j) {
      int c = (tx << 2) + j;
      yt[(ty << 2) + i][c] = acc[i][j] + bias[c];
    }
  __syncthreads();

  int r8 = tid >> 3, j8 = tid & 7;
  int rg = rb + r8;
  if (mode == 0) {
    float s = 0.f;
#pragma unroll
    for (int t = 0; t < 16; ++t) s += yt[r8][(j8 << 4) + t];
    s += __shfl_xor(s, 1); s += __shfl_xor(s, 2); s += __shfl_xor(s, 4);
    float mu = s * (1.0f / 128.0f);
    float vs = 0.f;
#pragma unroll
    for (int t = 0; t < 16; ++t) {
      float d = yt[r8][(j8 << 4) + t] - mu;
      vs = fmaf(d, d, vs);
    }
    vs += __shfl_xor(vs, 1); vs += __shfl_xor(vs, 2); vs += __shfl_xor(vs, 4);
    float var = vs * (1.0f / 128.0f);
    float rstd = 1.0f / sqrtf(var + 1e-5f);
    float q2p = 0.f;
    ushort* qe = qext2 + (size_t)rg * 128;
#pragma unroll
    for (int t = 0; t < 16; ++t) {
      int c = (j8 << 4) + t;
      float qv = (yt[r8][c] - mu) * rstd * lng[c] + lnb[c];
      qrow[(size_t)rg * D_ + c] = qv;
      qe[c] = (ushort)bf16_rne(-2.0f * qv);
      q2p = fmaf(qv, qv, q2p);
    }
    q2p += __shfl_xor(q2p, 1); q2p += __shfl_xor(q2p, 2); q2p += __shfl_xor(q2p, 4);
    if (j8 == 0) q2out[rg] = q2p;
  } else {
    float s = 0.f;
#pragma unroll
    for (int t = 0; t < 16; ++t) {
      int c = (j8 << 4) + t;
      float v = yt[r8][c];
      v = v > 0.f ? v : 0.f;
      s = fmaf(v, v3s[c], s);
    }
    s += __shfl_xor(s, 1); s += __shfl_xor(s, 2); s += __shfl_xor(s, 4);
    if (j8 == 0) netout[rg] = s + c3[0];
  }
}

// ---------------- K5: build kslice-major key image + exact k2 norms -------------------
__global__ __launch_bounds__(256) void k5_keyimg(
    const float* __restrict__ keys, u32* __restrict__ keyimg,
    float* __restrict__ k2out)
{
  int tid = threadIdx.x;
  int p = blockIdx.x * 128 + (tid >> 1);   // padded key index
  int sub = tid & 1;
  int slice = p / SL_PAD;
  int within = p - slice * SL_PAD;
  int kb = within >> 6, kib = within & 63;
  u32* img = keyimg + (size_t)(slice * NB + kb) * IMG_U32;
  bool real = within < SL_REAL;

  u32 w[32];
  float ss = 0.f;
  if (real) {
    const float* kp = keys + (size_t)(slice * SL_REAL + within) * D_ + sub * 64;
#pragma unroll
    for (int i = 0; i < 16; ++i) {
      float4 x = *(const float4*)(kp + i * 4);
      ss = fmaf(x.x, x.x, fmaf(x.y, x.y, fmaf(x.z, x.z, fmaf(x.w, x.w, ss))));
      w[i * 2]     = bf16_rne(x.x) | (bf16_rne(x.y) << 16);
      w[i * 2 + 1] = bf16_rne(x.z) | (bf16_rne(x.w) << 16);
    }
  } else {
#pragma unroll
    for (int i = 0; i < 32; ++i) w[i] = 0;
  }
#pragma unroll
  for (int cc = 0; cc < 2; ++cc) {
    int c = sub * 2 + cc;
#pragma unroll
    for (int j = 0; j < 4; ++j) {
      u32x4 v = {w[cc*16 + j*4], w[cc*16 + j*4 + 1], w[cc*16 + j*4 + 2], w[cc*16 + j*4 + 3]};
      *(u32x4*)&img[c * 1024 + j * 256 + kib * 4] = v;
    }
  }
  float tot = ss + __shfl_xor(ss, 1);
  if (sub == 0) {
    u32 w0;
    if (real) {
      k2out[slice * SL_REAL + within] = tot;
      u32 h = bf16_rne(tot);
      float hf = __uint_as_float(h << 16);
      u32 lo = bf16_rne(tot - hf);
      w0 = h | (lo << 16);
    } else {
      w0 = 0x7FC07FC0u;   // NaN,NaN -> dd = NaN -> never selected
    }
    u32x4 v0 = {w0, 0, 0, 0};
    u32x4 z  = {0, 0, 0, 0};
    *(u32x4*)&img[4 * 1024 + 0 * 256 + kib * 4] = v0;
    *(u32x4*)&img[4 * 1024 + 1 * 256 + kib * 4] = z;
    *(u32x4*)&img[4 * 1024 + 2 * 256 + kib * 4] = z;
    *(u32x4*)&img[4 * 1024 + 3 * 256 + kib * 4] = z;
  }
}

// ---------------- K3 helper: single-wave bitonic sort of 128 u32 ----------------------
__device__ __forceinline__ void sort128_wave(u32* sb, int lane) {
  for (int k = 2; k <= 128; k <<= 1)
    for (int j = k >> 1; j > 0; j >>= 1) {
#pragma unroll
      for (int half = 0; half < 2; ++half) {
        int e = lane + (half << 6);
        int pp = e ^ j;
        if (pp > e) {
          u32 x = sb[e], y = sb[pp];
          bool up = ((e & k) == 0);
          if ((x > y) == up) { sb[e] = y; sb[pp] = x; }
        }
      }
      __builtin_amdgcn_wave_barrier();
    }
}

#define CSWAP(A, B) do { u32 lo_ = (A) < (B) ? (A) : (B);           \
    u32 hi_ = (A) < (B) ? (B) : (A); (A) = lo_; (B) = hi_; } while (0)

// ---------------- K3: K=160 bf16 MFMA distance GEMM + register-queue top-k ------------
// 64 q-rows x 6250 keys per block; 16 waves (4 row-groups x 4 key-quarters);
// 1 row & 1 queue per lane. Selection = branchless bitonic partial merge.
__global__ __launch_bounds__(1024, 8) void k3_knn(
    const ushort* __restrict__ qext2,  // [B][128] bf16 of (-2q)
    const float* __restrict__ q2g,
    const u32* __restrict__ keyimg,    // kslice-major images
    u32* __restrict__ lbuf)
{
  __shared__ u32 kbuf[2][IMG_U32];     // 2 x 20KB; aliased as merge buffer at the end

  int tid = threadIdx.x;
  int l = tid & 63, w = tid >> 6;      // w: 0..15
  int l15 = l & 15, l4 = l >> 4;
  int wr = w & 3, wc = w >> 2;         // wr: key quarter, wc: row quarter (16 rows each)
  int slice = blockIdx.x & 7;          // consecutive blocks -> different XCDs
  int rb = (blockIdx.x >> 3) << 6;     // 64 q rows per block

  // ---- B-frags (q side) in registers for the whole kernel ----
  bf16x8 bfr[4];
#pragma unroll
  for (int c = 0; c < 4; ++c) {
    const ushort* qp = qext2 + (size_t)(rb + wc * 16 + l15) * 128 + c * 32 + l4 * 8;
    bfr[c] = __builtin_bit_cast(bf16x8, *(const u32x4*)qp);
  }
  bf16x8 bk2;
  {
    u16x8 v = {0, 0, 0, 0, 0, 0, 0, 0};
    if (l4 == 0) { v[0] = 0x3F80; v[1] = 0x3F80; }
    bk2 = __builtin_bit_cast(bf16x8, v);
  }
  float q2v = q2g[rb + wc * 16 + l15];

  // ---- per-lane register top-QT queue (ONE row per lane), always sorted asc ----
  u32 topq[QT];
#pragma unroll
  for (int j = 0; j < QT; ++j) topq[j] = 0xFFFFFFFFu;

  const u32* imgbase = keyimg + (size_t)slice * NB * IMG_U32;

  auto stage = [&](int b, int t) {
    if (w < 5) {
      const u32* src = imgbase + (size_t)t * IMG_U32 + w * 1024 + l * 4;
      u32* dst = &kbuf[b][w * 1024];
#pragma unroll
      for (int i = 0; i < 4; ++i)
        gl_lds16(src + i * 256, dst + i * 256);
    }
  };

  stage(0, 0);
  __syncthreads();

  int cur = 0;
  for (int t = 0; t < NB; ++t) {
    if (t + 1 < NB) stage(cur ^ 1, t + 1);   // in flight across compute+selection

    f32x4 acc = {};
#pragma unroll
    for (int c = 0; c < 5; ++c) {
      bf16x8 a = __builtin_bit_cast(bf16x8,
          *(const u32x4*)&kbuf[cur][c * 1024 + l4 * 256 + (wr * 16 + l15) * 4]);
      acc = __builtin_amdgcn_mfma_f32_16x16x32_bf16(a, (c < 4) ? bfr[c] : bk2, acc, 0, 0, 0);
    }

    // ---- selection: dd = q2 + (-2*dot + k2) -> branchless partial merge into topq ---
    u32 cc[4];
#pragma unroll
    for (int r = 0; r < 4; ++r) {
      float dd = q2v + acc[r];
      cc[r] = (__float_as_uint(dd) & 0xFFFFE000u) |
              (u32)(t * BKEY + wr * 16 + (l4 << 2) + r);
    }
    // sort4 ascending
    CSWAP(cc[0], cc[1]); CSWAP(cc[2], cc[3]);
    CSWAP(cc[0], cc[2]); CSWAP(cc[1], cc[3]);
    CSWAP(cc[1], cc[2]);
    // reversed elementwise min: keeps bottom-8 of the 12, topq becomes bitonic
    topq[7] = topq[7] < cc[0] ? topq[7] : cc[0];
    topq[6] = topq[6] < cc[1] ? topq[6] : cc[1];
    topq[5] = topq[5] < cc[2] ? topq[5] : cc[2];
    topq[4] = topq[4] < cc[3] ? topq[4] : cc[3];
    // bitonic merge 8 -> sorted ascending
    CSWAP(topq[0], topq[4]); CSWAP(topq[1], topq[5]);
    CSWAP(topq[2], topq[6]); CSWAP(topq[3], topq[7]);
    CSWAP(topq[0], topq[2]); CSWAP(topq[1], topq[3]);
    CSWAP(topq[4], topq[6]); CSWAP(topq[5], topq[7]);
    CSWAP(topq[0], topq[1]); CSWAP(topq[2], topq[3]);
    CSWAP(topq[4], topq[5]); CSWAP(topq[6], topq[7]);

    __syncthreads();               // stage(t+1) drained; kbuf[cur] free
    cur ^= 1;
  }

  // ---- end-of-kernel merge: 16 slots x QT=8 per row = 128 -> exact top-50 -----------
  __syncthreads();
  u32* mb = &kbuf[0][0];           // [16 rows][128] = 8KB, fits in kbuf (40KB)

#pragma unroll 1
  for (int g = 0; g < 4; ++g) {    // row group: rows g*16 .. g*16+15
    if (wc == g) {
      u32* dst = mb + l15 * 128 + (wr * 4 + l4) * QT;
#pragma unroll
      for (int j = 0; j < QT; ++j) dst[j] = topq[j];
    }
    __syncthreads();

    // each of the 16 waves sorts one row (wave-private LDS region)
    sort128_wave(mb + w * 128, l);

    // write exact top-50 per (row, slice)
    if (l < KNN) {
      int grow = rb + g * 16 + w;
      lbuf[((size_t)grow * NSLICE + slice) * CAP + l] = mb[w * 128 + l];
    }
    __syncthreads();               // before next group's dump overwrites mb
  }
}

// ---------------- K4: merge 8x50 -> approx top-64 -> exact fp32 rerank -> output ------
__global__ __launch_bounds__(256) void k4_rerank(
    const u32* __restrict__ lbuf, const float* __restrict__ qrow,
    const float* __restrict__ q2g, const float* __restrict__ k2g,
    const float* __restrict__ keys, const float* __restrict__ memv,
    const float* __restrict__ net, float* __restrict__ out)
{
  __shared__ u64 sb[512];
  __shared__ float qs[128];
  __shared__ float part[4][RR];
  __shared__ u64 cand[RR];
  int b = blockIdx.x, t = threadIdx.x;
  if (t < 128) qs[t] = qrow[(size_t)b * D_ + t];
#pragma unroll
  for (int h = 0; h < 2; ++h) {
    int e = t + (h << 8);
    u64 v = ~0ull;
    if (e < NSLICE * KNN) {
      int s = e / KNN, j = e - s * KNN;
      u32 k32 = lbuf[((size_t)b * NSLICE + s) * CAP + j];
      v = ((u64)(k32 & 0xFFFFE000u) << 32) | (u32)(s * SL_REAL + (k32 & 0x1FFFu));
    }
    sb[e] = v;
  }
  __syncthreads();
  for (int k = 2; k <= 512; k <<= 1)
    for (int j = k >> 1; j > 0; j >>= 1) {
#pragma unroll
      for (int h = 0; h < 2; ++h) {
        int e = t + (h << 8);
        int p = e ^ j;
        if (p > e) {
          u64 x = sb[e], y = sb[p];
          bool up = ((e & k) == 0);
          if ((x > y) == up) { sb[e] = y; sb[p] = x; }
        }
      }
      __syncthreads();
    }

  // exact rerank of approx-top-RR
  int cid = t & 63, g = t >> 6;
  u32 gidx = (u32)sb[cid];
  const float* kp = keys + (size_t)gidx * D_ + g * 32;
  float dot = 0.f;
#pragma unroll
  for (int i = 0; i < 8; ++i) {
    float4 kv = *(const float4*)(kp + i * 4);
    float4 qv = *(const float4*)&qs[g * 32 + i * 4];
    dot = fmaf(kv.x, qv.x, dot); dot = fmaf(kv.y, qv.y, dot);
    dot = fmaf(kv.z, qv.z, dot); dot = fmaf(kv.w, qv.w, dot);
  }
  part[g][cid] = dot;
  __syncthreads();
  if (t < RR) {
    float dotf = part[0][t] + part[1][t] + part[2][t] + part[3][t];
    u32 gi = (u32)sb[t];
    float dd = q2g[b] + k2g[gi] - 2.0f * dotf;
    cand[t] = ((u64)__float_as_uint(dd) << 32) | gi;
  }
  __syncthreads();
  if (t < 64) {
    for (int k = 2; k <= 64; k <<= 1)
      for (int j = k >> 1; j > 0; j >>= 1) {
        u64 x = cand[t], y = cand[t ^ j];
        __builtin_amdgcn_wave_barrier();
        bool up = ((t & k) == 0);
        u64 mn = x < y ? x : y, mx = x < y ? y : x;
        cand[t] = ((t < (t ^ j)) == up) ? mn : mx;
        __builtin_amdgcn_wave_barrier();
      }
    u64 key = cand[t];
    float d = __uint_as_float((u32)(key >> 32));
    u32 idx = (u32)key;
    float w = 0.f, wv = 0.f;
    if (t < KNN) {
      float ww = 1.0f / (d + 1e-7f);
      w = ww;
      wv = ww * memv[idx];
    }
#pragma unroll
    for (int o = 1; o < 64; o <<= 1) {
      w += __shfl_xor(w, o);
      wv += __shfl_xor(wv, o);
    }
    if (t == 0) out[b] = 0.9f * (wv / w) + 0.1f * net[b];
  }
}

// ---------------- launch --------------------------------------------------------------
extern "C" void kernel_launch(void* const* d_in, const int* in_sizes, int n_in,
                              void* d_out, int out_size, void* d_ws, size_t ws_size,
                              hipStream_t stream)
{
  const float* states     = (const float*)d_in[0];
  const float* W1         = (const float*)d_in[1];
  const float* b1         = (const float*)d_in[2];
  const float* W2         = (const float*)d_in[3];
  const float* b2         = (const float*)d_in[4];
  const float* lng        = (const float*)d_in[5];
  const float* lnb        = (const float*)d_in[6];
  const float* mem_keys   = (const float*)d_in[7];
  const float* mem_values = (const float*)d_in[8];
  const float* V1         = (const float*)d_in[9];
  const float* c1         = (const float*)d_in[10];
  const float* V2         = (const float*)d_in[11];
  const float* c2         = (const float*)d_in[12];
  const float* V3         = (const float*)d_in[13];
  const float* c3         = (const float*)d_in[14];
  float* out = (float*)d_out;

  char* ws = (char*)d_ws;
  ushort* qext2 = (ushort*)(ws + 0);          // 1 MB
  float*  qrow  = (float*)(ws + 1048576);     // 2 MB
  float*  q2    = (float*)(ws + 3145728);     // 16 KB
  float*  net   = (float*)(ws + 3162112);     // 16 KB
  float*  k2g   = (float*)(ws + 3178496);     // 200 KB (ends 3383296)
  u32*  keyimg  = (u32*)(ws + 3383296);       // 16.06 MB (ends 19,439,616)
  u32*  lbuf    = (u32*)(ws + 19439616);      // 16.78 MB (ends 36,216,832)
  float* h  = (float*)(ws + 3383296);             // overlays keyimg (dead before k5)
  float* v1 = (float*)(ws + 3383296 + 4194304);

  k1_gemm<<<dim3(H_ / 64, B_ / 64, 2), 256, 0, stream>>>(states, W1, b1, V1, c1, h, v1);
  k2_fused<<<dim3(B_ / 32, 1, 2), 256, 0, stream>>>(h, v1, W2, b2, V2, c2, lng, lnb, V3, c3,
                                                    qext2, qrow, q2, net);
  k5_keyimg<<<dim3(NSLICE * SL_PAD / 128), 256, 0, stream>>>(mem_keys, keyimg, k2g);
  k3_knn<<<dim3((B_ / 64) * NSLICE), 1024, 0, stream>>>(qext2, q2, keyimg, lbuf);
  k4_rerank<<<dim3(B_), 256, 0, stream>>>(lbuf, qrow, q2, k2g, mem_keys, mem_values, net, out);
}

// Round 16
// 234.034 us; speedup vs baseline: 3.8593x; 1.1096x over previous
//
#include <hip/hip_runtime.h>
#include <stdint.h>

#define B_   4096
#define S_   544
#define H_   256
#define D_   128
#define M_   50000
#define KNN  50
#define NSLICE 8
#define SL_REAL 6250
#define BKEY 64
#define NB   98                  // 64-key tiles per slice
#define SL_PAD (NB * BKEY)       // 6272
#define CAP  64
#define RR   64
#define IMG_U32 5120             // 5 chunks * 4 kslices * 64 keys * 4 u32 = 20KB
#define QT   8                   // per-lane queue depth (16 slots x 8 = 128 merge)

typedef unsigned long long u64;
typedef unsigned int u32;
typedef __attribute__((ext_vector_type(8))) __bf16 bf16x8;
typedef __attribute__((ext_vector_type(8))) unsigned short u16x8;
typedef __attribute__((ext_vector_type(4))) float f32x4;
typedef __attribute__((ext_vector_type(4))) u32 u32x4;

__device__ __forceinline__ u32 bf16_rne(float x) {
  u32 u = __float_as_uint(x);
  return (u + 0x7FFFu + ((u >> 16) & 1u)) >> 16;
}

__device__ __forceinline__ void gl_lds16(const u32* g, u32* l) {
  __builtin_amdgcn_global_load_lds(
      (const __attribute__((address_space(1))) u32*)g,
      (__attribute__((address_space(3))) u32*)l, 16, 0, 0);
}

// ---------------- K15: fused k1 (h,v1 GEMMs) + k5 (key image + norms) -----------------
// blocks [0,512): h = relu(states@W1+b1) (z=0), v1 = relu(states@V1+c1) (z=1)
// blocks [512,904): kslice-major key image + exact k2 norms
__global__ __launch_bounds__(256) void k15_fused(
    const float* __restrict__ A,
    const float* __restrict__ W1, const float* __restrict__ b1,
    const float* __restrict__ V1, const float* __restrict__ c1,
    float* __restrict__ hout, float* __restrict__ v1out,
    const float* __restrict__ keys, u32* __restrict__ keyimg,
    float* __restrict__ k2out)
{
  __shared__ float as[16][68];
  __shared__ float bs[16][64];

  int tid = threadIdx.x;

  if (blockIdx.x < 512) {
    int bx = blockIdx.x;
    int cb = (bx & 3) * 64, rb = ((bx >> 2) & 63) * 64, zz = bx >> 8;
    const float* W    = (zz == 0) ? W1 : V1;
    const float* bias = (zz == 0) ? b1 : c1;
    float* out        = (zz == 0) ? hout : v1out;

    int tx = tid & 15, ty = tid >> 4;
    float acc[4][4] = {};

    for (int k0 = 0; k0 < S_; k0 += 16) {
      {
        int r = tid >> 2, k4 = (tid & 3) << 2;
        float4 a = *(const float4*)&A[(size_t)(rb + r) * S_ + k0 + k4];
        as[k4 + 0][r] = a.x; as[k4 + 1][r] = a.y;
        as[k4 + 2][r] = a.z; as[k4 + 3][r] = a.w;
      }
      {
        int kk = tid >> 4, c4 = (tid & 15) << 2;
        *(float4*)&bs[kk][c4] = *(const float4*)&W[(size_t)(k0 + kk) * H_ + cb + c4];
      }
      __syncthreads();
#pragma unroll
      for (int kk = 0; kk < 16; ++kk) {
        float4 a4 = *(const float4*)&as[kk][ty << 2];
        float4 b4 = *(const float4*)&bs[kk][tx << 2];
        float av[4] = {a4.x, a4.y, a4.z, a4.w};
        float bv[4] = {b4.x, b4.y, b4.z, b4.w};
#pragma unroll
        for (int i = 0; i < 4; ++i)
#pragma unroll
          for (int j = 0; j < 4; ++j)
            acc[i][j] = fmaf(av[i], bv[j], acc[i][j]);
      }
      __syncthreads();
    }

#pragma unroll
    for (int i = 0; i < 4; ++i) {
      int r = rb + (ty << 2) + i;
#pragma unroll
      for (int j = 0; j < 4; ++j) {
        int c = cb + (tx << 2) + j;
        float v = acc[i][j] + bias[c];
        out[(size_t)r * H_ + c] = v > 0.0f ? v : 0.0f;
      }
    }
    return;
  }

  // ---- k5 body ----
  int p = (blockIdx.x - 512) * 128 + (tid >> 1);   // padded key index
  int sub = tid & 1;
  int slice = p / SL_PAD;
  int within = p - slice * SL_PAD;
  int kb = within >> 6, kib = within & 63;
  u32* img = keyimg + (size_t)(slice * NB + kb) * IMG_U32;
  bool real = within < SL_REAL;

  u32 w[32];
  float ss = 0.f;
  if (real) {
    const float* kp = keys + (size_t)(slice * SL_REAL + within) * D_ + sub * 64;
#pragma unroll
    for (int i = 0; i < 16; ++i) {
      float4 x = *(const float4*)(kp + i * 4);
      ss = fmaf(x.x, x.x, fmaf(x.y, x.y, fmaf(x.z, x.z, fmaf(x.w, x.w, ss))));
      w[i * 2]     = bf16_rne(x.x) | (bf16_rne(x.y) << 16);
      w[i * 2 + 1] = bf16_rne(x.z) | (bf16_rne(x.w) << 16);
    }
  } else {
#pragma unroll
    for (int i = 0; i < 32; ++i) w[i] = 0;
  }
#pragma unroll
  for (int cc = 0; cc < 2; ++cc) {
    int c = sub * 2 + cc;
#pragma unroll
    for (int j = 0; j < 4; ++j) {
      u32x4 v = {w[cc*16 + j*4], w[cc*16 + j*4 + 1], w[cc*16 + j*4 + 2], w[cc*16 + j*4 + 3]};
      *(u32x4*)&img[c * 1024 + j * 256 + kib * 4] = v;
    }
  }
  float tot = ss + __shfl_xor(ss, 1);
  if (sub == 0) {
    u32 w0;
    if (real) {
      k2out[slice * SL_REAL + within] = tot;
      u32 h = bf16_rne(tot);
      float hf = __uint_as_float(h << 16);
      u32 lo = bf16_rne(tot - hf);
      w0 = h | (lo << 16);
    } else {
      w0 = 0x7FC07FC0u;   // NaN,NaN -> dd = NaN -> never selected
    }
    u32x4 v0 = {w0, 0, 0, 0};
    u32x4 z  = {0, 0, 0, 0};
    *(u32x4*)&img[4 * 1024 + 0 * 256 + kib * 4] = v0;
    *(u32x4*)&img[4 * 1024 + 1 * 256 + kib * 4] = z;
    *(u32x4*)&img[4 * 1024 + 2 * 256 + kib * 4] = z;
    *(u32x4*)&img[4 * 1024 + 3 * 256 + kib * 4] = z;
  }
}

// ---------------- K2 (z=0): q = LN(h@W2+b2) -> qrow(f32), qext2(bf16 of -2q), q2
//                  (z=1): v2 = relu(v1@V2+c2); net = v2@V3 + c3 -----------------------
__global__ __launch_bounds__(256) void k2_fused(
    const float* __restrict__ A0,     // h  [B_][H_]
    const float* __restrict__ A1,     // v1 [B_][H_]
    const float* __restrict__ W2, const float* __restrict__ b2,
    const float* __restrict__ V2, const float* __restrict__ c2,
    const float* __restrict__ lng, const float* __restrict__ lnb,
    const float* __restrict__ V3, const float* __restrict__ c3,
    ushort* __restrict__ qext2, float* __restrict__ qrow,
    float* __restrict__ q2out, float* __restrict__ netout)
{
  __shared__ float as[32][36];
  __shared__ float bs[32][132];
  __shared__ float yt[32][132];
  __shared__ float v3s[128];

  int mode = blockIdx.z;
  const float* A    = mode ? A1 : A0;
  const float* W    = mode ? V2 : W2;
  const float* bias = mode ? c2 : b2;

  int tid = threadIdx.x;
  int tx = tid & 31, ty = tid >> 5;
  int rb = blockIdx.x * 32;

  if (mode == 1 && tid < 128) v3s[tid] = V3[tid];

  float acc[4][4] = {};

  for (int k0 = 0; k0 < H_; k0 += 32) {
    {
      int r = tid >> 3, k4 = (tid & 7) << 2;
      float4 a = *(const float4*)&A[(size_t)(rb + r) * H_ + k0 + k4];
      as[k4 + 0][r] = a.x; as[k4 + 1][r] = a.y;
      as[k4 + 2][r] = a.z; as[k4 + 3][r] = a.w;
    }
    {
      int kk = tid >> 3, c16 = (tid & 7) << 4;
#pragma unroll
      for (int t = 0; t < 4; ++t)
        *(float4*)&bs[kk][c16 + (t << 2)] =
            *(const float4*)&W[(size_t)(k0 + kk) * D_ + c16 + (t << 2)];
    }
    __syncthreads();
#pragma unroll
    for (int kk = 0; kk < 32; ++kk) {
      float4 a4 = *(const float4*)&as[kk][ty << 2];
      float4 b4 = *(const float4*)&bs[kk][tx << 2];
      float av[4] = {a4.x, a4.y, a4.z, a4.w};
      float bv[4] = {b4.x, b4.y, b4.z, b4.w};
#pragma unroll
      for (int i = 0; i < 4; ++i)
#pragma unroll
        for (int j = 0; j < 4; ++j)
          acc[i][j] = fmaf(av[i], bv[j], acc[i][j]);
    }
    __syncthreads();
  }

#pragma unroll
  for (int i = 0; i < 4; ++i)
#pragma unroll
    for (int j = 0; j < 4; ++j) {
      int c = (tx << 2) + j;
      yt[(ty << 2) + i][c] = acc[i][j] + bias[c];
    }
  __syncthreads();

  int r8 = tid >> 3, j8 = tid & 7;
  int rg = rb + r8;
  if (mode == 0) {
    float s = 0.f;
#pragma unroll
    for (int t = 0; t < 16; ++t) s += yt[r8][(j8 << 4) + t];
    s += __shfl_xor(s, 1); s += __shfl_xor(s, 2); s += __shfl_xor(s, 4);
    float mu = s * (1.0f / 128.0f);
    float vs = 0.f;
#pragma unroll
    for (int t = 0; t < 16; ++t) {
      float d = yt[r8][(j8 << 4) + t] - mu;
      vs = fmaf(d, d, vs);
    }
    vs += __shfl_xor(vs, 1); vs += __shfl_xor(vs, 2); vs += __shfl_xor(vs, 4);
    float var = vs * (1.0f / 128.0f);
    float rstd = 1.0f / sqrtf(var + 1e-5f);
    float q2p = 0.f;
    ushort* qe = qext2 + (size_t)rg * 128;
#pragma unroll
    for (int t = 0; t < 16; ++t) {
      int c = (j8 << 4) + t;
      float qv = (yt[r8][c] - mu) * rstd * lng[c] + lnb[c];
      qrow[(size_t)rg * D_ + c] = qv;
      qe[c] = (ushort)bf16_rne(-2.0f * qv);
      q2p = fmaf(qv, qv, q2p);
    }
    q2p += __shfl_xor(q2p, 1); q2p += __shfl_xor(q2p, 2); q2p += __shfl_xor(q2p, 4);
    if (j8 == 0) q2out[rg] = q2p;
  } else {
    float s = 0.f;
#pragma unroll
    for (int t = 0; t < 16; ++t) {
      int c = (j8 << 4) + t;
      float v = yt[r8][c];
      v = v > 0.f ? v : 0.f;
      s = fmaf(v, v3s[c], s);
    }
    s += __shfl_xor(s, 1); s += __shfl_xor(s, 2); s += __shfl_xor(s, 4);
    if (j8 == 0) netout[rg] = s + c3[0];
  }
}

// ---------------- K3 helper: single-wave bitonic sort of 128 u32 ----------------------
__device__ __forceinline__ void sort128_wave(u32* sb, int lane) {
  for (int k = 2; k <= 128; k <<= 1)
    for (int j = k >> 1; j > 0; j >>= 1) {
#pragma unroll
      for (int half = 0; half < 2; ++half) {
        int e = lane + (half << 6);
        int pp = e ^ j;
        if (pp > e) {
          u32 x = sb[e], y = sb[pp];
          bool up = ((e & k) == 0);
          if ((x > y) == up) { sb[e] = y; sb[pp] = x; }
        }
      }
      __builtin_amdgcn_wave_barrier();
    }
}

#define CSWAP(A, B) do { u32 lo_ = (A) < (B) ? (A) : (B);           \
    u32 hi_ = (A) < (B) ? (B) : (A); (A) = lo_; (B) = hi_; } while (0)

// ---------------- K3: K=160 bf16 MFMA distance GEMM + register-queue top-k ------------
// 64 q-rows x 6250 keys per block; 16 waves; 2 tiles per barrier (4 LDS buffers).
__global__ __launch_bounds__(1024, 8) void k3_knn(
    const ushort* __restrict__ qext2,  // [B][128] bf16 of (-2q)
    const float* __restrict__ q2g,
    const u32* __restrict__ keyimg,    // kslice-major images
    u32* __restrict__ lbuf)
{
  __shared__ u32 kbuf[4][IMG_U32];     // 4 x 20KB; aliased as merge buffer at the end

  int tid = threadIdx.x;
  int l = tid & 63, w = tid >> 6;      // w: 0..15
  int l15 = l & 15, l4 = l >> 4;
  int wr = w & 3, wc = w >> 2;         // wr: key quarter, wc: row quarter (16 rows each)
  int slice = blockIdx.x & 7;          // consecutive blocks -> different XCDs
  int rb = (blockIdx.x >> 3) << 6;     // 64 q rows per block

  // ---- B-frags (q side) in registers for the whole kernel ----
  bf16x8 bfr[4];
#pragma unroll
  for (int c = 0; c < 4; ++c) {
    const ushort* qp = qext2 + (size_t)(rb + wc * 16 + l15) * 128 + c * 32 + l4 * 8;
    bfr[c] = __builtin_bit_cast(bf16x8, *(const u32x4*)qp);
  }
  bf16x8 bk2;
  {
    u16x8 v = {0, 0, 0, 0, 0, 0, 0, 0};
    if (l4 == 0) { v[0] = 0x3F80; v[1] = 0x3F80; }
    bk2 = __builtin_bit_cast(bf16x8, v);
  }
  float q2v = q2g[rb + wc * 16 + l15];

  // ---- per-lane register top-QT queue (ONE row per lane), always sorted asc ----
  u32 topq[QT];
#pragma unroll
  for (int j = 0; j < QT; ++j) topq[j] = 0xFFFFFFFFu;

  const u32* imgbase = keyimg + (size_t)slice * NB * IMG_U32;

  auto stage = [&](int b, int t) {
    if (w < 5) {
      const u32* src = imgbase + (size_t)t * IMG_U32 + w * 1024 + l * 4;
      u32* dst = &kbuf[b][w * 1024];
#pragma unroll
      for (int i = 0; i < 4; ++i)
        gl_lds16(src + i * 256, dst + i * 256);
    }
  };

  auto compute_tile = [&](int t, int bi) {
    f32x4 acc = {};
#pragma unroll
    for (int c = 0; c < 5; ++c) {
      bf16x8 a = __builtin_bit_cast(bf16x8,
          *(const u32x4*)&kbuf[bi][c * 1024 + l4 * 256 + (wr * 16 + l15) * 4]);
      acc = __builtin_amdgcn_mfma_f32_16x16x32_bf16(a, (c < 4) ? bfr[c] : bk2, acc, 0, 0, 0);
    }
    u32 cc[4];
#pragma unroll
    for (int r = 0; r < 4; ++r) {
      float dd = q2v + acc[r];
      cc[r] = (__float_as_uint(dd) & 0xFFFFE000u) |
              (u32)(t * BKEY + wr * 16 + (l4 << 2) + r);
    }
    // sort4 ascending
    CSWAP(cc[0], cc[1]); CSWAP(cc[2], cc[3]);
    CSWAP(cc[0], cc[2]); CSWAP(cc[1], cc[3]);
    CSWAP(cc[1], cc[2]);
    // reversed elementwise min (keep bottom-8 of 12); topq becomes bitonic
    topq[7] = topq[7] < cc[0] ? topq[7] : cc[0];
    topq[6] = topq[6] < cc[1] ? topq[6] : cc[1];
    topq[5] = topq[5] < cc[2] ? topq[5] : cc[2];
    topq[4] = topq[4] < cc[3] ? topq[4] : cc[3];
    // bitonic merge 8 -> sorted ascending
    CSWAP(topq[0], topq[4]); CSWAP(topq[1], topq[5]);
    CSWAP(topq[2], topq[6]); CSWAP(topq[3], topq[7]);
    CSWAP(topq[0], topq[2]); CSWAP(topq[1], topq[3]);
    CSWAP(topq[4], topq[6]); CSWAP(topq[5], topq[7]);
    CSWAP(topq[0], topq[1]); CSWAP(topq[2], topq[3]);
    CSWAP(topq[4], topq[5]); CSWAP(topq[6], topq[7]);
  };

  stage(0, 0);
  stage(1, 1);
  __syncthreads();

#pragma unroll 1
  for (int k = 0; k < NB / 2; ++k) {
    int t0 = 2 * k;
    if (t0 + 2 < NB) stage((t0 + 2) & 3, t0 + 2);
    if (t0 + 3 < NB) stage((t0 + 3) & 3, t0 + 3);
    compute_tile(t0, t0 & 3);
    compute_tile(t0 + 1, (t0 + 1) & 3);
    __syncthreads();               // stages drained; bufs t0, t0+1 free
  }

  // ---- end-of-kernel merge: 16 slots x QT=8 per row = 128 -> exact top-50 -----------
  u32* mb = &kbuf[0][0];           // [16 rows][128] = 8KB

#pragma unroll 1
  for (int g = 0; g < 4; ++g) {    // row group: rows g*16 .. g*16+15
    if (wc == g) {
      u32* dst = mb + l15 * 128 + (wr * 4 + l4) * QT;
#pragma unroll
      for (int j = 0; j < QT; ++j) dst[j] = topq[j];
    }
    __syncthreads();

    // each of the 16 waves sorts one row (wave-private LDS region)
    sort128_wave(mb + w * 128, l);

    // write exact top-50 per (row, slice)
    if (l < KNN) {
      int grow = rb + g * 16 + w;
      lbuf[((size_t)grow * NSLICE + slice) * CAP + l] = mb[w * 128 + l];
    }
    __syncthreads();               // before next group's dump overwrites mb
  }
}

// ---------------- K4: hierarchical merge of 8 sorted-50 -> top-64 -> exact rerank -----
__global__ __launch_bounds__(256) void k4_rerank(
    const u32* __restrict__ lbuf, const float* __restrict__ qrow,
    const float* __restrict__ q2g, const float* __restrict__ k2g,
    const float* __restrict__ keys, const float* __restrict__ memv,
    const float* __restrict__ net, float* __restrict__ out)
{
  __shared__ u64 sb[512];
  __shared__ float qs[128];
  __shared__ float part[4][RR];
  __shared__ u64 cand[RR];
  int b = blockIdx.x, t = threadIdx.x;
  if (t < 128) qs[t] = qrow[(size_t)b * D_ + t];

  // load 8 sorted-50 lists (pad to 64 with INF); odd lists stored reversed
#pragma unroll
  for (int h = 0; h < 2; ++h) {
    int e = t + (h << 8);          // 0..511
    int s = e >> 6, jj = e & 63;
    u64 v = ~0ull;
    if (jj < KNN) {
      u32 k32 = lbuf[((size_t)b * NSLICE + s) * CAP + jj];
      v = ((u64)(k32 & 0xFFFFE000u) << 32) | (u32)(s * SL_REAL + (k32 & 0x1FFFu));
    }
    int dst = (s & 1) ? ((s << 6) + 63 - jj) : ((s << 6) + jj);
    sb[dst] = v;
  }
  __syncthreads();

  // round 0: 4 pairs x 128 (asc+desc concatenated = bitonic) -> sorted-128, keep low 64
  for (int j = 64; j > 0; j >>= 1) {
#pragma unroll
    for (int h = 0; h < 2; ++h) {
      int g = t + (h << 8);
      if ((g & j) == 0) {
        int p = g | j;
        u64 x = sb[g], y = sb[p];
        if (y < x) { sb[g] = y; sb[p] = x; }
      }
    }
    __syncthreads();
  }
  // compact: pairs' low-64 -> 4 lists at stride 64; reverse new odd lists
  {
    int li = t >> 6, jj = t & 63;
    u64 keep = sb[li * 128 + jj];
    int dst = (li & 1) ? ((li << 6) + 63 - jj) : ((li << 6) + jj);
    __syncthreads();
    sb[dst] = keep;
    __syncthreads();
  }
  // round 1: 2 pairs x 128
  for (int j = 64; j > 0; j >>= 1) {
    if ((t & j) == 0) {
      int p = t | j;
      u64 x = sb[t], y = sb[p];
      if (y < x) { sb[t] = y; sb[p] = x; }
    }
    __syncthreads();
  }
  // compact: 2 lists -> stride 64; reverse second
  {
    u64 keep = ~0ull; int dst = -1;
    if (t < 128) {
      int li = t >> 6, jj = t & 63;
      keep = sb[li * 128 + jj];
      dst = li ? (64 + 63 - jj) : jj;
    }
    __syncthreads();
    if (dst >= 0) sb[dst] = keep;
    __syncthreads();
  }
  // round 2: 1 pair x 128 -> sb[0..63] = global top-64 ascending
  for (int j = 64; j > 0; j >>= 1) {
    if (t < 128 && (t & j) == 0) {
      int p = t | j;
      u64 x = sb[t], y = sb[p];
      if (y < x) { sb[t] = y; sb[p] = x; }
    }
    __syncthreads();
  }

  // exact rerank of top-RR
  int cid = t & 63, g = t >> 6;
  u32 gidx = (u32)sb[cid];
  const float* kp = keys + (size_t)gidx * D_ + g * 32;
  float dot = 0.f;
#pragma unroll
  for (int i = 0; i < 8; ++i) {
    float4 kv = *(const float4*)(kp + i * 4);
    float4 qv = *(const float4*)&qs[g * 32 + i * 4];
    dot = fmaf(kv.x, qv.x, dot); dot = fmaf(kv.y, qv.y, dot);
    dot = fmaf(kv.z, qv.z, dot); dot = fmaf(kv.w, qv.w, dot);
  }
  part[g][cid] = dot;
  __syncthreads();
  if (t < RR) {
    float dotf = part[0][t] + part[1][t] + part[2][t] + part[3][t];
    u32 gi = (u32)sb[t];
    float dd = q2g[b] + k2g[gi] - 2.0f * dotf;
    cand[t] = ((u64)__float_as_uint(dd) << 32) | gi;
  }
  __syncthreads();
  if (t < 64) {
    for (int k = 2; k <= 64; k <<= 1)
      for (int j = k >> 1; j > 0; j >>= 1) {
        u64 x = cand[t], y = cand[t ^ j];
        __builtin_amdgcn_wave_barrier();
        bool up = ((t & k) == 0);
        u64 mn = x < y ? x : y, mx = x < y ? y : x;
        cand[t] = ((t < (t ^ j)) == up) ? mn : mx;
        __builtin_amdgcn_wave_barrier();
      }
    u64 key = cand[t];
    float d = __uint_as_float((u32)(key >> 32));
    u32 idx = (u32)key;
    float w = 0.f, wv = 0.f;
    if (t < KNN) {
      float ww = 1.0f / (d + 1e-7f);
      w = ww;
      wv = ww * memv[idx];
    }
#pragma unroll
    for (int o = 1; o < 64; o <<= 1) {
      w += __shfl_xor(w, o);
      wv += __shfl_xor(wv, o);
    }
    if (t == 0) out[b] = 0.9f * (wv / w) + 0.1f * net[b];
  }
}

// ---------------- launch --------------------------------------------------------------
extern "C" void kernel_launch(void* const* d_in, const int* in_sizes, int n_in,
                              void* d_out, int out_size, void* d_ws, size_t ws_size,
                              hipStream_t stream)
{
  const float* states     = (const float*)d_in[0];
  const float* W1         = (const float*)d_in[1];
  const float* b1         = (const float*)d_in[2];
  const float* W2         = (const float*)d_in[3];
  const float* b2         = (const float*)d_in[4];
  const float* lng        = (const float*)d_in[5];
  const float* lnb        = (const float*)d_in[6];
  const float* mem_keys   = (const float*)d_in[7];
  const float* mem_values = (const float*)d_in[8];
  const float* V1         = (const float*)d_in[9];
  const float* c1         = (const float*)d_in[10];
  const float* V2         = (const float*)d_in[11];
  const float* c2         = (const float*)d_in[12];
  const float* V3         = (const float*)d_in[13];
  const float* c3         = (const float*)d_in[14];
  float* out = (float*)d_out;

  char* ws = (char*)d_ws;
  ushort* qext2 = (ushort*)(ws + 0);          // 1 MB
  float*  qrow  = (float*)(ws + 1048576);     // 2 MB
  float*  q2    = (float*)(ws + 3145728);     // 16 KB
  float*  net   = (float*)(ws + 3162112);     // 16 KB
  float*  k2g   = (float*)(ws + 3178496);     // 200 KB (ends 3383296)
  u32*  keyimg  = (u32*)(ws + 3383296);       // 16.06 MB (ends 19,439,616)
  u32*  lbuf    = (u32*)(ws + 19439616);      // CAP=64: 8.39 MB (ends 27,828,224)
  float* h      = (float*)(ws + 27828224);    // 4 MB (ends 31,...)
  float* v1     = (float*)(ws + 27828224 + 4194304);  // 4 MB (ends 36,216,832)

  k15_fused<<<dim3(512 + NSLICE * SL_PAD / 128), 256, 0, stream>>>(
      states, W1, b1, V1, c1, h, v1, mem_keys, keyimg, k2g);
  k2_fused<<<dim3(B_ / 32, 1, 2), 256, 0, stream>>>(h, v1, W2, b2, V2, c2, lng, lnb, V3, c3,
                                                    qext2, qrow, q2, net);
  k3_knn<<<dim3((B_ / 64) * NSLICE), 1024, 0, stream>>>(qext2, q2, keyimg, lbuf);
  k4_rerank<<<dim3(B_), 256, 0, stream>>>(lbuf, qrow, q2, k2g, mem_keys, mem_values, net, out);
}